// Round 8
// baseline (266.630 us; speedup 1.0000x reference)
//
#include <hip/hip_runtime.h>

#define N_NODES 50000
#define N_EDGES 800000
#define FEATS   128
#define HID     32
#define HEADS   4
#define D1      128      // HEADS*HID
#define NGRAPH  64
#define SCAN_NB ((N_NODES + 1023) / 1024)   // 49

__device__ __forceinline__ float lrelu_(float v) { return fmaxf(v, 0.2f * v); }
__device__ __forceinline__ float elu_(float v)   { return v > 0.f ? v : __expf(v) - 1.f; }

typedef __attribute__((ext_vector_type(8))) short short8v;
typedef __attribute__((ext_vector_type(4))) float f32x4;
typedef __attribute__((ext_vector_type(8))) unsigned short u16x8;

#define L2E 1.4426950408889634f

// fp32 -> bf16 (RNE) high part
__device__ __forceinline__ unsigned short bf16hi_(float x) {
    unsigned u = __float_as_uint(x);
    unsigned r = u + 0x7FFFu + ((u >> 16) & 1);
    return (unsigned short)(r >> 16);
}
__device__ __forceinline__ float bf16f_(unsigned short h) {
    return __uint_as_float(((unsigned)h) << 16);
}

// ---------- CSR build ----------
__global__ __launch_bounds__(256) void k_hist(const int* __restrict__ ei, int* __restrict__ deg)
{
    int e = blockIdx.x * 256 + threadIdx.x;
    if (e < N_EDGES) atomicAdd(&deg[ei[N_EDGES + e]], 1);
}

__global__ __launch_bounds__(1024) void k_scan_local(
    const int* __restrict__ deg, int* __restrict__ rs, int* __restrict__ btot)
{
    __shared__ int sm[1024];
    int idx = blockIdx.x * 1024 + threadIdx.x;
    int v = (idx < N_NODES) ? deg[idx] : 0;
    sm[threadIdx.x] = v;
    __syncthreads();
    for (int off = 1; off < 1024; off <<= 1) {
        int t = (threadIdx.x >= off) ? sm[threadIdx.x - off] : 0;
        __syncthreads();
        sm[threadIdx.x] += t;
        __syncthreads();
    }
    if (idx < N_NODES) rs[idx] = sm[threadIdx.x] - v;   // exclusive
    if (threadIdx.x == 1023) btot[blockIdx.x] = sm[1023];
}

__global__ __launch_bounds__(64) void k_scan_btot(
    const int* __restrict__ btot, int* __restrict__ boff)
{
    int t = threadIdx.x;
    int own = (t < SCAN_NB) ? btot[t] : 0;
    int v = own;
    for (int off = 1; off < 64; off <<= 1) {
        int u = __shfl_up(v, off);
        if (t >= off) v += u;
    }
    if (t < SCAN_NB) boff[t] = v - own;   // exclusive
}

__global__ __launch_bounds__(1024) void k_scan_add(
    int* __restrict__ rs, const int* __restrict__ boff)
{
    int idx = blockIdx.x * 1024 + threadIdx.x;
    if (idx < N_NODES) rs[idx] += boff[blockIdx.x];
    if (idx == N_NODES) rs[N_NODES] = N_EDGES;
}

__global__ __launch_bounds__(256) void k_scatter(const int* __restrict__ ei,
                                                const int* __restrict__ rs,
                                                int* __restrict__ cur,
                                                int* __restrict__ csr_src)
{
    int e = blockIdx.x * 256 + threadIdx.x;
    if (e >= N_EDGES) return;
    int d = ei[N_EDGES + e];
    int p = rs[d] + atomicAdd(&cur[d], 1);
    csr_src[p] = ei[e];
}

__global__ __launch_bounds__(256) void k_gbound(const int* __restrict__ batch, int* __restrict__ gstart)
{
    int i = blockIdx.x * 256 + threadIdx.x;
    if (i > N_NODES) return;
    int b    = (i < N_NODES) ? batch[i] : NGRAPH;
    int prev = (i == 0) ? -1 : batch[i - 1];
    for (int g = prev + 1; g <= b; ++g) gstart[g] = i;
}

// ---------- weight re-layout: conv1 weights -> MFMA-frag-ordered bf16 hi/lo ----------
__global__ __launch_bounds__(256) void k_wtrans1(
    const float* __restrict__ wl, const float* __restrict__ wr,
    unsigned short* __restrict__ bh, unsigned short* __restrict__ blo)
{
    int idx = blockIdx.x * 256 + threadIdx.x;   // 32768
    if (idx >= 32768) return;
    int j    = idx & 7;
    int lane = (idx >> 3) & 63;
    int ks   = (idx >> 9) & 3;
    int nfg  = idx >> 11;                       // 0..15
    int col  = nfg * 16 + (lane & 15);
    int k    = ks * 32 + ((lane >> 4) & 3) * 8 + j;
    float wv = (col < 128) ? wl[col * FEATS + k] : wr[(col - 128) * FEATS + k];
    unsigned short h = bf16hi_(wv);
    float lo = wv - bf16f_(h);
    bh[idx]  = h;
    blo[idx] = bf16hi_(lo);
}

__global__ __launch_bounds__(256) void k_wtrans2(
    const float* __restrict__ wl, const float* __restrict__ wr, float* __restrict__ wtg)
{
    int idx = blockIdx.x * 256 + threadIdx.x;   // 8192
    if (idx >= 32 * 64 * 4) return;
    int kk = idx & 3, j = (idx >> 2) & 63, k4 = idx >> 8;
    int k = k4 * 4 + kk;
    wtg[idx] = (j < 32) ? wl[j * D1 + k] : wr[(j - 32) * D1 + k];
}

// ---------- conv1 transform: MFMA bf16x3, 64 rows/block, wave owns 64 cols ----------
__global__ __launch_bounds__(256) void k_transform1(
    const float* __restrict__ x,
    const unsigned short* __restrict__ bh1, const unsigned short* __restrict__ bl1,
    const float* __restrict__ bl, const float* __restrict__ br,
    unsigned short* __restrict__ xlb, float* __restrict__ xr)
{
    __shared__ unsigned short XH[64 * 136];   // 17.4 KB
    __shared__ unsigned short XL[64 * 136];   // 17.4 KB
    int m0 = blockIdx.x * 64;
    for (int i = threadIdx.x; i < 2048; i += 256) {      // 64 rows x 32 float4
        int r = i >> 5, c4 = i & 31;
        int n = m0 + r; if (n > N_NODES - 1) n = N_NODES - 1;   // tail clamp (benign dup)
        float4 v = *(const float4*)&x[(size_t)n * FEATS + c4 * 4];
        ushort4 h, lo;
        h.x = bf16hi_(v.x); lo.x = bf16hi_(v.x - bf16f_(h.x));
        h.y = bf16hi_(v.y); lo.y = bf16hi_(v.y - bf16f_(h.y));
        h.z = bf16hi_(v.z); lo.z = bf16hi_(v.z - bf16f_(h.z));
        h.w = bf16hi_(v.w); lo.w = bf16hi_(v.w - bf16f_(h.w));
        *(ushort4*)&XH[r * 136 + c4 * 4] = h;
        *(ushort4*)&XL[r * 136 + c4 * 4] = lo;
    }
    __syncthreads();

    int l  = threadIdx.x & 63;
    int wq = threadIdx.x >> 6;          // wave id = col-quadrant (64 cols)
    int lr = l & 15;
    int lk = (l >> 4) & 3;

    f32x4 acc[4][4];
#pragma unroll
    for (int m = 0; m < 4; ++m)
#pragma unroll
        for (int n = 0; n < 4; ++n)
#pragma unroll
            for (int g = 0; g < 4; ++g) acc[m][n][g] = 0.f;

    const short8v* bhp = (const short8v*)bh1;
    const short8v* blp = (const short8v*)bl1;

#pragma unroll
    for (int ks = 0; ks < 4; ++ks) {
        short8v bh[4], bw[4], ah[4], al[4];
#pragma unroll
        for (int nf = 0; nf < 4; ++nf) {
            int fidx = (((wq * 4 + nf) * 4 + ks) * 64) + l;
            bh[nf] = bhp[fidx];
            bw[nf] = blp[fidx];
        }
#pragma unroll
        for (int mf = 0; mf < 4; ++mf) {
            int off = (mf * 16 + lr) * 136 + ks * 32 + lk * 8;
            ah[mf] = *(const short8v*)&XH[off];
            al[mf] = *(const short8v*)&XL[off];
        }
#pragma unroll
        for (int mf = 0; mf < 4; ++mf)
#pragma unroll
            for (int nf = 0; nf < 4; ++nf) {
                acc[mf][nf] = __builtin_amdgcn_mfma_f32_16x16x32_bf16(ah[mf], bh[nf], acc[mf][nf], 0, 0, 0);
                acc[mf][nf] = __builtin_amdgcn_mfma_f32_16x16x32_bf16(ah[mf], bw[nf], acc[mf][nf], 0, 0, 0);
                acc[mf][nf] = __builtin_amdgcn_mfma_f32_16x16x32_bf16(al[mf], bh[nf], acc[mf][nf], 0, 0, 0);
            }
    }

    // epilogue: D col = lane&15, row = (lane>>4)*4 + reg
#pragma unroll
    for (int nf = 0; nf < 4; ++nf) {
        int col = wq * 64 + nf * 16 + lr;
        float bv = (col < 128) ? bl[col] : br[col - 128];
#pragma unroll
        for (int mf = 0; mf < 4; ++mf)
#pragma unroll
            for (int g = 0; g < 4; ++g) {
                int row = m0 + mf * 16 + lk * 4 + g;
                if (row > N_NODES - 1) row = N_NODES - 1;    // benign dup (same values)
                float v = acc[mf][nf][g] + bv;
                if (col < 128) xlb[(size_t)row * 128 + col] = bf16hi_(v);
                else           xr [(size_t)row * D1 + (col - 128)] = v;
            }
    }
}

// ---------- conv2 transform: 64 nodes/block, 8 nodes/thread, 2 cols/thread ----------
__global__ __launch_bounds__(256, 2) void k_transform2(
    const float* __restrict__ hin, const float* __restrict__ wtg,
    const float* __restrict__ bl, const float* __restrict__ br,
    unsigned short* __restrict__ xlb2, float* __restrict__ xr2)
{
    __shared__ float4 xs[64][32];   // 32 KB
    int node0 = blockIdx.x * 64;
    for (int i = threadIdx.x; i < 2048; i += 256) {
        int r = i >> 5, k4 = i & 31;
        int n = node0 + r; if (n > N_NODES - 1) n = N_NODES - 1;
        xs[r][k4] = *(const float4*)&hin[(size_t)n * D1 + k4 * 4];
    }
    __syncthreads();
    int j  = threadIdx.x & 31;
    int r0 = (threadIdx.x >> 5) * 8;
    const float4* __restrict__ wp = (const float4*)wtg;
    float accl[8], accr[8];
#pragma unroll
    for (int r = 0; r < 8; ++r) { accl[r] = 0.f; accr[r] = 0.f; }

    float4 wl_ = wp[j], wr_ = wp[j + 32];

#pragma unroll 2
    for (int k4 = 0; k4 < 32; ++k4) {
        int k4n = (k4 < 31) ? k4 + 1 : 31;
        float4 wln = wp[k4n * 64 + j];
        float4 wrn = wp[k4n * 64 + j + 32];
        float4 xv[8];
#pragma unroll
        for (int r = 0; r < 8; ++r) xv[r] = xs[r0 + r][k4];
#pragma unroll
        for (int r = 0; r < 8; ++r) {
            accl[r] = fmaf(wl_.x, xv[r].x, fmaf(wl_.y, xv[r].y,
                      fmaf(wl_.z, xv[r].z, fmaf(wl_.w, xv[r].w, accl[r]))));
            accr[r] = fmaf(wr_.x, xv[r].x, fmaf(wr_.y, xv[r].y,
                      fmaf(wr_.z, xv[r].z, fmaf(wr_.w, xv[r].w, accr[r]))));
        }
        wl_ = wln; wr_ = wrn;
    }
    float bls = bl[j], brs = br[j];
#pragma unroll
    for (int r = 0; r < 8; ++r) {
        int nn = node0 + r0 + r; if (nn > N_NODES - 1) nn = N_NODES - 1;
        size_t n = (size_t)nn;
        xlb2[n * HID + j] = bf16hi_(accl[r] + bls);
        xr2 [n * HID + j] = accr[r] + brs;
    }
}

// ---------- conv1 fused: wave per node, 16 lanes/edge (ushort8), 4 edges in flight ----------
// lane: j = lane&15 -> dims 8j..8j+7; q = lane>>4 -> edge quarter.
// att pre-scaled by log2(e); exp via exp2f. Quarters combined at the end (shfl 16,32).
__global__ __launch_bounds__(256) void k_gat1_fused(
    const int* __restrict__ rs, const int* __restrict__ csr_src,
    const unsigned short* __restrict__ xlb, const float* __restrict__ xr,
    const float* __restrict__ att, const float* __restrict__ bias,
    float* __restrict__ hout)
{
    int n = (blockIdx.x * 256 + threadIdx.x) >> 6;
    if (n >= N_NODES) return;
    int lane = threadIdx.x & 63;
    int j    = lane & 15;
    int q    = lane >> 4;
    const u16x8*  xlp = (const u16x8*)xlb;    // row = 16 slots
    const float4* xrp = (const float4*)xr;
    const float4* atp = (const float4*)att;

    float rr[8], aa[8];
    {
        float4 t0 = xrp[n * 32 + 2 * j], t1 = xrp[n * 32 + 2 * j + 1];
        rr[0]=t0.x; rr[1]=t0.y; rr[2]=t0.z; rr[3]=t0.w;
        rr[4]=t1.x; rr[5]=t1.y; rr[6]=t1.z; rr[7]=t1.w;
        float4 a0 = atp[2 * j], a1 = atp[2 * j + 1];
        aa[0]=a0.x*L2E; aa[1]=a0.y*L2E; aa[2]=a0.z*L2E; aa[3]=a0.w*L2E;
        aa[4]=a1.x*L2E; aa[5]=a1.y*L2E; aa[6]=a1.z*L2E; aa[7]=a1.w*L2E;
    }

    float acc[8], den;
    {   // self edge (counted on quarter 0 only)
        u16x8 u = xlp[(n << 4) | j];
        float lv[8], sc = 0.f;
#pragma unroll
        for (int e = 0; e < 8; ++e) {
            lv[e] = bf16f_((unsigned short)u[e]);
            float t = lv[e] + rr[e];
            sc = fmaf(aa[e], lrelu_(t), sc);
        }
        sc += __shfl_xor(sc, 1);
        sc += __shfl_xor(sc, 2);
        float ex = (q == 0) ? exp2f(sc) : 0.f;
        den = ex;
#pragma unroll
        for (int e = 0; e < 8; ++e) acc[e] = ex * lv[e];
    }

    int e1 = rs[n + 1];
    int p  = rs[n];
    for (; p + 16 <= e1; p += 16) {      // 4 quads = 16 edges, 4 loads/lane in flight
        int s0 = csr_src[p + q];
        int s1 = csr_src[p + 4 + q];
        int s2 = csr_src[p + 8 + q];
        int s3 = csr_src[p + 12 + q];
        u16x8 u0 = xlp[(s0 << 4) | j];
        u16x8 u1 = xlp[(s1 << 4) | j];
        u16x8 u2 = xlp[(s2 << 4) | j];
        u16x8 u3 = xlp[(s3 << 4) | j];
        float v0[8], v1[8], v2[8], v3[8];
        float c0 = 0.f, c1 = 0.f, c2 = 0.f, c3 = 0.f;
#pragma unroll
        for (int e = 0; e < 8; ++e) {
            v0[e] = bf16f_((unsigned short)u0[e]);
            float t = v0[e] + rr[e];
            c0 = fmaf(aa[e], lrelu_(t), c0);
        }
#pragma unroll
        for (int e = 0; e < 8; ++e) {
            v1[e] = bf16f_((unsigned short)u1[e]);
            float t = v1[e] + rr[e];
            c1 = fmaf(aa[e], lrelu_(t), c1);
        }
#pragma unroll
        for (int e = 0; e < 8; ++e) {
            v2[e] = bf16f_((unsigned short)u2[e]);
            float t = v2[e] + rr[e];
            c2 = fmaf(aa[e], lrelu_(t), c2);
        }
#pragma unroll
        for (int e = 0; e < 8; ++e) {
            v3[e] = bf16f_((unsigned short)u3[e]);
            float t = v3[e] + rr[e];
            c3 = fmaf(aa[e], lrelu_(t), c3);
        }
        c0 += __shfl_xor(c0, 1); c1 += __shfl_xor(c1, 1);
        c2 += __shfl_xor(c2, 1); c3 += __shfl_xor(c3, 1);
        c0 += __shfl_xor(c0, 2); c1 += __shfl_xor(c1, 2);
        c2 += __shfl_xor(c2, 2); c3 += __shfl_xor(c3, 2);
        float x0 = exp2f(c0), x1 = exp2f(c1), x2 = exp2f(c2), x3 = exp2f(c3);
        den += (x0 + x1) + (x2 + x3);
#pragma unroll
        for (int e = 0; e < 8; ++e) {
            float t = fmaf(x0, v0[e], acc[e]);
            t = fmaf(x1, v1[e], t);
            t = fmaf(x2, v2[e], t);
            acc[e] = fmaf(x3, v3[e], t);
        }
    }
    for (; p < e1; p += 4) {             // masked quad tail
        int  idx = p + q;
        bool vld = idx < e1;
        int  s   = csr_src[vld ? idx : e1 - 1];
        u16x8 u = xlp[(s << 4) | j];
        float v[8], sb = 0.f;
#pragma unroll
        for (int e = 0; e < 8; ++e) {
            v[e] = bf16f_((unsigned short)u[e]);
            float t = v[e] + rr[e];
            sb = fmaf(aa[e], lrelu_(t), sb);
        }
        sb += __shfl_xor(sb, 1);
        sb += __shfl_xor(sb, 2);
        float ex = vld ? exp2f(sb) : 0.f;
        den += ex;
#pragma unroll
        for (int e = 0; e < 8; ++e) acc[e] = fmaf(ex, v[e], acc[e]);
    }

    // combine quarters
    den += __shfl_xor(den, 16);
    den += __shfl_xor(den, 32);
#pragma unroll
    for (int e = 0; e < 8; ++e) {
        acc[e] += __shfl_xor(acc[e], 16);
        acc[e] += __shfl_xor(acc[e], 32);
    }
    if (q == 0) {
        float inv = 1.f / (den + 1e-16f);
        float4 b0 = ((const float4*)bias)[2 * j], b1 = ((const float4*)bias)[2 * j + 1];
        float4 o0, o1;
        o0.x = elu_(acc[0] * inv + b0.x);
        o0.y = elu_(acc[1] * inv + b0.y);
        o0.z = elu_(acc[2] * inv + b0.z);
        o0.w = elu_(acc[3] * inv + b0.w);
        o1.x = elu_(acc[4] * inv + b1.x);
        o1.y = elu_(acc[5] * inv + b1.y);
        o1.z = elu_(acc[6] * inv + b1.z);
        o1.w = elu_(acc[7] * inv + b1.w);
        ((float4*)hout)[(size_t)n * 32 + 2 * j]     = o0;   // hout aliases xr: own row only
        ((float4*)hout)[(size_t)n * 32 + 2 * j + 1] = o1;
    }
}

// ---------- conv2 fused: half-wave per node, 4 lanes/edge (ushort8), 8 edges in flight ----------
__global__ __launch_bounds__(256) void k_gat2_fused(
    const int* __restrict__ rs, const int* __restrict__ csr_src,
    const unsigned short* __restrict__ xlb2, const float* __restrict__ xr2,
    const float* __restrict__ att, const float* __restrict__ bias,
    float* __restrict__ h2)
{
    int n = (blockIdx.x * 256 + threadIdx.x) >> 5;
    if (n >= N_NODES) return;
    int lane = threadIdx.x & 31;
    int j    = lane & 3;
    int q    = lane >> 2;               // 0..7
    const u16x8* xlp = (const u16x8*)xlb2;   // row = 4 slots
    float rr[8], aa[8];
    {
        float4 t0 = ((const float4*)xr2)[n * 8 + 2 * j], t1 = ((const float4*)xr2)[n * 8 + 2 * j + 1];
        rr[0]=t0.x; rr[1]=t0.y; rr[2]=t0.z; rr[3]=t0.w;
        rr[4]=t1.x; rr[5]=t1.y; rr[6]=t1.z; rr[7]=t1.w;
        float4 a0 = ((const float4*)att)[2 * j], a1 = ((const float4*)att)[2 * j + 1];
        aa[0]=a0.x*L2E; aa[1]=a0.y*L2E; aa[2]=a0.z*L2E; aa[3]=a0.w*L2E;
        aa[4]=a1.x*L2E; aa[5]=a1.y*L2E; aa[6]=a1.z*L2E; aa[7]=a1.w*L2E;
    }

    float acc[8], den;
    {   // self edge (octant 0 only)
        u16x8 u = xlp[(n << 2) | j];
        float lv[8], sc = 0.f;
#pragma unroll
        for (int e = 0; e < 8; ++e) {
            lv[e] = bf16f_((unsigned short)u[e]);
            float t = lv[e] + rr[e];
            sc = fmaf(aa[e], lrelu_(t), sc);
        }
        sc += __shfl_xor(sc, 1);
        sc += __shfl_xor(sc, 2);
        float ex = (q == 0) ? exp2f(sc) : 0.f;
        den = ex;
#pragma unroll
        for (int e = 0; e < 8; ++e) acc[e] = ex * lv[e];
    }

    int e1 = rs[n + 1];
    int p  = rs[n];
    for (; p + 16 <= e1; p += 16) {      // 2 octo-groups = 16 edges, 2 loads/lane
        int s0 = csr_src[p + q];
        int s1 = csr_src[p + 8 + q];
        u16x8 u0 = xlp[(s0 << 2) | j];
        u16x8 u1 = xlp[(s1 << 2) | j];
        float v0[8], v1[8];
        float c0 = 0.f, c1 = 0.f;
#pragma unroll
        for (int e = 0; e < 8; ++e) {
            v0[e] = bf16f_((unsigned short)u0[e]);
            float t = v0[e] + rr[e];
            c0 = fmaf(aa[e], lrelu_(t), c0);
        }
#pragma unroll
        for (int e = 0; e < 8; ++e) {
            v1[e] = bf16f_((unsigned short)u1[e]);
            float t = v1[e] + rr[e];
            c1 = fmaf(aa[e], lrelu_(t), c1);
        }
        c0 += __shfl_xor(c0, 1); c1 += __shfl_xor(c1, 1);
        c0 += __shfl_xor(c0, 2); c1 += __shfl_xor(c1, 2);
        float x0 = exp2f(c0), x1 = exp2f(c1);
        den += x0 + x1;
#pragma unroll
        for (int e = 0; e < 8; ++e)
            acc[e] = fmaf(x1, v1[e], fmaf(x0, v0[e], acc[e]));
    }
    for (; p < e1; p += 8) {             // masked octo tail
        int  idx = p + q;
        bool vld = idx < e1;
        int  s   = csr_src[vld ? idx : e1 - 1];
        u16x8 u = xlp[(s << 2) | j];
        float v[8], sb = 0.f;
#pragma unroll
        for (int e = 0; e < 8; ++e) {
            v[e] = bf16f_((unsigned short)u[e]);
            float t = v[e] + rr[e];
            sb = fmaf(aa[e], lrelu_(t), sb);
        }
        sb += __shfl_xor(sb, 1);
        sb += __shfl_xor(sb, 2);
        float ex = vld ? exp2f(sb) : 0.f;
        den += ex;
#pragma unroll
        for (int e = 0; e < 8; ++e) acc[e] = fmaf(ex, v[e], acc[e]);
    }

    // combine octants (stays within 32-lane half)
    den += __shfl_xor(den, 4);
    den += __shfl_xor(den, 8);
    den += __shfl_xor(den, 16);
#pragma unroll
    for (int e = 0; e < 8; ++e) {
        acc[e] += __shfl_xor(acc[e], 4);
        acc[e] += __shfl_xor(acc[e], 8);
        acc[e] += __shfl_xor(acc[e], 16);
    }
    if (q == 0) {
        float inv = 1.f / (den + 1e-16f);
        float4 b0 = ((const float4*)bias)[2 * j], b1 = ((const float4*)bias)[2 * j + 1];
        float4 o0, o1;
        o0.x = elu_(acc[0] * inv + b0.x);
        o0.y = elu_(acc[1] * inv + b0.y);
        o0.z = elu_(acc[2] * inv + b0.z);
        o0.w = elu_(acc[3] * inv + b0.w);
        o1.x = elu_(acc[4] * inv + b1.x);
        o1.y = elu_(acc[5] * inv + b1.y);
        o1.z = elu_(acc[6] * inv + b1.z);
        o1.w = elu_(acc[7] * inv + b1.w);
        ((float4*)h2)[(size_t)n * 8 + 2 * j]     = o0;
        ((float4*)h2)[(size_t)n * 8 + 2 * j + 1] = o1;
    }
}

// ---------- per-graph mean pool + both heads ----------
__global__ __launch_bounds__(256) void k_pool_heads(
    const float* __restrict__ h2, const int* __restrict__ gstart,
    const float* __restrict__ wc, const float* __restrict__ bc,
    const float* __restrict__ wp, const float* __restrict__ bp,
    float* __restrict__ out)
{
    int g  = blockIdx.x;
    int n0 = gstart[g], n1 = gstart[g + 1];
    int c    = threadIdx.x & 31;
    int slot = threadIdx.x >> 5;   // 0..7
    float s = 0.f;
    for (int n = n0 + slot; n < n1; n += 8)
        s += h2[n * HID + c];
    __shared__ float red[8][HID];
    red[slot][c] = s;
    __syncthreads();
    if (slot == 0) {
        float tot = 0.f;
#pragma unroll
        for (int i = 0; i < 8; ++i) tot += red[i][c];
        float cntf = fmaxf((float)(n1 - n0), 1.f);
        float p = tot / cntf;
        float sc = p * wc[c];
        float sp = p * wp[c];
        sc += __shfl_xor(sc, 1);  sp += __shfl_xor(sp, 1);
        sc += __shfl_xor(sc, 2);  sp += __shfl_xor(sp, 2);
        sc += __shfl_xor(sc, 4);  sp += __shfl_xor(sp, 4);
        sc += __shfl_xor(sc, 8);  sp += __shfl_xor(sp, 8);
        sc += __shfl_xor(sc, 16); sp += __shfl_xor(sp, 16);
        if (c == 0) {
            out[g]          = sc + bc[0];
            out[NGRAPH + g] = sp + bp[0];
        }
    }
}

extern "C" void kernel_launch(void* const* d_in, const int* in_sizes, int n_in,
                              void* d_out, int out_size, void* d_ws, size_t ws_size,
                              hipStream_t stream)
{
    const float* x     = (const float*)d_in[0];
    const int*   ei    = (const int*)d_in[1];
    const int*   batch = (const int*)d_in[2];
    const float* w1l   = (const float*)d_in[3];
    const float* b1l   = (const float*)d_in[4];
    const float* w1r   = (const float*)d_in[5];
    const float* b1r   = (const float*)d_in[6];
    const float* att1  = (const float*)d_in[7];
    const float* bias1 = (const float*)d_in[8];
    const float* w2l   = (const float*)d_in[9];
    const float* b2l   = (const float*)d_in[10];
    const float* w2r   = (const float*)d_in[11];
    const float* b2r   = (const float*)d_in[12];
    const float* att2  = (const float*)d_in[13];
    const float* bias2 = (const float*)d_in[14];
    const float* wc    = (const float*)d_in[15];
    const float* bc    = (const float*)d_in[16];
    const float* wp    = (const float*)d_in[17];
    const float* bp    = (const float*)d_in[18];
    float* out = (float*)d_out;

    float* ws   = (float*)d_ws;
    // conv1 phase: xlb (bf16 gathered table); xr1 at +6.4M
    unsigned short* xlb = (unsigned short*)ws;          // 6,400,000 ushorts = 12.8 MB
    float* xr1  = ws + 6400000;       // 6,400,000 floats
    float* hbuf = ws + 6400000;       // ALIASES xr1 (safe: per-wave read-own-row-then-write)
    // conv2 phase (xlb region dead after k_gat1_fused)
    unsigned short* xlb2 = (unsigned short*)ws;         // 1,600,000 ushorts = 3.2 MB
    float* xr2  = ws + 1600000;       // 1,600,000 floats
    float* h2   = ws + 3200000;       // 1,600,000 floats
    // int region (after 12.8M floats)
    int* ibase   = (int*)(ws + 12800000);
    int* deg     = ibase;              //  50,000
    int* rs      = ibase + 50000;      //  50,001
    int* cur     = ibase + 100001;     //  50,000
    int* csr_src = ibase + 150001;     // 800,000
    int* gstart  = ibase + 950001;     //      65
    int* btot    = ibase + 950101;     //      49
    int* boff    = ibase + 950151;     //      49
    // re-laid-out weights: conv1 bf16 hi/lo frag-order, conv2 fp32
    unsigned short* bh1 = (unsigned short*)(ws + 13800000);   // 32768 ushort
    unsigned short* bl1_ = (unsigned short*)(ws + 13816384);  // 32768 ushort
    float* wtg2 = ws + 13840000;       //  8,192 floats

    // ---- one-time weight re-layout + CSR build + graph boundaries ----
    k_wtrans1<<<128, 256, 0, stream>>>(w1l, w1r, bh1, bl1_);
    k_wtrans2<<<32, 256, 0, stream>>>(w2l, w2r, wtg2);
    hipMemsetAsync(deg, 0, N_NODES * sizeof(int), stream);
    hipMemsetAsync(cur, 0, N_NODES * sizeof(int), stream);
    k_hist<<<(N_EDGES + 255) / 256, 256, 0, stream>>>(ei, deg);
    k_scan_local<<<SCAN_NB, 1024, 0, stream>>>(deg, rs, btot);
    k_scan_btot<<<1, 64, 0, stream>>>(btot, boff);
    k_scan_add<<<SCAN_NB, 1024, 0, stream>>>(rs, boff);
    k_scatter<<<(N_EDGES + 255) / 256, 256, 0, stream>>>(ei, rs, cur, csr_src);
    k_gbound<<<(N_NODES + 1 + 255) / 256, 256, 0, stream>>>(batch, gstart);

    // ---- conv1 ----
    k_transform1<<<(N_NODES + 63) / 64, 256, 0, stream>>>(x, bh1, bl1_, b1l, b1r, xlb, xr1);
    k_gat1_fused<<<(N_NODES * 64 + 255) / 256, 256, 0, stream>>>(rs, csr_src, xlb, xr1, att1, bias1, hbuf);

    // ---- conv2 ----
    k_transform2<<<(N_NODES + 63) / 64, 256, 0, stream>>>(hbuf, wtg2, b2l, b2r, xlb2, xr2);
    k_gat2_fused<<<(N_NODES * 32 + 255) / 256, 256, 0, stream>>>(rs, csr_src, xlb2, xr2, att2, bias2, h2);

    // ---- pool + heads ----
    k_pool_heads<<<NGRAPH, 256, 0, stream>>>(h2, gstart, wc, bc, wp, bp, out);
}

// Round 9
// 236.338 us; speedup vs baseline: 1.1282x; 1.1282x over previous
//
#include <hip/hip_runtime.h>

#define N_NODES 50000
#define N_EDGES 800000
#define FEATS   128
#define HID     32
#define HEADS   4
#define D1      128      // HEADS*HID
#define NGRAPH  64
#define SCAN_NB ((N_NODES + 1023) / 1024)   // 49

__device__ __forceinline__ float lrelu_(float v) { return fmaxf(v, 0.2f * v); }
__device__ __forceinline__ float elu_(float v)   { return v > 0.f ? v : __expf(v) - 1.f; }

typedef __attribute__((ext_vector_type(8))) short short8v;
typedef __attribute__((ext_vector_type(4))) float f32x4;

// fp32 -> bf16 (RNE) high part
__device__ __forceinline__ unsigned short bf16hi_(float x) {
    unsigned u = __float_as_uint(x);
    unsigned r = u + 0x7FFFu + ((u >> 16) & 1);
    return (unsigned short)(r >> 16);
}
__device__ __forceinline__ float bf16f_(unsigned short h) {
    return __uint_as_float(((unsigned)h) << 16);
}
__device__ __forceinline__ float4 b2f4_(ushort4 u) {
    float4 f;
    f.x = __uint_as_float(((unsigned)u.x) << 16);
    f.y = __uint_as_float(((unsigned)u.y) << 16);
    f.z = __uint_as_float(((unsigned)u.z) << 16);
    f.w = __uint_as_float(((unsigned)u.w) << 16);
    return f;
}

// ---------- fused prep: wtrans1(bf16 hi/lo) | wtrans2 | zero(deg,cur) | gbound ----------
// block ranges: [0,128) wtrans1, [128,160) wtrans2, [160,551) zero, [551,747) gbound
__global__ __launch_bounds__(256) void k_prep(
    const float* __restrict__ w1l, const float* __restrict__ w1r,
    unsigned short* __restrict__ bh, unsigned short* __restrict__ blo,
    const float* __restrict__ w2l, const float* __restrict__ w2r, float* __restrict__ wtg2,
    int* __restrict__ deg, int* __restrict__ cur,
    const int* __restrict__ batch, int* __restrict__ gstart)
{
    int b = blockIdx.x;
    if (b < 128) {
        int idx = b * 256 + threadIdx.x;            // 32768
        int j    = idx & 7;
        int lane = (idx >> 3) & 63;
        int ks   = (idx >> 9) & 3;
        int nfg  = idx >> 11;                       // 0..15
        int col  = nfg * 16 + (lane & 15);
        int k    = ks * 32 + ((lane >> 4) & 3) * 8 + j;
        float wv = (col < 128) ? w1l[col * FEATS + k] : w1r[(col - 128) * FEATS + k];
        unsigned short h = bf16hi_(wv);
        float lo = wv - bf16f_(h);
        bh[idx]  = h;
        blo[idx] = bf16hi_(lo);
    } else if (b < 160) {
        int idx = (b - 128) * 256 + threadIdx.x;    // 8192
        int kk = idx & 3, j = (idx >> 2) & 63, k4 = idx >> 8;
        int k = k4 * 4 + kk;
        wtg2[idx] = (j < 32) ? w2l[j * D1 + k] : w2r[(j - 32) * D1 + k];
    } else if (b < 551) {
        int i = (b - 160) * 256 + threadIdx.x;      // 100000
        if (i < N_NODES) deg[i] = 0;
        else if (i < 2 * N_NODES) cur[i - N_NODES] = 0;
    } else {
        int i = (b - 551) * 256 + threadIdx.x;      // 50001
        if (i > N_NODES) return;
        int bb   = (i < N_NODES) ? batch[i] : NGRAPH;
        int prev = (i == 0) ? -1 : batch[i - 1];
        for (int g = prev + 1; g <= bb; ++g) gstart[g] = i;
    }
}

// ---------- CSR build ----------
__global__ __launch_bounds__(256) void k_hist(const int* __restrict__ ei, int* __restrict__ deg)
{
    int e = blockIdx.x * 256 + threadIdx.x;
    if (e < N_EDGES) atomicAdd(&deg[ei[N_EDGES + e]], 1);
}

__global__ __launch_bounds__(1024) void k_scan_local(
    const int* __restrict__ deg, int* __restrict__ rs, int* __restrict__ btot)
{
    __shared__ int sm[1024];
    int idx = blockIdx.x * 1024 + threadIdx.x;
    int v = (idx < N_NODES) ? deg[idx] : 0;
    sm[threadIdx.x] = v;
    __syncthreads();
    for (int off = 1; off < 1024; off <<= 1) {
        int t = (threadIdx.x >= off) ? sm[threadIdx.x - off] : 0;
        __syncthreads();
        sm[threadIdx.x] += t;
        __syncthreads();
    }
    if (idx < N_NODES) rs[idx] = sm[threadIdx.x] - v;   // exclusive
    if (threadIdx.x == 1023) btot[blockIdx.x] = sm[1023];
}

__global__ __launch_bounds__(64) void k_scan_btot(
    const int* __restrict__ btot, int* __restrict__ boff)
{
    int t = threadIdx.x;
    int own = (t < SCAN_NB) ? btot[t] : 0;
    int v = own;
    for (int off = 1; off < 64; off <<= 1) {
        int u = __shfl_up(v, off);
        if (t >= off) v += u;
    }
    if (t < SCAN_NB) boff[t] = v - own;   // exclusive
}

__global__ __launch_bounds__(1024) void k_scan_add(
    int* __restrict__ rs, const int* __restrict__ boff)
{
    int idx = blockIdx.x * 1024 + threadIdx.x;
    if (idx < N_NODES) rs[idx] += boff[blockIdx.x];
    if (idx == N_NODES) rs[N_NODES] = N_EDGES;
}

__global__ __launch_bounds__(256) void k_scatter(const int* __restrict__ ei,
                                                const int* __restrict__ rs,
                                                int* __restrict__ cur,
                                                int* __restrict__ csr_src)
{
    int e = blockIdx.x * 256 + threadIdx.x;
    if (e >= N_EDGES) return;
    int d = ei[N_EDGES + e];
    int p = rs[d] + atomicAdd(&cur[d], 1);
    csr_src[p] = ei[e];
}

// ---------- conv1 transform: MFMA bf16x3, 64 rows/block, wave owns 64 cols ----------
__global__ __launch_bounds__(256) void k_transform1(
    const float* __restrict__ x,
    const unsigned short* __restrict__ bh1, const unsigned short* __restrict__ bl1,
    const float* __restrict__ bl, const float* __restrict__ br,
    unsigned short* __restrict__ xlb, float* __restrict__ xr)
{
    __shared__ unsigned short XH[64 * 136];   // 17.4 KB
    __shared__ unsigned short XL[64 * 136];   // 17.4 KB
    int m0 = blockIdx.x * 64;
    for (int i = threadIdx.x; i < 2048; i += 256) {      // 64 rows x 32 float4
        int r = i >> 5, c4 = i & 31;
        int n = m0 + r; if (n > N_NODES - 1) n = N_NODES - 1;   // tail clamp (benign dup)
        float4 v = *(const float4*)&x[(size_t)n * FEATS + c4 * 4];
        ushort4 h, lo;
        h.x = bf16hi_(v.x); lo.x = bf16hi_(v.x - bf16f_(h.x));
        h.y = bf16hi_(v.y); lo.y = bf16hi_(v.y - bf16f_(h.y));
        h.z = bf16hi_(v.z); lo.z = bf16hi_(v.z - bf16f_(h.z));
        h.w = bf16hi_(v.w); lo.w = bf16hi_(v.w - bf16f_(h.w));
        *(ushort4*)&XH[r * 136 + c4 * 4] = h;
        *(ushort4*)&XL[r * 136 + c4 * 4] = lo;
    }
    __syncthreads();

    int l  = threadIdx.x & 63;
    int wq = threadIdx.x >> 6;          // wave id = col-quadrant (64 cols)
    int lr = l & 15;
    int lk = (l >> 4) & 3;

    f32x4 acc[4][4];
#pragma unroll
    for (int m = 0; m < 4; ++m)
#pragma unroll
        for (int n = 0; n < 4; ++n)
#pragma unroll
            for (int g = 0; g < 4; ++g) acc[m][n][g] = 0.f;

    const short8v* bhp = (const short8v*)bh1;
    const short8v* blp = (const short8v*)bl1;

#pragma unroll
    for (int ks = 0; ks < 4; ++ks) {
        short8v bh[4], bw[4], ah[4], al[4];
#pragma unroll
        for (int nf = 0; nf < 4; ++nf) {
            int fidx = (((wq * 4 + nf) * 4 + ks) * 64) + l;
            bh[nf] = bhp[fidx];
            bw[nf] = blp[fidx];
        }
#pragma unroll
        for (int mf = 0; mf < 4; ++mf) {
            int off = (mf * 16 + lr) * 136 + ks * 32 + lk * 8;
            ah[mf] = *(const short8v*)&XH[off];
            al[mf] = *(const short8v*)&XL[off];
        }
#pragma unroll
        for (int mf = 0; mf < 4; ++mf)
#pragma unroll
            for (int nf = 0; nf < 4; ++nf) {
                acc[mf][nf] = __builtin_amdgcn_mfma_f32_16x16x32_bf16(ah[mf], bh[nf], acc[mf][nf], 0, 0, 0);
                acc[mf][nf] = __builtin_amdgcn_mfma_f32_16x16x32_bf16(ah[mf], bw[nf], acc[mf][nf], 0, 0, 0);
                acc[mf][nf] = __builtin_amdgcn_mfma_f32_16x16x32_bf16(al[mf], bh[nf], acc[mf][nf], 0, 0, 0);
            }
    }

    // epilogue: D col = lane&15, row = (lane>>4)*4 + reg
#pragma unroll
    for (int nf = 0; nf < 4; ++nf) {
        int col = wq * 64 + nf * 16 + lr;
        float bv = (col < 128) ? bl[col] : br[col - 128];
#pragma unroll
        for (int mf = 0; mf < 4; ++mf)
#pragma unroll
            for (int g = 0; g < 4; ++g) {
                int row = m0 + mf * 16 + lk * 4 + g;
                if (row > N_NODES - 1) row = N_NODES - 1;    // benign dup (same values)
                float v = acc[mf][nf][g] + bv;
                if (col < 128) xlb[(size_t)row * 128 + col] = bf16hi_(v);
                else           xr [(size_t)row * D1 + (col - 128)] = v;
            }
    }
}

// ---------- conv2 transform: 64 nodes/block, 8 nodes/thread, 2 cols/thread ----------
__global__ __launch_bounds__(256, 2) void k_transform2(
    const float* __restrict__ hin, const float* __restrict__ wtg,
    const float* __restrict__ bl, const float* __restrict__ br,
    unsigned short* __restrict__ xlb2, float* __restrict__ xr2)
{
    __shared__ float4 xs[64][32];   // 32 KB
    int node0 = blockIdx.x * 64;
    for (int i = threadIdx.x; i < 2048; i += 256) {
        int r = i >> 5, k4 = i & 31;
        int n = node0 + r; if (n > N_NODES - 1) n = N_NODES - 1;
        xs[r][k4] = *(const float4*)&hin[(size_t)n * D1 + k4 * 4];
    }
    __syncthreads();
    int j  = threadIdx.x & 31;
    int r0 = (threadIdx.x >> 5) * 8;
    const float4* __restrict__ wp = (const float4*)wtg;
    float accl[8], accr[8];
#pragma unroll
    for (int r = 0; r < 8; ++r) { accl[r] = 0.f; accr[r] = 0.f; }

    float4 wl_ = wp[j], wr_ = wp[j + 32];

#pragma unroll 2
    for (int k4 = 0; k4 < 32; ++k4) {
        int k4n = (k4 < 31) ? k4 + 1 : 31;
        float4 wln = wp[k4n * 64 + j];
        float4 wrn = wp[k4n * 64 + j + 32];
        float4 xv[8];
#pragma unroll
        for (int r = 0; r < 8; ++r) xv[r] = xs[r0 + r][k4];
#pragma unroll
        for (int r = 0; r < 8; ++r) {
            accl[r] = fmaf(wl_.x, xv[r].x, fmaf(wl_.y, xv[r].y,
                      fmaf(wl_.z, xv[r].z, fmaf(wl_.w, xv[r].w, accl[r]))));
            accr[r] = fmaf(wr_.x, xv[r].x, fmaf(wr_.y, xv[r].y,
                      fmaf(wr_.z, xv[r].z, fmaf(wr_.w, xv[r].w, accr[r]))));
        }
        wl_ = wln; wr_ = wrn;
    }
    float bls = bl[j], brs = br[j];
#pragma unroll
    for (int r = 0; r < 8; ++r) {
        int nn = node0 + r0 + r; if (nn > N_NODES - 1) nn = N_NODES - 1;
        size_t n = (size_t)nn;
        xlb2[n * HID + j] = bf16hi_(accl[r] + bls);
        xr2 [n * HID + j] = accr[r] + brs;
    }
}

// ---------- conv1 fused: wave per node, 2 edges/wave, bf16 ushort4 (8B) gathers ----------
__global__ __launch_bounds__(256) void k_gat1_fused(
    const int* __restrict__ rs, const int* __restrict__ csr_src,
    const unsigned short* __restrict__ xlb, const float* __restrict__ xr,
    const float* __restrict__ att, const float* __restrict__ bias,
    float* __restrict__ hout)
{
    int n = (blockIdx.x * 256 + threadIdx.x) >> 6;
    if (n >= N_NODES) return;
    int lane = threadIdx.x & 63;
    int d0   = lane & 31;
    int half = lane >> 5;
    const ushort4* xlp = (const ushort4*)xlb;
    float4 r = ((const float4*)xr)[(size_t)n * 32 + d0];
    float4 a = ((const float4*)att)[d0];
    float4 l = b2f4_(xlp[(size_t)n * 32 + d0]);
    float sc = lrelu_(l.x + r.x) * a.x + lrelu_(l.y + r.y) * a.y
             + lrelu_(l.z + r.z) * a.z + lrelu_(l.w + r.w) * a.w;
    sc += __shfl_xor(sc, 1);
    sc += __shfl_xor(sc, 2);
    sc += __shfl_xor(sc, 4);
    float ex  = (half == 0) ? __expf(sc) : 0.f;
    float den = ex;
    float4 acc = { ex * l.x, ex * l.y, ex * l.z, ex * l.w };
    int e0 = rs[n], e1 = rs[n + 1];
    int p = e0;
    for (; p + 8 <= e1; p += 8) {
        int    sA[4];
        ushort4 lu[4];
        float4 ll[4];
        float  sb[4];
#pragma unroll
        for (int i = 0; i < 4; ++i) sA[i] = csr_src[p + 2 * i + half];
#pragma unroll
        for (int i = 0; i < 4; ++i) lu[i] = xlp[(size_t)sA[i] * 32 + d0];
#pragma unroll
        for (int i = 0; i < 4; ++i) ll[i] = b2f4_(lu[i]);
#pragma unroll
        for (int i = 0; i < 4; ++i)
            sb[i] = lrelu_(ll[i].x + r.x) * a.x + lrelu_(ll[i].y + r.y) * a.y
                  + lrelu_(ll[i].z + r.z) * a.z + lrelu_(ll[i].w + r.w) * a.w;
#pragma unroll
        for (int i = 0; i < 4; ++i) sb[i] += __shfl_xor(sb[i], 1);
#pragma unroll
        for (int i = 0; i < 4; ++i) sb[i] += __shfl_xor(sb[i], 2);
#pragma unroll
        for (int i = 0; i < 4; ++i) sb[i] += __shfl_xor(sb[i], 4);
#pragma unroll
        for (int i = 0; i < 4; ++i) {
            float exx = __expf(sb[i]);
            den   += exx;
            acc.x += exx * ll[i].x;
            acc.y += exx * ll[i].y;
            acc.z += exx * ll[i].z;
            acc.w += exx * ll[i].w;
        }
    }
    for (; p < e1; p += 2) {
        int  idx = p + half;
        bool v   = idx < e1;
        int  s   = csr_src[v ? idx : e1 - 1];
        float4 ll = b2f4_(xlp[(size_t)s * 32 + d0]);
        float  s1 = lrelu_(ll.x + r.x) * a.x + lrelu_(ll.y + r.y) * a.y
                  + lrelu_(ll.z + r.z) * a.z + lrelu_(ll.w + r.w) * a.w;
        s1 += __shfl_xor(s1, 1);
        s1 += __shfl_xor(s1, 2);
        s1 += __shfl_xor(s1, 4);
        float exx = v ? __expf(s1) : 0.f;
        den   += exx;
        acc.x += exx * ll.x;
        acc.y += exx * ll.y;
        acc.z += exx * ll.z;
        acc.w += exx * ll.w;
    }
    den   += __shfl_xor(den, 32);
    acc.x += __shfl_xor(acc.x, 32);
    acc.y += __shfl_xor(acc.y, 32);
    acc.z += __shfl_xor(acc.z, 32);
    acc.w += __shfl_xor(acc.w, 32);
    if (half == 0) {
        float inv = 1.f / (den + 1e-16f);
        float4 b = ((const float4*)bias)[d0];
        float4 o;
        o.x = elu_(acc.x * inv + b.x);
        o.y = elu_(acc.y * inv + b.y);
        o.z = elu_(acc.z * inv + b.z);
        o.w = elu_(acc.w * inv + b.w);
        ((float4*)hout)[(size_t)n * 32 + d0] = o;   // hout aliases xr: own row only
    }
}

// ---------- conv2 fused: half-wave per node, 4 edges in flight, bf16 gathers ----------
__global__ __launch_bounds__(256) void k_gat2_fused(
    const int* __restrict__ rs, const int* __restrict__ csr_src,
    const unsigned short* __restrict__ xlb2, const float* __restrict__ xr2,
    const float* __restrict__ att, const float* __restrict__ bias,
    float* __restrict__ h2)
{
    int n = (blockIdx.x * 256 + threadIdx.x) >> 5;
    if (n >= N_NODES) return;
    int lane = threadIdx.x & 31;
    int d0   = lane & 7;
    int sub  = lane >> 3;
    const ushort4* xlp = (const ushort4*)xlb2;
    float4 r = ((const float4*)xr2)[(size_t)n * 8 + d0];
    float4 a = ((const float4*)att)[d0];
    float4 l = b2f4_(xlp[(size_t)n * 8 + d0]);
    float sc = lrelu_(l.x + r.x) * a.x + lrelu_(l.y + r.y) * a.y
             + lrelu_(l.z + r.z) * a.z + lrelu_(l.w + r.w) * a.w;
    sc += __shfl_xor(sc, 1);
    sc += __shfl_xor(sc, 2);
    sc += __shfl_xor(sc, 4);
    float ex  = (sub == 0) ? __expf(sc) : 0.f;
    float den = ex;
    float4 acc = { ex * l.x, ex * l.y, ex * l.z, ex * l.w };
    int e0 = rs[n], e1 = rs[n + 1];
    int p = e0;
    for (; p + 16 <= e1; p += 16) {
        int    sA[4];
        ushort4 lu[4];
        float4 ll[4];
        float  sb[4];
#pragma unroll
        for (int i = 0; i < 4; ++i) sA[i] = csr_src[p + 4 * i + sub];
#pragma unroll
        for (int i = 0; i < 4; ++i) lu[i] = xlp[(size_t)sA[i] * 8 + d0];
#pragma unroll
        for (int i = 0; i < 4; ++i) ll[i] = b2f4_(lu[i]);
#pragma unroll
        for (int i = 0; i < 4; ++i)
            sb[i] = lrelu_(ll[i].x + r.x) * a.x + lrelu_(ll[i].y + r.y) * a.y
                  + lrelu_(ll[i].z + r.z) * a.z + lrelu_(ll[i].w + r.w) * a.w;
#pragma unroll
        for (int i = 0; i < 4; ++i) sb[i] += __shfl_xor(sb[i], 1);
#pragma unroll
        for (int i = 0; i < 4; ++i) sb[i] += __shfl_xor(sb[i], 2);
#pragma unroll
        for (int i = 0; i < 4; ++i) sb[i] += __shfl_xor(sb[i], 4);
#pragma unroll
        for (int i = 0; i < 4; ++i) {
            float exx = __expf(sb[i]);
            den   += exx;
            acc.x += exx * ll[i].x;
            acc.y += exx * ll[i].y;
            acc.z += exx * ll[i].z;
            acc.w += exx * ll[i].w;
        }
    }
    for (; p < e1; p += 4) {
        int  idx = p + sub;
        bool v   = idx < e1;
        int  s   = csr_src[v ? idx : e1 - 1];
        float4 ll = b2f4_(xlp[(size_t)s * 8 + d0]);
        float  s1 = lrelu_(ll.x + r.x) * a.x + lrelu_(ll.y + r.y) * a.y
                  + lrelu_(ll.z + r.z) * a.z + lrelu_(ll.w + r.w) * a.w;
        s1 += __shfl_xor(s1, 1);
        s1 += __shfl_xor(s1, 2);
        s1 += __shfl_xor(s1, 4);
        float exx = v ? __expf(s1) : 0.f;
        den   += exx;
        acc.x += exx * ll.x;
        acc.y += exx * ll.y;
        acc.z += exx * ll.z;
        acc.w += exx * ll.w;
    }
    den   += __shfl_xor(den, 8);
    den   += __shfl_xor(den, 16);
    acc.x += __shfl_xor(acc.x, 8);  acc.x += __shfl_xor(acc.x, 16);
    acc.y += __shfl_xor(acc.y, 8);  acc.y += __shfl_xor(acc.y, 16);
    acc.z += __shfl_xor(acc.z, 8);  acc.z += __shfl_xor(acc.z, 16);
    acc.w += __shfl_xor(acc.w, 8);  acc.w += __shfl_xor(acc.w, 16);
    if (sub == 0) {
        float inv = 1.f / (den + 1e-16f);
        float4 b = ((const float4*)bias)[d0];
        float4 o;
        o.x = elu_(acc.x * inv + b.x);
        o.y = elu_(acc.y * inv + b.y);
        o.z = elu_(acc.z * inv + b.z);
        o.w = elu_(acc.w * inv + b.w);
        ((float4*)h2)[(size_t)n * 8 + d0] = o;
    }
}

// ---------- per-graph mean pool + both heads ----------
__global__ __launch_bounds__(256) void k_pool_heads(
    const float* __restrict__ h2, const int* __restrict__ gstart,
    const float* __restrict__ wc, const float* __restrict__ bc,
    const float* __restrict__ wp, const float* __restrict__ bp,
    float* __restrict__ out)
{
    int g  = blockIdx.x;
    int n0 = gstart[g], n1 = gstart[g + 1];
    int c    = threadIdx.x & 31;
    int slot = threadIdx.x >> 5;   // 0..7
    float s = 0.f;
    for (int n = n0 + slot; n < n1; n += 8)
        s += h2[n * HID + c];
    __shared__ float red[8][HID];
    red[slot][c] = s;
    __syncthreads();
    if (slot == 0) {
        float tot = 0.f;
#pragma unroll
        for (int i = 0; i < 8; ++i) tot += red[i][c];
        float cntf = fmaxf((float)(n1 - n0), 1.f);
        float p = tot / cntf;
        float sc = p * wc[c];
        float sp = p * wp[c];
        sc += __shfl_xor(sc, 1);  sp += __shfl_xor(sp, 1);
        sc += __shfl_xor(sc, 2);  sp += __shfl_xor(sp, 2);
        sc += __shfl_xor(sc, 4);  sp += __shfl_xor(sp, 4);
        sc += __shfl_xor(sc, 8);  sp += __shfl_xor(sp, 8);
        sc += __shfl_xor(sc, 16); sp += __shfl_xor(sp, 16);
        if (c == 0) {
            out[g]          = sc + bc[0];
            out[NGRAPH + g] = sp + bp[0];
        }
    }
}

extern "C" void kernel_launch(void* const* d_in, const int* in_sizes, int n_in,
                              void* d_out, int out_size, void* d_ws, size_t ws_size,
                              hipStream_t stream)
{
    const float* x     = (const float*)d_in[0];
    const int*   ei    = (const int*)d_in[1];
    const int*   batch = (const int*)d_in[2];
    const float* w1l   = (const float*)d_in[3];
    const float* b1l   = (const float*)d_in[4];
    const float* w1r   = (const float*)d_in[5];
    const float* b1r   = (const float*)d_in[6];
    const float* att1  = (const float*)d_in[7];
    const float* bias1 = (const float*)d_in[8];
    const float* w2l   = (const float*)d_in[9];
    const float* b2l   = (const float*)d_in[10];
    const float* w2r   = (const float*)d_in[11];
    const float* b2r   = (const float*)d_in[12];
    const float* att2  = (const float*)d_in[13];
    const float* bias2 = (const float*)d_in[14];
    const float* wc    = (const float*)d_in[15];
    const float* bc    = (const float*)d_in[16];
    const float* wp    = (const float*)d_in[17];
    const float* bp    = (const float*)d_in[18];
    float* out = (float*)d_out;

    float* ws   = (float*)d_ws;
    // conv1 phase: xlb (bf16 gathered table); xr1 at +6.4M
    unsigned short* xlb = (unsigned short*)ws;          // 6,400,000 ushorts = 12.8 MB
    float* xr1  = ws + 6400000;       // 6,400,000 floats
    float* hbuf = ws + 6400000;       // ALIASES xr1 (safe: per-wave read-own-row-then-write)
    // conv2 phase (xlb region dead after k_gat1_fused)
    unsigned short* xlb2 = (unsigned short*)ws;         // 1,600,000 ushorts = 3.2 MB
    float* xr2  = ws + 1600000;       // 1,600,000 floats
    float* h2   = ws + 3200000;       // 1,600,000 floats
    // int region (after 12.8M floats)
    int* ibase   = (int*)(ws + 12800000);
    int* deg     = ibase;              //  50,000
    int* rs      = ibase + 50000;      //  50,001
    int* cur     = ibase + 100001;     //  50,000
    int* csr_src = ibase + 150001;     // 800,000
    int* gstart  = ibase + 950001;     //      65
    int* btot    = ibase + 950101;     //      49
    int* boff    = ibase + 950151;     //      49
    // re-laid-out weights: conv1 bf16 hi/lo frag-order, conv2 fp32
    unsigned short* bh1 = (unsigned short*)(ws + 13800000);   // 32768 ushort
    unsigned short* bl1_ = (unsigned short*)(ws + 13816384);  // 32768 ushort
    float* wtg2 = ws + 13840000;       //  8,192 floats

    // ---- fused prep (wtrans1+wtrans2+zero+gbound), then CSR build: 6 dispatches ----
    k_prep<<<747, 256, 0, stream>>>(w1l, w1r, bh1, bl1_, w2l, w2r, wtg2, deg, cur, batch, gstart);
    k_hist<<<(N_EDGES + 255) / 256, 256, 0, stream>>>(ei, deg);
    k_scan_local<<<SCAN_NB, 1024, 0, stream>>>(deg, rs, btot);
    k_scan_btot<<<1, 64, 0, stream>>>(btot, boff);
    k_scan_add<<<SCAN_NB, 1024, 0, stream>>>(rs, boff);
    k_scatter<<<(N_EDGES + 255) / 256, 256, 0, stream>>>(ei, rs, cur, csr_src);

    // ---- conv1 ----
    k_transform1<<<(N_NODES + 63) / 64, 256, 0, stream>>>(x, bh1, bl1_, b1l, b1r, xlb, xr1);
    k_gat1_fused<<<(N_NODES * 64 + 255) / 256, 256, 0, stream>>>(rs, csr_src, xlb, xr1, att1, bias1, hbuf);

    // ---- conv2 ----
    k_transform2<<<(N_NODES + 63) / 64, 256, 0, stream>>>(hbuf, wtg2, b2l, b2r, xlb2, xr2);
    k_gat2_fused<<<(N_NODES * 32 + 255) / 256, 256, 0, stream>>>(rs, csr_src, xlb2, xr2, att2, bias2, h2);

    // ---- pool + heads ----
    k_pool_heads<<<NGRAPH, 256, 0, stream>>>(h2, gstart, wc, bc, wp, bp, out);
}

// Round 10
// 231.727 us; speedup vs baseline: 1.1506x; 1.0199x over previous
//
#include <hip/hip_runtime.h>

#define N_NODES 50000
#define N_EDGES 800000
#define FEATS   128
#define HID     32
#define HEADS   4
#define D1      128      // HEADS*HID
#define NGRAPH  64
#define SCAN_NB ((N_NODES + 1023) / 1024)   // 49
#define NRANGE  8
#define RNODES  (N_NODES / NRANGE)          // 6250
#define ESLICE  8192
#define NSLICE  ((N_EDGES + ESLICE - 1) / ESLICE)   // 98

__device__ __forceinline__ float lrelu_(float v) { return fmaxf(v, 0.2f * v); }
__device__ __forceinline__ float elu_(float v)   { return v > 0.f ? v : __expf(v) - 1.f; }

typedef __attribute__((ext_vector_type(8))) short short8v;
typedef __attribute__((ext_vector_type(4))) float f32x4;

// fp32 -> bf16 (RNE) high part
__device__ __forceinline__ unsigned short bf16hi_(float x) {
    unsigned u = __float_as_uint(x);
    unsigned r = u + 0x7FFFu + ((u >> 16) & 1);
    return (unsigned short)(r >> 16);
}
__device__ __forceinline__ float bf16f_(unsigned short h) {
    return __uint_as_float(((unsigned)h) << 16);
}
__device__ __forceinline__ float4 b2f4_(ushort4 u) {
    float4 f;
    f.x = __uint_as_float(((unsigned)u.x) << 16);
    f.y = __uint_as_float(((unsigned)u.y) << 16);
    f.z = __uint_as_float(((unsigned)u.z) << 16);
    f.w = __uint_as_float(((unsigned)u.w) << 16);
    return f;
}

// ---------- fused prep: wtrans1(bf16 hi/lo) | wtrans2 | zero(deg,cur) | gbound ----------
// block ranges: [0,128) wtrans1, [128,160) wtrans2, [160,551) zero, [551,747) gbound
__global__ __launch_bounds__(256) void k_prep(
    const float* __restrict__ w1l, const float* __restrict__ w1r,
    unsigned short* __restrict__ bh, unsigned short* __restrict__ blo,
    const float* __restrict__ w2l, const float* __restrict__ w2r, float* __restrict__ wtg2,
    int* __restrict__ deg, int* __restrict__ cur,
    const int* __restrict__ batch, int* __restrict__ gstart)
{
    int b = blockIdx.x;
    if (b < 128) {
        int idx = b * 256 + threadIdx.x;            // 32768
        int j    = idx & 7;
        int lane = (idx >> 3) & 63;
        int ks   = (idx >> 9) & 3;
        int nfg  = idx >> 11;                       // 0..15
        int col  = nfg * 16 + (lane & 15);
        int k    = ks * 32 + ((lane >> 4) & 3) * 8 + j;
        float wv = (col < 128) ? w1l[col * FEATS + k] : w1r[(col - 128) * FEATS + k];
        unsigned short h = bf16hi_(wv);
        float lo = wv - bf16f_(h);
        bh[idx]  = h;
        blo[idx] = bf16hi_(lo);
    } else if (b < 160) {
        int idx = (b - 128) * 256 + threadIdx.x;    // 8192
        int kk = idx & 3, j = (idx >> 2) & 63, k4 = idx >> 8;
        int k = k4 * 4 + kk;
        wtg2[idx] = (j < 32) ? w2l[j * D1 + k] : w2r[(j - 32) * D1 + k];
    } else if (b < 551) {
        int i = (b - 160) * 256 + threadIdx.x;      // 100000
        if (i < N_NODES) deg[i] = 0;
        else if (i < 2 * N_NODES) cur[i - N_NODES] = 0;
    } else {
        int i = (b - 551) * 256 + threadIdx.x;      // 50001
        if (i > N_NODES) return;
        int bb   = (i < N_NODES) ? batch[i] : NGRAPH;
        int prev = (i == 0) ? -1 : batch[i - 1];
        for (int g = prev + 1; g <= bb; ++g) gstart[g] = i;
    }
}

// ---------- CSR build: XCD-partitioned histogram ----------
// block handles edge-slice (bid>>3), commits only dst in range (bid&7)*RNODES..+RNODES.
// With round-robin block->XCD placement, each deg line is touched by ONE XCD's L2.
__global__ __launch_bounds__(256) void k_hist(const int* __restrict__ ei, int* __restrict__ deg)
{
    int range = blockIdx.x & 7;
    int sid   = blockIdx.x >> 3;
    int lo = range * RNODES, hi = lo + RNODES;
    int base = sid * ESLICE;
    int end  = base + ESLICE; if (end > N_EDGES) end = N_EDGES;
    for (int e = base + threadIdx.x; e < end; e += 256) {
        int d = ei[N_EDGES + e];
        if (d >= lo && d < hi) atomicAdd(&deg[d], 1);
    }
}

__global__ __launch_bounds__(1024) void k_scan_local(
    const int* __restrict__ deg, int* __restrict__ rs, int* __restrict__ btot)
{
    __shared__ int sm[1024];
    int idx = blockIdx.x * 1024 + threadIdx.x;
    int v = (idx < N_NODES) ? deg[idx] : 0;
    sm[threadIdx.x] = v;
    __syncthreads();
    for (int off = 1; off < 1024; off <<= 1) {
        int t = (threadIdx.x >= off) ? sm[threadIdx.x - off] : 0;
        __syncthreads();
        sm[threadIdx.x] += t;
        __syncthreads();
    }
    if (idx < N_NODES) rs[idx] = sm[threadIdx.x] - v;   // exclusive
    if (threadIdx.x == 1023) btot[blockIdx.x] = sm[1023];
}

__global__ __launch_bounds__(64) void k_scan_btot(
    const int* __restrict__ btot, int* __restrict__ boff)
{
    int t = threadIdx.x;
    int own = (t < SCAN_NB) ? btot[t] : 0;
    int v = own;
    for (int off = 1; off < 64; off <<= 1) {
        int u = __shfl_up(v, off);
        if (t >= off) v += u;
    }
    if (t < SCAN_NB) boff[t] = v - own;   // exclusive
}

__global__ __launch_bounds__(1024) void k_scan_add(
    int* __restrict__ rs, const int* __restrict__ boff)
{
    int idx = blockIdx.x * 1024 + threadIdx.x;
    if (idx < N_NODES) rs[idx] += boff[blockIdx.x];
    if (idx == N_NODES) rs[N_NODES] = N_EDGES;
}

// ---------- XCD-partitioned scatter: csr_src/cur lines stay in one XCD's L2 ----------
__global__ __launch_bounds__(256) void k_scatter(const int* __restrict__ ei,
                                                const int* __restrict__ rs,
                                                int* __restrict__ cur,
                                                int* __restrict__ csr_src)
{
    int range = blockIdx.x & 7;
    int sid   = blockIdx.x >> 3;
    int lo = range * RNODES, hi = lo + RNODES;
    int base = sid * ESLICE;
    int end  = base + ESLICE; if (end > N_EDGES) end = N_EDGES;
    for (int e = base + threadIdx.x; e < end; e += 256) {
        int d = ei[N_EDGES + e];
        if (d >= lo && d < hi) {
            int p = rs[d] + atomicAdd(&cur[d], 1);
            csr_src[p] = ei[e];
        }
    }
}

// ---------- conv1 transform: MFMA bf16x3, 64 rows/block, wave owns 64 cols ----------
__global__ __launch_bounds__(256) void k_transform1(
    const float* __restrict__ x,
    const unsigned short* __restrict__ bh1, const unsigned short* __restrict__ bl1,
    const float* __restrict__ bl, const float* __restrict__ br,
    unsigned short* __restrict__ xlb, float* __restrict__ xr)
{
    __shared__ unsigned short XH[64 * 136];   // 17.4 KB
    __shared__ unsigned short XL[64 * 136];   // 17.4 KB
    int m0 = blockIdx.x * 64;
    for (int i = threadIdx.x; i < 2048; i += 256) {      // 64 rows x 32 float4
        int r = i >> 5, c4 = i & 31;
        int n = m0 + r; if (n > N_NODES - 1) n = N_NODES - 1;   // tail clamp (benign dup)
        float4 v = *(const float4*)&x[(size_t)n * FEATS + c4 * 4];
        ushort4 h, lo;
        h.x = bf16hi_(v.x); lo.x = bf16hi_(v.x - bf16f_(h.x));
        h.y = bf16hi_(v.y); lo.y = bf16hi_(v.y - bf16f_(h.y));
        h.z = bf16hi_(v.z); lo.z = bf16hi_(v.z - bf16f_(h.z));
        h.w = bf16hi_(v.w); lo.w = bf16hi_(v.w - bf16f_(h.w));
        *(ushort4*)&XH[r * 136 + c4 * 4] = h;
        *(ushort4*)&XL[r * 136 + c4 * 4] = lo;
    }
    __syncthreads();

    int l  = threadIdx.x & 63;
    int wq = threadIdx.x >> 6;          // wave id = col-quadrant (64 cols)
    int lr = l & 15;
    int lk = (l >> 4) & 3;

    f32x4 acc[4][4];
#pragma unroll
    for (int m = 0; m < 4; ++m)
#pragma unroll
        for (int n = 0; n < 4; ++n)
#pragma unroll
            for (int g = 0; g < 4; ++g) acc[m][n][g] = 0.f;

    const short8v* bhp = (const short8v*)bh1;
    const short8v* blp = (const short8v*)bl1;

#pragma unroll
    for (int ks = 0; ks < 4; ++ks) {
        short8v bh[4], bw[4], ah[4], al[4];
#pragma unroll
        for (int nf = 0; nf < 4; ++nf) {
            int fidx = (((wq * 4 + nf) * 4 + ks) * 64) + l;
            bh[nf] = bhp[fidx];
            bw[nf] = blp[fidx];
        }
#pragma unroll
        for (int mf = 0; mf < 4; ++mf) {
            int off = (mf * 16 + lr) * 136 + ks * 32 + lk * 8;
            ah[mf] = *(const short8v*)&XH[off];
            al[mf] = *(const short8v*)&XL[off];
        }
#pragma unroll
        for (int mf = 0; mf < 4; ++mf)
#pragma unroll
            for (int nf = 0; nf < 4; ++nf) {
                acc[mf][nf] = __builtin_amdgcn_mfma_f32_16x16x32_bf16(ah[mf], bh[nf], acc[mf][nf], 0, 0, 0);
                acc[mf][nf] = __builtin_amdgcn_mfma_f32_16x16x32_bf16(ah[mf], bw[nf], acc[mf][nf], 0, 0, 0);
                acc[mf][nf] = __builtin_amdgcn_mfma_f32_16x16x32_bf16(al[mf], bh[nf], acc[mf][nf], 0, 0, 0);
            }
    }

    // epilogue: D col = lane&15, row = (lane>>4)*4 + reg
#pragma unroll
    for (int nf = 0; nf < 4; ++nf) {
        int col = wq * 64 + nf * 16 + lr;
        float bv = (col < 128) ? bl[col] : br[col - 128];
#pragma unroll
        for (int mf = 0; mf < 4; ++mf)
#pragma unroll
            for (int g = 0; g < 4; ++g) {
                int row = m0 + mf * 16 + lk * 4 + g;
                if (row > N_NODES - 1) row = N_NODES - 1;    // benign dup (same values)
                float v = acc[mf][nf][g] + bv;
                if (col < 128) xlb[(size_t)row * 128 + col] = bf16hi_(v);
                else           xr [(size_t)row * D1 + (col - 128)] = v;
            }
    }
}

// ---------- conv2 transform: 64 nodes/block, 8 nodes/thread, 2 cols/thread ----------
__global__ __launch_bounds__(256, 2) void k_transform2(
    const float* __restrict__ hin, const float* __restrict__ wtg,
    const float* __restrict__ bl, const float* __restrict__ br,
    unsigned short* __restrict__ xlb2, float* __restrict__ xr2)
{
    __shared__ float4 xs[64][32];   // 32 KB
    int node0 = blockIdx.x * 64;
    for (int i = threadIdx.x; i < 2048; i += 256) {
        int r = i >> 5, k4 = i & 31;
        int n = node0 + r; if (n > N_NODES - 1) n = N_NODES - 1;
        xs[r][k4] = *(const float4*)&hin[(size_t)n * D1 + k4 * 4];
    }
    __syncthreads();
    int j  = threadIdx.x & 31;
    int r0 = (threadIdx.x >> 5) * 8;
    const float4* __restrict__ wp = (const float4*)wtg;
    float accl[8], accr[8];
#pragma unroll
    for (int r = 0; r < 8; ++r) { accl[r] = 0.f; accr[r] = 0.f; }

    float4 wl_ = wp[j], wr_ = wp[j + 32];

#pragma unroll 2
    for (int k4 = 0; k4 < 32; ++k4) {
        int k4n = (k4 < 31) ? k4 + 1 : 31;
        float4 wln = wp[k4n * 64 + j];
        float4 wrn = wp[k4n * 64 + j + 32];
        float4 xv[8];
#pragma unroll
        for (int r = 0; r < 8; ++r) xv[r] = xs[r0 + r][k4];
#pragma unroll
        for (int r = 0; r < 8; ++r) {
            accl[r] = fmaf(wl_.x, xv[r].x, fmaf(wl_.y, xv[r].y,
                      fmaf(wl_.z, xv[r].z, fmaf(wl_.w, xv[r].w, accl[r]))));
            accr[r] = fmaf(wr_.x, xv[r].x, fmaf(wr_.y, xv[r].y,
                      fmaf(wr_.z, xv[r].z, fmaf(wr_.w, xv[r].w, accr[r]))));
        }
        wl_ = wln; wr_ = wrn;
    }
    float bls = bl[j], brs = br[j];
#pragma unroll
    for (int r = 0; r < 8; ++r) {
        int nn = node0 + r0 + r; if (nn > N_NODES - 1) nn = N_NODES - 1;
        size_t n = (size_t)nn;
        xlb2[n * HID + j] = bf16hi_(accl[r] + bls);
        xr2 [n * HID + j] = accr[r] + brs;
    }
}

// ---------- conv1 fused: wave per node, 2 edges/wave, bf16 ushort4 (8B) gathers ----------
__global__ __launch_bounds__(256) void k_gat1_fused(
    const int* __restrict__ rs, const int* __restrict__ csr_src,
    const unsigned short* __restrict__ xlb, const float* __restrict__ xr,
    const float* __restrict__ att, const float* __restrict__ bias,
    float* __restrict__ hout)
{
    int n = (blockIdx.x * 256 + threadIdx.x) >> 6;
    if (n >= N_NODES) return;
    int lane = threadIdx.x & 63;
    int d0   = lane & 31;
    int half = lane >> 5;
    const ushort4* xlp = (const ushort4*)xlb;
    float4 r = ((const float4*)xr)[(size_t)n * 32 + d0];
    float4 a = ((const float4*)att)[d0];
    float4 l = b2f4_(xlp[(size_t)n * 32 + d0]);
    float sc = lrelu_(l.x + r.x) * a.x + lrelu_(l.y + r.y) * a.y
             + lrelu_(l.z + r.z) * a.z + lrelu_(l.w + r.w) * a.w;
    sc += __shfl_xor(sc, 1);
    sc += __shfl_xor(sc, 2);
    sc += __shfl_xor(sc, 4);
    float ex  = (half == 0) ? __expf(sc) : 0.f;
    float den = ex;
    float4 acc = { ex * l.x, ex * l.y, ex * l.z, ex * l.w };
    int e0 = rs[n], e1 = rs[n + 1];
    int p = e0;
    for (; p + 8 <= e1; p += 8) {
        int    sA[4];
        ushort4 lu[4];
        float4 ll[4];
        float  sb[4];
#pragma unroll
        for (int i = 0; i < 4; ++i) sA[i] = csr_src[p + 2 * i + half];
#pragma unroll
        for (int i = 0; i < 4; ++i) lu[i] = xlp[(size_t)sA[i] * 32 + d0];
#pragma unroll
        for (int i = 0; i < 4; ++i) ll[i] = b2f4_(lu[i]);
#pragma unroll
        for (int i = 0; i < 4; ++i)
            sb[i] = lrelu_(ll[i].x + r.x) * a.x + lrelu_(ll[i].y + r.y) * a.y
                  + lrelu_(ll[i].z + r.z) * a.z + lrelu_(ll[i].w + r.w) * a.w;
#pragma unroll
        for (int i = 0; i < 4; ++i) sb[i] += __shfl_xor(sb[i], 1);
#pragma unroll
        for (int i = 0; i < 4; ++i) sb[i] += __shfl_xor(sb[i], 2);
#pragma unroll
        for (int i = 0; i < 4; ++i) sb[i] += __shfl_xor(sb[i], 4);
#pragma unroll
        for (int i = 0; i < 4; ++i) {
            float exx = __expf(sb[i]);
            den   += exx;
            acc.x += exx * ll[i].x;
            acc.y += exx * ll[i].y;
            acc.z += exx * ll[i].z;
            acc.w += exx * ll[i].w;
        }
    }
    for (; p < e1; p += 2) {
        int  idx = p + half;
        bool v   = idx < e1;
        int  s   = csr_src[v ? idx : e1 - 1];
        float4 ll = b2f4_(xlp[(size_t)s * 32 + d0]);
        float  s1 = lrelu_(ll.x + r.x) * a.x + lrelu_(ll.y + r.y) * a.y
                  + lrelu_(ll.z + r.z) * a.z + lrelu_(ll.w + r.w) * a.w;
        s1 += __shfl_xor(s1, 1);
        s1 += __shfl_xor(s1, 2);
        s1 += __shfl_xor(s1, 4);
        float exx = v ? __expf(s1) : 0.f;
        den   += exx;
        acc.x += exx * ll.x;
        acc.y += exx * ll.y;
        acc.z += exx * ll.z;
        acc.w += exx * ll.w;
    }
    den   += __shfl_xor(den, 32);
    acc.x += __shfl_xor(acc.x, 32);
    acc.y += __shfl_xor(acc.y, 32);
    acc.z += __shfl_xor(acc.z, 32);
    acc.w += __shfl_xor(acc.w, 32);
    if (half == 0) {
        float inv = 1.f / (den + 1e-16f);
        float4 b = ((const float4*)bias)[d0];
        float4 o;
        o.x = elu_(acc.x * inv + b.x);
        o.y = elu_(acc.y * inv + b.y);
        o.z = elu_(acc.z * inv + b.z);
        o.w = elu_(acc.w * inv + b.w);
        ((float4*)hout)[(size_t)n * 32 + d0] = o;   // hout aliases xr: own row only
    }
}

// ---------- conv2 fused: half-wave per node, 4 edges in flight, bf16 gathers ----------
__global__ __launch_bounds__(256) void k_gat2_fused(
    const int* __restrict__ rs, const int* __restrict__ csr_src,
    const unsigned short* __restrict__ xlb2, const float* __restrict__ xr2,
    const float* __restrict__ att, const float* __restrict__ bias,
    float* __restrict__ h2)
{
    int n = (blockIdx.x * 256 + threadIdx.x) >> 5;
    if (n >= N_NODES) return;
    int lane = threadIdx.x & 31;
    int d0   = lane & 7;
    int sub  = lane >> 3;
    const ushort4* xlp = (const ushort4*)xlb2;
    float4 r = ((const float4*)xr2)[(size_t)n * 8 + d0];
    float4 a = ((const float4*)att)[d0];
    float4 l = b2f4_(xlp[(size_t)n * 8 + d0]);
    float sc = lrelu_(l.x + r.x) * a.x + lrelu_(l.y + r.y) * a.y
             + lrelu_(l.z + r.z) * a.z + lrelu_(l.w + r.w) * a.w;
    sc += __shfl_xor(sc, 1);
    sc += __shfl_xor(sc, 2);
    sc += __shfl_xor(sc, 4);
    float ex  = (sub == 0) ? __expf(sc) : 0.f;
    float den = ex;
    float4 acc = { ex * l.x, ex * l.y, ex * l.z, ex * l.w };
    int e0 = rs[n], e1 = rs[n + 1];
    int p = e0;
    for (; p + 16 <= e1; p += 16) {
        int    sA[4];
        ushort4 lu[4];
        float4 ll[4];
        float  sb[4];
#pragma unroll
        for (int i = 0; i < 4; ++i) sA[i] = csr_src[p + 4 * i + sub];
#pragma unroll
        for (int i = 0; i < 4; ++i) lu[i] = xlp[(size_t)sA[i] * 8 + d0];
#pragma unroll
        for (int i = 0; i < 4; ++i) ll[i] = b2f4_(lu[i]);
#pragma unroll
        for (int i = 0; i < 4; ++i)
            sb[i] = lrelu_(ll[i].x + r.x) * a.x + lrelu_(ll[i].y + r.y) * a.y
                  + lrelu_(ll[i].z + r.z) * a.z + lrelu_(ll[i].w + r.w) * a.w;
#pragma unroll
        for (int i = 0; i < 4; ++i) sb[i] += __shfl_xor(sb[i], 1);
#pragma unroll
        for (int i = 0; i < 4; ++i) sb[i] += __shfl_xor(sb[i], 2);
#pragma unroll
        for (int i = 0; i < 4; ++i) sb[i] += __shfl_xor(sb[i], 4);
#pragma unroll
        for (int i = 0; i < 4; ++i) {
            float exx = __expf(sb[i]);
            den   += exx;
            acc.x += exx * ll[i].x;
            acc.y += exx * ll[i].y;
            acc.z += exx * ll[i].z;
            acc.w += exx * ll[i].w;
        }
    }
    for (; p < e1; p += 4) {
        int  idx = p + sub;
        bool v   = idx < e1;
        int  s   = csr_src[v ? idx : e1 - 1];
        float4 ll = b2f4_(xlp[(size_t)s * 8 + d0]);
        float  s1 = lrelu_(ll.x + r.x) * a.x + lrelu_(ll.y + r.y) * a.y
                  + lrelu_(ll.z + r.z) * a.z + lrelu_(ll.w + r.w) * a.w;
        s1 += __shfl_xor(s1, 1);
        s1 += __shfl_xor(s1, 2);
        s1 += __shfl_xor(s1, 4);
        float exx = v ? __expf(s1) : 0.f;
        den   += exx;
        acc.x += exx * ll.x;
        acc.y += exx * ll.y;
        acc.z += exx * ll.z;
        acc.w += exx * ll.w;
    }
    den   += __shfl_xor(den, 8);
    den   += __shfl_xor(den, 16);
    acc.x += __shfl_xor(acc.x, 8);  acc.x += __shfl_xor(acc.x, 16);
    acc.y += __shfl_xor(acc.y, 8);  acc.y += __shfl_xor(acc.y, 16);
    acc.z += __shfl_xor(acc.z, 8);  acc.z += __shfl_xor(acc.z, 16);
    acc.w += __shfl_xor(acc.w, 8);  acc.w += __shfl_xor(acc.w, 16);
    if (sub == 0) {
        float inv = 1.f / (den + 1e-16f);
        float4 b = ((const float4*)bias)[d0];
        float4 o;
        o.x = elu_(acc.x * inv + b.x);
        o.y = elu_(acc.y * inv + b.y);
        o.z = elu_(acc.z * inv + b.z);
        o.w = elu_(acc.w * inv + b.w);
        ((float4*)h2)[(size_t)n * 8 + d0] = o;
    }
}

// ---------- per-graph mean pool + both heads ----------
__global__ __launch_bounds__(256) void k_pool_heads(
    const float* __restrict__ h2, const int* __restrict__ gstart,
    const float* __restrict__ wc, const float* __restrict__ bc,
    const float* __restrict__ wp, const float* __restrict__ bp,
    float* __restrict__ out)
{
    int g  = blockIdx.x;
    int n0 = gstart[g], n1 = gstart[g + 1];
    int c    = threadIdx.x & 31;
    int slot = threadIdx.x >> 5;   // 0..7
    float s = 0.f;
    for (int n = n0 + slot; n < n1; n += 8)
        s += h2[n * HID + c];
    __shared__ float red[8][HID];
    red[slot][c] = s;
    __syncthreads();
    if (slot == 0) {
        float tot = 0.f;
#pragma unroll
        for (int i = 0; i < 8; ++i) tot += red[i][c];
        float cntf = fmaxf((float)(n1 - n0), 1.f);
        float p = tot / cntf;
        float sc = p * wc[c];
        float sp = p * wp[c];
        sc += __shfl_xor(sc, 1);  sp += __shfl_xor(sp, 1);
        sc += __shfl_xor(sc, 2);  sp += __shfl_xor(sp, 2);
        sc += __shfl_xor(sc, 4);  sp += __shfl_xor(sp, 4);
        sc += __shfl_xor(sc, 8);  sp += __shfl_xor(sp, 8);
        sc += __shfl_xor(sc, 16); sp += __shfl_xor(sp, 16);
        if (c == 0) {
            out[g]          = sc + bc[0];
            out[NGRAPH + g] = sp + bp[0];
        }
    }
}

extern "C" void kernel_launch(void* const* d_in, const int* in_sizes, int n_in,
                              void* d_out, int out_size, void* d_ws, size_t ws_size,
                              hipStream_t stream)
{
    const float* x     = (const float*)d_in[0];
    const int*   ei    = (const int*)d_in[1];
    const int*   batch = (const int*)d_in[2];
    const float* w1l   = (const float*)d_in[3];
    const float* b1l   = (const float*)d_in[4];
    const float* w1r   = (const float*)d_in[5];
    const float* b1r   = (const float*)d_in[6];
    const float* att1  = (const float*)d_in[7];
    const float* bias1 = (const float*)d_in[8];
    const float* w2l   = (const float*)d_in[9];
    const float* b2l   = (const float*)d_in[10];
    const float* w2r   = (const float*)d_in[11];
    const float* b2r   = (const float*)d_in[12];
    const float* att2  = (const float*)d_in[13];
    const float* bias2 = (const float*)d_in[14];
    const float* wc    = (const float*)d_in[15];
    const float* bc    = (const float*)d_in[16];
    const float* wp    = (const float*)d_in[17];
    const float* bp    = (const float*)d_in[18];
    float* out = (float*)d_out;

    float* ws   = (float*)d_ws;
    // conv1 phase: xlb (bf16 gathered table); xr1 at +6.4M
    unsigned short* xlb = (unsigned short*)ws;          // 6,400,000 ushorts = 12.8 MB
    float* xr1  = ws + 6400000;       // 6,400,000 floats
    float* hbuf = ws + 6400000;       // ALIASES xr1 (safe: per-wave read-own-row-then-write)
    // conv2 phase (xlb region dead after k_gat1_fused)
    unsigned short* xlb2 = (unsigned short*)ws;         // 1,600,000 ushorts = 3.2 MB
    float* xr2  = ws + 1600000;       // 1,600,000 floats
    float* h2   = ws + 3200000;       // 1,600,000 floats
    // int region (after 12.8M floats)
    int* ibase   = (int*)(ws + 12800000);
    int* deg     = ibase;              //  50,000
    int* rs      = ibase + 50000;      //  50,001
    int* cur     = ibase + 100001;     //  50,000
    int* csr_src = ibase + 150001;     // 800,000
    int* gstart  = ibase + 950001;     //      65
    int* btot    = ibase + 950101;     //      49
    int* boff    = ibase + 950151;     //      49
    // re-laid-out weights: conv1 bf16 hi/lo frag-order, conv2 fp32
    unsigned short* bh1 = (unsigned short*)(ws + 13800000);   // 32768 ushort
    unsigned short* bl1_ = (unsigned short*)(ws + 13816384);  // 32768 ushort
    float* wtg2 = ws + 13840000;       //  8,192 floats

    // ---- fused prep, then XCD-partitioned CSR build ----
    k_prep<<<747, 256, 0, stream>>>(w1l, w1r, bh1, bl1_, w2l, w2r, wtg2, deg, cur, batch, gstart);
    k_hist<<<NRANGE * NSLICE, 256, 0, stream>>>(ei, deg);
    k_scan_local<<<SCAN_NB, 1024, 0, stream>>>(deg, rs, btot);
    k_scan_btot<<<1, 64, 0, stream>>>(btot, boff);
    k_scan_add<<<SCAN_NB, 1024, 0, stream>>>(rs, boff);
    k_scatter<<<NRANGE * NSLICE, 256, 0, stream>>>(ei, rs, cur, csr_src);

    // ---- conv1 ----
    k_transform1<<<(N_NODES + 63) / 64, 256, 0, stream>>>(x, bh1, bl1_, b1l, b1r, xlb, xr1);
    k_gat1_fused<<<(N_NODES * 64 + 255) / 256, 256, 0, stream>>>(rs, csr_src, xlb, xr1, att1, bias1, hbuf);

    // ---- conv2 ----
    k_transform2<<<(N_NODES + 63) / 64, 256, 0, stream>>>(hbuf, wtg2, b2l, b2r, xlb2, xr2);
    k_gat2_fused<<<(N_NODES * 32 + 255) / 256, 256, 0, stream>>>(rs, csr_src, xlb2, xr2, att2, bias2, h2);

    // ---- pool + heads ----
    k_pool_heads<<<NGRAPH, 256, 0, stream>>>(h2, gstart, wc, bc, wp, bp, out);
}

// Round 11
// 204.562 us; speedup vs baseline: 1.3034x; 1.1328x over previous
//
#include <hip/hip_runtime.h>

#define N_NODES 50000
#define N_EDGES 800000
#define FEATS   128
#define HID     32
#define HEADS   4
#define D1      128      // HEADS*HID
#define NGRAPH  64
#define SCAN_NB ((N_NODES + 1023) / 1024)   // 49

__device__ __forceinline__ float lrelu_(float v) { return fmaxf(v, 0.2f * v); }
__device__ __forceinline__ float elu_(float v)   { return v > 0.f ? v : __expf(v) - 1.f; }

typedef __attribute__((ext_vector_type(8))) short short8v;
typedef __attribute__((ext_vector_type(4))) float f32x4;

// fp32 -> bf16 (RNE) high part
__device__ __forceinline__ unsigned short bf16hi_(float x) {
    unsigned u = __float_as_uint(x);
    unsigned r = u + 0x7FFFu + ((u >> 16) & 1);
    return (unsigned short)(r >> 16);
}
__device__ __forceinline__ float bf16f_(unsigned short h) {
    return __uint_as_float(((unsigned)h) << 16);
}
__device__ __forceinline__ float4 b2f4_(ushort4 u) {
    float4 f;
    f.x = __uint_as_float(((unsigned)u.x) << 16);
    f.y = __uint_as_float(((unsigned)u.y) << 16);
    f.z = __uint_as_float(((unsigned)u.z) << 16);
    f.w = __uint_as_float(((unsigned)u.w) << 16);
    return f;
}

// ---------- fused prep: wtrans1(bf16 hi/lo) | wtrans2 | zero(deg) | gbound ----------
// block ranges: [0,128) wtrans1, [128,160) wtrans2, [160,356) zero deg, [356,552) gbound
__global__ __launch_bounds__(256) void k_prep(
    const float* __restrict__ w1l, const float* __restrict__ w1r,
    unsigned short* __restrict__ bh, unsigned short* __restrict__ blo,
    const float* __restrict__ w2l, const float* __restrict__ w2r, float* __restrict__ wtg2,
    int* __restrict__ deg,
    const int* __restrict__ batch, int* __restrict__ gstart)
{
    int b = blockIdx.x;
    if (b < 128) {
        int idx = b * 256 + threadIdx.x;            // 32768
        int j    = idx & 7;
        int lane = (idx >> 3) & 63;
        int ks   = (idx >> 9) & 3;
        int nfg  = idx >> 11;                       // 0..15
        int col  = nfg * 16 + (lane & 15);
        int k    = ks * 32 + ((lane >> 4) & 3) * 8 + j;
        float wv = (col < 128) ? w1l[col * FEATS + k] : w1r[(col - 128) * FEATS + k];
        unsigned short h = bf16hi_(wv);
        float lo = wv - bf16f_(h);
        bh[idx]  = h;
        blo[idx] = bf16hi_(lo);
    } else if (b < 160) {
        int idx = (b - 128) * 256 + threadIdx.x;    // 8192
        int kk = idx & 3, j = (idx >> 2) & 63, k4 = idx >> 8;
        int k = k4 * 4 + kk;
        wtg2[idx] = (j < 32) ? w2l[j * D1 + k] : w2r[(j - 32) * D1 + k];
    } else if (b < 356) {
        int i = (b - 160) * 256 + threadIdx.x;      // 50176 >= 50000
        if (i < N_NODES) deg[i] = 0;
    } else {
        int i = (b - 356) * 256 + threadIdx.x;      // 50001
        if (i > N_NODES) return;
        int bb   = (i < N_NODES) ? batch[i] : NGRAPH;
        int prev = (i == 0) ? -1 : batch[i - 1];
        for (int g = prev + 1; g <= bb; ++g) gstart[g] = i;
    }
}

// ---------- CSR build: hist captures per-edge rank (counting-sort key) ----------
__global__ __launch_bounds__(256) void k_hist(const int* __restrict__ ei,
                                              int* __restrict__ deg,
                                              int* __restrict__ rank)
{
    int e = blockIdx.x * 256 + threadIdx.x;
    if (e < N_EDGES) rank[e] = atomicAdd(&deg[ei[N_EDGES + e]], 1);
}

__global__ __launch_bounds__(1024) void k_scan_local(
    const int* __restrict__ deg, int* __restrict__ rs, int* __restrict__ btot)
{
    __shared__ int sm[1024];
    int idx = blockIdx.x * 1024 + threadIdx.x;
    int v = (idx < N_NODES) ? deg[idx] : 0;
    sm[threadIdx.x] = v;
    __syncthreads();
    for (int off = 1; off < 1024; off <<= 1) {
        int t = (threadIdx.x >= off) ? sm[threadIdx.x - off] : 0;
        __syncthreads();
        sm[threadIdx.x] += t;
        __syncthreads();
    }
    if (idx < N_NODES) rs[idx] = sm[threadIdx.x] - v;   // exclusive
    if (threadIdx.x == 1023) btot[blockIdx.x] = sm[1023];
}

__global__ __launch_bounds__(64) void k_scan_btot(
    const int* __restrict__ btot, int* __restrict__ boff)
{
    int t = threadIdx.x;
    int own = (t < SCAN_NB) ? btot[t] : 0;
    int v = own;
    for (int off = 1; off < 64; off <<= 1) {
        int u = __shfl_up(v, off);
        if (t >= off) v += u;
    }
    if (t < SCAN_NB) boff[t] = v - own;   // exclusive
}

__global__ __launch_bounds__(1024) void k_scan_add(
    int* __restrict__ rs, const int* __restrict__ boff)
{
    int idx = blockIdx.x * 1024 + threadIdx.x;
    if (idx < N_NODES) rs[idx] += boff[blockIdx.x];
    if (idx == N_NODES) rs[N_NODES] = N_EDGES;
}

// ---------- scatter: NO atomics — position = rs[dst] + rank[e] (fire-and-forget store) ----------
__global__ __launch_bounds__(256) void k_scatter(const int* __restrict__ ei,
                                                const int* __restrict__ rs,
                                                const int* __restrict__ rank,
                                                int* __restrict__ csr_src)
{
    int e = blockIdx.x * 256 + threadIdx.x;
    if (e >= N_EDGES) return;
    int d = ei[N_EDGES + e];
    csr_src[rs[d] + rank[e]] = ei[e];
}

// ---------- conv1 transform: MFMA bf16x3, 64 rows/block, wave owns 64 cols ----------
__global__ __launch_bounds__(256) void k_transform1(
    const float* __restrict__ x,
    const unsigned short* __restrict__ bh1, const unsigned short* __restrict__ bl1,
    const float* __restrict__ bl, const float* __restrict__ br,
    unsigned short* __restrict__ xlb, float* __restrict__ xr)
{
    __shared__ unsigned short XH[64 * 136];   // 17.4 KB
    __shared__ unsigned short XL[64 * 136];   // 17.4 KB
    int m0 = blockIdx.x * 64;
    for (int i = threadIdx.x; i < 2048; i += 256) {      // 64 rows x 32 float4
        int r = i >> 5, c4 = i & 31;
        int n = m0 + r; if (n > N_NODES - 1) n = N_NODES - 1;   // tail clamp (benign dup)
        float4 v = *(const float4*)&x[(size_t)n * FEATS + c4 * 4];
        ushort4 h, lo;
        h.x = bf16hi_(v.x); lo.x = bf16hi_(v.x - bf16f_(h.x));
        h.y = bf16hi_(v.y); lo.y = bf16hi_(v.y - bf16f_(h.y));
        h.z = bf16hi_(v.z); lo.z = bf16hi_(v.z - bf16f_(h.z));
        h.w = bf16hi_(v.w); lo.w = bf16hi_(v.w - bf16f_(h.w));
        *(ushort4*)&XH[r * 136 + c4 * 4] = h;
        *(ushort4*)&XL[r * 136 + c4 * 4] = lo;
    }
    __syncthreads();

    int l  = threadIdx.x & 63;
    int wq = threadIdx.x >> 6;          // wave id = col-quadrant (64 cols)
    int lr = l & 15;
    int lk = (l >> 4) & 3;

    f32x4 acc[4][4];
#pragma unroll
    for (int m = 0; m < 4; ++m)
#pragma unroll
        for (int n = 0; n < 4; ++n)
#pragma unroll
            for (int g = 0; g < 4; ++g) acc[m][n][g] = 0.f;

    const short8v* bhp = (const short8v*)bh1;
    const short8v* blp = (const short8v*)bl1;

#pragma unroll
    for (int ks = 0; ks < 4; ++ks) {
        short8v bh[4], bw[4], ah[4], al[4];
#pragma unroll
        for (int nf = 0; nf < 4; ++nf) {
            int fidx = (((wq * 4 + nf) * 4 + ks) * 64) + l;
            bh[nf] = bhp[fidx];
            bw[nf] = blp[fidx];
        }
#pragma unroll
        for (int mf = 0; mf < 4; ++mf) {
            int off = (mf * 16 + lr) * 136 + ks * 32 + lk * 8;
            ah[mf] = *(const short8v*)&XH[off];
            al[mf] = *(const short8v*)&XL[off];
        }
#pragma unroll
        for (int mf = 0; mf < 4; ++mf)
#pragma unroll
            for (int nf = 0; nf < 4; ++nf) {
                acc[mf][nf] = __builtin_amdgcn_mfma_f32_16x16x32_bf16(ah[mf], bh[nf], acc[mf][nf], 0, 0, 0);
                acc[mf][nf] = __builtin_amdgcn_mfma_f32_16x16x32_bf16(ah[mf], bw[nf], acc[mf][nf], 0, 0, 0);
                acc[mf][nf] = __builtin_amdgcn_mfma_f32_16x16x32_bf16(al[mf], bh[nf], acc[mf][nf], 0, 0, 0);
            }
    }

    // epilogue: D col = lane&15, row = (lane>>4)*4 + reg
#pragma unroll
    for (int nf = 0; nf < 4; ++nf) {
        int col = wq * 64 + nf * 16 + lr;
        float bv = (col < 128) ? bl[col] : br[col - 128];
#pragma unroll
        for (int mf = 0; mf < 4; ++mf)
#pragma unroll
            for (int g = 0; g < 4; ++g) {
                int row = m0 + mf * 16 + lk * 4 + g;
                if (row > N_NODES - 1) row = N_NODES - 1;    // benign dup (same values)
                float v = acc[mf][nf][g] + bv;
                if (col < 128) xlb[(size_t)row * 128 + col] = bf16hi_(v);
                else           xr [(size_t)row * D1 + (col - 128)] = v;
            }
    }
}

// ---------- conv2 transform: 64 nodes/block, 8 nodes/thread, 2 cols/thread ----------
__global__ __launch_bounds__(256, 2) void k_transform2(
    const float* __restrict__ hin, const float* __restrict__ wtg,
    const float* __restrict__ bl, const float* __restrict__ br,
    unsigned short* __restrict__ xlb2, float* __restrict__ xr2)
{
    __shared__ float4 xs[64][32];   // 32 KB
    int node0 = blockIdx.x * 64;
    for (int i = threadIdx.x; i < 2048; i += 256) {
        int r = i >> 5, k4 = i & 31;
        int n = node0 + r; if (n > N_NODES - 1) n = N_NODES - 1;
        xs[r][k4] = *(const float4*)&hin[(size_t)n * D1 + k4 * 4];
    }
    __syncthreads();
    int j  = threadIdx.x & 31;
    int r0 = (threadIdx.x >> 5) * 8;
    const float4* __restrict__ wp = (const float4*)wtg;
    float accl[8], accr[8];
#pragma unroll
    for (int r = 0; r < 8; ++r) { accl[r] = 0.f; accr[r] = 0.f; }

    float4 wl_ = wp[j], wr_ = wp[j + 32];

#pragma unroll 2
    for (int k4 = 0; k4 < 32; ++k4) {
        int k4n = (k4 < 31) ? k4 + 1 : 31;
        float4 wln = wp[k4n * 64 + j];
        float4 wrn = wp[k4n * 64 + j + 32];
        float4 xv[8];
#pragma unroll
        for (int r = 0; r < 8; ++r) xv[r] = xs[r0 + r][k4];
#pragma unroll
        for (int r = 0; r < 8; ++r) {
            accl[r] = fmaf(wl_.x, xv[r].x, fmaf(wl_.y, xv[r].y,
                      fmaf(wl_.z, xv[r].z, fmaf(wl_.w, xv[r].w, accl[r]))));
            accr[r] = fmaf(wr_.x, xv[r].x, fmaf(wr_.y, xv[r].y,
                      fmaf(wr_.z, xv[r].z, fmaf(wr_.w, xv[r].w, accr[r]))));
        }
        wl_ = wln; wr_ = wrn;
    }
    float bls = bl[j], brs = br[j];
#pragma unroll
    for (int r = 0; r < 8; ++r) {
        int nn = node0 + r0 + r; if (nn > N_NODES - 1) nn = N_NODES - 1;
        size_t n = (size_t)nn;
        xlb2[n * HID + j] = bf16hi_(accl[r] + bls);
        xr2 [n * HID + j] = accr[r] + brs;
    }
}

// ---------- conv1 fused: wave per node, 2 edges/wave, bf16 ushort4 (8B) gathers ----------
__global__ __launch_bounds__(256) void k_gat1_fused(
    const int* __restrict__ rs, const int* __restrict__ csr_src,
    const unsigned short* __restrict__ xlb, const float* __restrict__ xr,
    const float* __restrict__ att, const float* __restrict__ bias,
    float* __restrict__ hout)
{
    int n = (blockIdx.x * 256 + threadIdx.x) >> 6;
    if (n >= N_NODES) return;
    int lane = threadIdx.x & 63;
    int d0   = lane & 31;
    int half = lane >> 5;
    const ushort4* xlp = (const ushort4*)xlb;
    float4 r = ((const float4*)xr)[(size_t)n * 32 + d0];
    float4 a = ((const float4*)att)[d0];
    float4 l = b2f4_(xlp[(size_t)n * 32 + d0]);
    float sc = lrelu_(l.x + r.x) * a.x + lrelu_(l.y + r.y) * a.y
             + lrelu_(l.z + r.z) * a.z + lrelu_(l.w + r.w) * a.w;
    sc += __shfl_xor(sc, 1);
    sc += __shfl_xor(sc, 2);
    sc += __shfl_xor(sc, 4);
    float ex  = (half == 0) ? __expf(sc) : 0.f;
    float den = ex;
    float4 acc = { ex * l.x, ex * l.y, ex * l.z, ex * l.w };
    int e0 = rs[n], e1 = rs[n + 1];
    int p = e0;
    for (; p + 8 <= e1; p += 8) {
        int    sA[4];
        ushort4 lu[4];
        float4 ll[4];
        float  sb[4];
#pragma unroll
        for (int i = 0; i < 4; ++i) sA[i] = csr_src[p + 2 * i + half];
#pragma unroll
        for (int i = 0; i < 4; ++i) lu[i] = xlp[(size_t)sA[i] * 32 + d0];
#pragma unroll
        for (int i = 0; i < 4; ++i) ll[i] = b2f4_(lu[i]);
#pragma unroll
        for (int i = 0; i < 4; ++i)
            sb[i] = lrelu_(ll[i].x + r.x) * a.x + lrelu_(ll[i].y + r.y) * a.y
                  + lrelu_(ll[i].z + r.z) * a.z + lrelu_(ll[i].w + r.w) * a.w;
#pragma unroll
        for (int i = 0; i < 4; ++i) sb[i] += __shfl_xor(sb[i], 1);
#pragma unroll
        for (int i = 0; i < 4; ++i) sb[i] += __shfl_xor(sb[i], 2);
#pragma unroll
        for (int i = 0; i < 4; ++i) sb[i] += __shfl_xor(sb[i], 4);
#pragma unroll
        for (int i = 0; i < 4; ++i) {
            float exx = __expf(sb[i]);
            den   += exx;
            acc.x += exx * ll[i].x;
            acc.y += exx * ll[i].y;
            acc.z += exx * ll[i].z;
            acc.w += exx * ll[i].w;
        }
    }
    for (; p < e1; p += 2) {
        int  idx = p + half;
        bool v   = idx < e1;
        int  s   = csr_src[v ? idx : e1 - 1];
        float4 ll = b2f4_(xlp[(size_t)s * 32 + d0]);
        float  s1 = lrelu_(ll.x + r.x) * a.x + lrelu_(ll.y + r.y) * a.y
                  + lrelu_(ll.z + r.z) * a.z + lrelu_(ll.w + r.w) * a.w;
        s1 += __shfl_xor(s1, 1);
        s1 += __shfl_xor(s1, 2);
        s1 += __shfl_xor(s1, 4);
        float exx = v ? __expf(s1) : 0.f;
        den   += exx;
        acc.x += exx * ll.x;
        acc.y += exx * ll.y;
        acc.z += exx * ll.z;
        acc.w += exx * ll.w;
    }
    den   += __shfl_xor(den, 32);
    acc.x += __shfl_xor(acc.x, 32);
    acc.y += __shfl_xor(acc.y, 32);
    acc.z += __shfl_xor(acc.z, 32);
    acc.w += __shfl_xor(acc.w, 32);
    if (half == 0) {
        float inv = 1.f / (den + 1e-16f);
        float4 b = ((const float4*)bias)[d0];
        float4 o;
        o.x = elu_(acc.x * inv + b.x);
        o.y = elu_(acc.y * inv + b.y);
        o.z = elu_(acc.z * inv + b.z);
        o.w = elu_(acc.w * inv + b.w);
        ((float4*)hout)[(size_t)n * 32 + d0] = o;   // hout aliases xr: own row only
    }
}

// ---------- conv2 fused: half-wave per node, 4 edges in flight, bf16 gathers ----------
__global__ __launch_bounds__(256) void k_gat2_fused(
    const int* __restrict__ rs, const int* __restrict__ csr_src,
    const unsigned short* __restrict__ xlb2, const float* __restrict__ xr2,
    const float* __restrict__ att, const float* __restrict__ bias,
    float* __restrict__ h2)
{
    int n = (blockIdx.x * 256 + threadIdx.x) >> 5;
    if (n >= N_NODES) return;
    int lane = threadIdx.x & 31;
    int d0   = lane & 7;
    int sub  = lane >> 3;
    const ushort4* xlp = (const ushort4*)xlb2;
    float4 r = ((const float4*)xr2)[(size_t)n * 8 + d0];
    float4 a = ((const float4*)att)[d0];
    float4 l = b2f4_(xlp[(size_t)n * 8 + d0]);
    float sc = lrelu_(l.x + r.x) * a.x + lrelu_(l.y + r.y) * a.y
             + lrelu_(l.z + r.z) * a.z + lrelu_(l.w + r.w) * a.w;
    sc += __shfl_xor(sc, 1);
    sc += __shfl_xor(sc, 2);
    sc += __shfl_xor(sc, 4);
    float ex  = (sub == 0) ? __expf(sc) : 0.f;
    float den = ex;
    float4 acc = { ex * l.x, ex * l.y, ex * l.z, ex * l.w };
    int e0 = rs[n], e1 = rs[n + 1];
    int p = e0;
    for (; p + 16 <= e1; p += 16) {
        int    sA[4];
        ushort4 lu[4];
        float4 ll[4];
        float  sb[4];
#pragma unroll
        for (int i = 0; i < 4; ++i) sA[i] = csr_src[p + 4 * i + sub];
#pragma unroll
        for (int i = 0; i < 4; ++i) lu[i] = xlp[(size_t)sA[i] * 8 + d0];
#pragma unroll
        for (int i = 0; i < 4; ++i) ll[i] = b2f4_(lu[i]);
#pragma unroll
        for (int i = 0; i < 4; ++i)
            sb[i] = lrelu_(ll[i].x + r.x) * a.x + lrelu_(ll[i].y + r.y) * a.y
                  + lrelu_(ll[i].z + r.z) * a.z + lrelu_(ll[i].w + r.w) * a.w;
#pragma unroll
        for (int i = 0; i < 4; ++i) sb[i] += __shfl_xor(sb[i], 1);
#pragma unroll
        for (int i = 0; i < 4; ++i) sb[i] += __shfl_xor(sb[i], 2);
#pragma unroll
        for (int i = 0; i < 4; ++i) sb[i] += __shfl_xor(sb[i], 4);
#pragma unroll
        for (int i = 0; i < 4; ++i) {
            float exx = __expf(sb[i]);
            den   += exx;
            acc.x += exx * ll[i].x;
            acc.y += exx * ll[i].y;
            acc.z += exx * ll[i].z;
            acc.w += exx * ll[i].w;
        }
    }
    for (; p < e1; p += 4) {
        int  idx = p + sub;
        bool v   = idx < e1;
        int  s   = csr_src[v ? idx : e1 - 1];
        float4 ll = b2f4_(xlp[(size_t)s * 8 + d0]);
        float  s1 = lrelu_(ll.x + r.x) * a.x + lrelu_(ll.y + r.y) * a.y
                  + lrelu_(ll.z + r.z) * a.z + lrelu_(ll.w + r.w) * a.w;
        s1 += __shfl_xor(s1, 1);
        s1 += __shfl_xor(s1, 2);
        s1 += __shfl_xor(s1, 4);
        float exx = v ? __expf(s1) : 0.f;
        den   += exx;
        acc.x += exx * ll.x;
        acc.y += exx * ll.y;
        acc.z += exx * ll.z;
        acc.w += exx * ll.w;
    }
    den   += __shfl_xor(den, 8);
    den   += __shfl_xor(den, 16);
    acc.x += __shfl_xor(acc.x, 8);  acc.x += __shfl_xor(acc.x, 16);
    acc.y += __shfl_xor(acc.y, 8);  acc.y += __shfl_xor(acc.y, 16);
    acc.z += __shfl_xor(acc.z, 8);  acc.z += __shfl_xor(acc.z, 16);
    acc.w += __shfl_xor(acc.w, 8);  acc.w += __shfl_xor(acc.w, 16);
    if (sub == 0) {
        float inv = 1.f / (den + 1e-16f);
        float4 b = ((const float4*)bias)[d0];
        float4 o;
        o.x = elu_(acc.x * inv + b.x);
        o.y = elu_(acc.y * inv + b.y);
        o.z = elu_(acc.z * inv + b.z);
        o.w = elu_(acc.w * inv + b.w);
        ((float4*)h2)[(size_t)n * 8 + d0] = o;
    }
}

// ---------- per-graph mean pool + both heads ----------
__global__ __launch_bounds__(256) void k_pool_heads(
    const float* __restrict__ h2, const int* __restrict__ gstart,
    const float* __restrict__ wc, const float* __restrict__ bc,
    const float* __restrict__ wp, const float* __restrict__ bp,
    float* __restrict__ out)
{
    int g  = blockIdx.x;
    int n0 = gstart[g], n1 = gstart[g + 1];
    int c    = threadIdx.x & 31;
    int slot = threadIdx.x >> 5;   // 0..7
    float s = 0.f;
    for (int n = n0 + slot; n < n1; n += 8)
        s += h2[n * HID + c];
    __shared__ float red[8][HID];
    red[slot][c] = s;
    __syncthreads();
    if (slot == 0) {
        float tot = 0.f;
#pragma unroll
        for (int i = 0; i < 8; ++i) tot += red[i][c];
        float cntf = fmaxf((float)(n1 - n0), 1.f);
        float p = tot / cntf;
        float sc = p * wc[c];
        float sp = p * wp[c];
        sc += __shfl_xor(sc, 1);  sp += __shfl_xor(sp, 1);
        sc += __shfl_xor(sc, 2);  sp += __shfl_xor(sp, 2);
        sc += __shfl_xor(sc, 4);  sp += __shfl_xor(sp, 4);
        sc += __shfl_xor(sc, 8);  sp += __shfl_xor(sp, 8);
        sc += __shfl_xor(sc, 16); sp += __shfl_xor(sp, 16);
        if (c == 0) {
            out[g]          = sc + bc[0];
            out[NGRAPH + g] = sp + bp[0];
        }
    }
}

extern "C" void kernel_launch(void* const* d_in, const int* in_sizes, int n_in,
                              void* d_out, int out_size, void* d_ws, size_t ws_size,
                              hipStream_t stream)
{
    const float* x     = (const float*)d_in[0];
    const int*   ei    = (const int*)d_in[1];
    const int*   batch = (const int*)d_in[2];
    const float* w1l   = (const float*)d_in[3];
    const float* b1l   = (const float*)d_in[4];
    const float* w1r   = (const float*)d_in[5];
    const float* b1r   = (const float*)d_in[6];
    const float* att1  = (const float*)d_in[7];
    const float* bias1 = (const float*)d_in[8];
    const float* w2l   = (const float*)d_in[9];
    const float* b2l   = (const float*)d_in[10];
    const float* w2r   = (const float*)d_in[11];
    const float* b2r   = (const float*)d_in[12];
    const float* att2  = (const float*)d_in[13];
    const float* bias2 = (const float*)d_in[14];
    const float* wc    = (const float*)d_in[15];
    const float* bc    = (const float*)d_in[16];
    const float* wp    = (const float*)d_in[17];
    const float* bp    = (const float*)d_in[18];
    float* out = (float*)d_out;

    float* ws   = (float*)d_ws;
    // conv1 phase: xlb (bf16 gathered table) = ws floats [0, 3.2M); xr1 at +6.4M
    unsigned short* xlb = (unsigned short*)ws;          // 6,400,000 ushorts = 12.8 MB
    float* xr1  = ws + 6400000;       // 6,400,000 floats
    float* hbuf = ws + 6400000;       // ALIASES xr1 (safe: per-wave read-own-row-then-write)
    // rank: 800,000 ints in ws floats [3.2M, 4M) — live only during CSR build,
    // later overwritten by h2 (conv2 phase). No temporal overlap.
    int* rank = (int*)(ws + 3200000);
    // conv2 phase (xlb region dead after k_gat1_fused)
    unsigned short* xlb2 = (unsigned short*)ws;         // 1,600,000 ushorts = 3.2 MB
    float* xr2  = ws + 1600000;       // 1,600,000 floats
    float* h2   = ws + 3200000;       // 1,600,000 floats
    // int region (after 12.8M floats)
    int* ibase   = (int*)(ws + 12800000);
    int* deg     = ibase;              //  50,000
    int* rs      = ibase + 50000;      //  50,001
    int* csr_src = ibase + 150001;     // 800,000
    int* gstart  = ibase + 950001;     //      65
    int* btot    = ibase + 950101;     //      49
    int* boff    = ibase + 950151;     //      49
    // re-laid-out weights: conv1 bf16 hi/lo frag-order, conv2 fp32
    unsigned short* bh1 = (unsigned short*)(ws + 13800000);   // 32768 ushort
    unsigned short* bl1_ = (unsigned short*)(ws + 13816384);  // 32768 ushort
    float* wtg2 = ws + 13840000;       //  8,192 floats

    // ---- fused prep, then CSR build (1 atomic pass; scatter is atomic-free) ----
    k_prep<<<552, 256, 0, stream>>>(w1l, w1r, bh1, bl1_, w2l, w2r, wtg2, deg, batch, gstart);
    k_hist<<<(N_EDGES + 255) / 256, 256, 0, stream>>>(ei, deg, rank);
    k_scan_local<<<SCAN_NB, 1024, 0, stream>>>(deg, rs, btot);
    k_scan_btot<<<1, 64, 0, stream>>>(btot, boff);
    k_scan_add<<<SCAN_NB, 1024, 0, stream>>>(rs, boff);
    k_scatter<<<(N_EDGES + 255) / 256, 256, 0, stream>>>(ei, rs, rank, csr_src);

    // ---- conv1 ----
    k_transform1<<<(N_NODES + 63) / 64, 256, 0, stream>>>(x, bh1, bl1_, b1l, b1r, xlb, xr1);
    k_gat1_fused<<<(N_NODES * 64 + 255) / 256, 256, 0, stream>>>(rs, csr_src, xlb, xr1, att1, bias1, hbuf);

    // ---- conv2 ----
    k_transform2<<<(N_NODES + 63) / 64, 256, 0, stream>>>(hbuf, wtg2, b2l, b2r, xlb2, xr2);
    k_gat2_fused<<<(N_NODES * 32 + 255) / 256, 256, 0, stream>>>(rs, csr_src, xlb2, xr2, att2, bias2, h2);

    // ---- pool + heads ----
    k_pool_heads<<<NGRAPH, 256, 0, stream>>>(h2, gstart, wc, bc, wp, bp, out);
}

// Round 13
// 202.527 us; speedup vs baseline: 1.3165x; 1.0100x over previous
//
#include <hip/hip_runtime.h>

#define N_NODES 50000
#define N_EDGES 800000
#define FEATS   128
#define HID     32
#define HEADS   4
#define D1      128      // HEADS*HID
#define NGRAPH  64
#define SCAN_NB ((N_NODES + 1023) / 1024)   // 49

__device__ __forceinline__ float lrelu_(float v) { return fmaxf(v, 0.2f * v); }
__device__ __forceinline__ float elu_(float v)   { return v > 0.f ? v : __expf(v) - 1.f; }

typedef __attribute__((ext_vector_type(8))) short short8v;
typedef __attribute__((ext_vector_type(4))) float f32x4;
typedef _Float16 hv2 __attribute__((ext_vector_type(2)));

// fp32 -> bf16 (RNE) high part (for MFMA input splitting)
__device__ __forceinline__ unsigned short bf16hi_(float x) {
    unsigned u = __float_as_uint(x);
    unsigned r = u + 0x7FFFu + ((u >> 16) & 1);
    return (unsigned short)(r >> 16);
}
__device__ __forceinline__ float bf16f_(unsigned short h) {
    return __uint_as_float(((unsigned)h) << 16);
}

// native packed-f16 helpers (no hip_fp16.h): +,* -> v_pk_add/mul_f16,
// elementwise_max -> v_pk_max_f16, fdot2 -> v_dot2_f32_f16
__device__ __forceinline__ hv2 h2mk_(float x, float y) {
    hv2 r; r.x = (_Float16)x; r.y = (_Float16)y; return r;
}
__device__ __forceinline__ float dot2acc_(hv2 a, hv2 b, float c) {
#if __has_builtin(__builtin_amdgcn_fdot2)
    return __builtin_amdgcn_fdot2(a, b, c, false);
#else
    return fmaf((float)a.x, (float)b.x, fmaf((float)a.y, (float)b.y, c));
#endif
}
__device__ __forceinline__ hv2 lrelu2_(hv2 t, hv2 c02) {
    return __builtin_elementwise_max(t, t * c02);
}
__device__ __forceinline__ unsigned short f2h_(float v) {
    return __builtin_bit_cast(unsigned short, (_Float16)v);
}

// ---------- fused prep: wtrans1(bf16 hi/lo) | wtrans2 | zero(deg) | gbound ----------
// block ranges: [0,128) wtrans1, [128,160) wtrans2, [160,356) zero deg, [356,552) gbound
__global__ __launch_bounds__(256) void k_prep(
    const float* __restrict__ w1l, const float* __restrict__ w1r,
    unsigned short* __restrict__ bh, unsigned short* __restrict__ blo,
    const float* __restrict__ w2l, const float* __restrict__ w2r, float* __restrict__ wtg2,
    int* __restrict__ deg,
    const int* __restrict__ batch, int* __restrict__ gstart)
{
    int b = blockIdx.x;
    if (b < 128) {
        int idx = b * 256 + threadIdx.x;            // 32768
        int j    = idx & 7;
        int lane = (idx >> 3) & 63;
        int ks   = (idx >> 9) & 3;
        int nfg  = idx >> 11;                       // 0..15
        int col  = nfg * 16 + (lane & 15);
        int k    = ks * 32 + ((lane >> 4) & 3) * 8 + j;
        float wv = (col < 128) ? w1l[col * FEATS + k] : w1r[(col - 128) * FEATS + k];
        unsigned short h = bf16hi_(wv);
        float lo = wv - bf16f_(h);
        bh[idx]  = h;
        blo[idx] = bf16hi_(lo);
    } else if (b < 160) {
        int idx = (b - 128) * 256 + threadIdx.x;    // 8192
        int kk = idx & 3, j = (idx >> 2) & 63, k4 = idx >> 8;
        int k = k4 * 4 + kk;
        wtg2[idx] = (j < 32) ? w2l[j * D1 + k] : w2r[(j - 32) * D1 + k];
    } else if (b < 356) {
        int i = (b - 160) * 256 + threadIdx.x;      // 50176 >= 50000
        if (i < N_NODES) deg[i] = 0;
    } else {
        int i = (b - 356) * 256 + threadIdx.x;      // 50001
        if (i > N_NODES) return;
        int bb   = (i < N_NODES) ? batch[i] : NGRAPH;
        int prev = (i == 0) ? -1 : batch[i - 1];
        for (int g = prev + 1; g <= bb; ++g) gstart[g] = i;
    }
}

// ---------- CSR build: hist captures per-edge rank (counting-sort key) ----------
__global__ __launch_bounds__(256) void k_hist(const int* __restrict__ ei,
                                              int* __restrict__ deg,
                                              int* __restrict__ rank)
{
    int e = blockIdx.x * 256 + threadIdx.x;
    if (e < N_EDGES) rank[e] = atomicAdd(&deg[ei[N_EDGES + e]], 1);
}

__global__ __launch_bounds__(1024) void k_scan_local(
    const int* __restrict__ deg, int* __restrict__ rs, int* __restrict__ btot)
{
    __shared__ int sm[1024];
    int idx = blockIdx.x * 1024 + threadIdx.x;
    int v = (idx < N_NODES) ? deg[idx] : 0;
    sm[threadIdx.x] = v;
    __syncthreads();
    for (int off = 1; off < 1024; off <<= 1) {
        int t = (threadIdx.x >= off) ? sm[threadIdx.x - off] : 0;
        __syncthreads();
        sm[threadIdx.x] += t;
        __syncthreads();
    }
    if (idx < N_NODES) rs[idx] = sm[threadIdx.x] - v;   // exclusive
    if (threadIdx.x == 1023) btot[blockIdx.x] = sm[1023];
}

__global__ __launch_bounds__(64) void k_scan_btot(
    const int* __restrict__ btot, int* __restrict__ boff)
{
    int t = threadIdx.x;
    int own = (t < SCAN_NB) ? btot[t] : 0;
    int v = own;
    for (int off = 1; off < 64; off <<= 1) {
        int u = __shfl_up(v, off);
        if (t >= off) v += u;
    }
    if (t < SCAN_NB) boff[t] = v - own;   // exclusive
}

__global__ __launch_bounds__(1024) void k_scan_add(
    int* __restrict__ rs, const int* __restrict__ boff)
{
    int idx = blockIdx.x * 1024 + threadIdx.x;
    if (idx < N_NODES) rs[idx] += boff[blockIdx.x];
    if (idx == N_NODES) rs[N_NODES] = N_EDGES;
}

// ---------- scatter: NO atomics — position = rs[dst] + rank[e] ----------
__global__ __launch_bounds__(256) void k_scatter(const int* __restrict__ ei,
                                                const int* __restrict__ rs,
                                                const int* __restrict__ rank,
                                                int* __restrict__ csr_src)
{
    int e = blockIdx.x * 256 + threadIdx.x;
    if (e >= N_EDGES) return;
    int d = ei[N_EDGES + e];
    csr_src[rs[d] + rank[e]] = ei[e];
}

// ---------- conv1 transform: MFMA bf16x3, 64 rows/block, wave owns 64 cols ----------
// xl output table now fp16 (better precision than bf16, same bytes).
__global__ __launch_bounds__(256) void k_transform1(
    const float* __restrict__ x,
    const unsigned short* __restrict__ bh1, const unsigned short* __restrict__ bl1,
    const float* __restrict__ bl, const float* __restrict__ br,
    unsigned short* __restrict__ xlb, float* __restrict__ xr)
{
    __shared__ unsigned short XH[64 * 136];   // 17.4 KB
    __shared__ unsigned short XL[64 * 136];   // 17.4 KB
    int m0 = blockIdx.x * 64;
    for (int i = threadIdx.x; i < 2048; i += 256) {      // 64 rows x 32 float4
        int r = i >> 5, c4 = i & 31;
        int n = m0 + r; if (n > N_NODES - 1) n = N_NODES - 1;   // tail clamp (benign dup)
        float4 v = *(const float4*)&x[(size_t)n * FEATS + c4 * 4];
        ushort4 h, lo;
        h.x = bf16hi_(v.x); lo.x = bf16hi_(v.x - bf16f_(h.x));
        h.y = bf16hi_(v.y); lo.y = bf16hi_(v.y - bf16f_(h.y));
        h.z = bf16hi_(v.z); lo.z = bf16hi_(v.z - bf16f_(h.z));
        h.w = bf16hi_(v.w); lo.w = bf16hi_(v.w - bf16f_(h.w));
        *(ushort4*)&XH[r * 136 + c4 * 4] = h;
        *(ushort4*)&XL[r * 136 + c4 * 4] = lo;
    }
    __syncthreads();

    int l  = threadIdx.x & 63;
    int wq = threadIdx.x >> 6;          // wave id = col-quadrant (64 cols)
    int lr = l & 15;
    int lk = (l >> 4) & 3;

    f32x4 acc[4][4];
#pragma unroll
    for (int m = 0; m < 4; ++m)
#pragma unroll
        for (int n = 0; n < 4; ++n)
#pragma unroll
            for (int g = 0; g < 4; ++g) acc[m][n][g] = 0.f;

    const short8v* bhp = (const short8v*)bh1;
    const short8v* blp = (const short8v*)bl1;

#pragma unroll
    for (int ks = 0; ks < 4; ++ks) {
        short8v bh[4], bw[4], ah[4], al[4];
#pragma unroll
        for (int nf = 0; nf < 4; ++nf) {
            int fidx = (((wq * 4 + nf) * 4 + ks) * 64) + l;
            bh[nf] = bhp[fidx];
            bw[nf] = blp[fidx];
        }
#pragma unroll
        for (int mf = 0; mf < 4; ++mf) {
            int off = (mf * 16 + lr) * 136 + ks * 32 + lk * 8;
            ah[mf] = *(const short8v*)&XH[off];
            al[mf] = *(const short8v*)&XL[off];
        }
#pragma unroll
        for (int mf = 0; mf < 4; ++mf)
#pragma unroll
            for (int nf = 0; nf < 4; ++nf) {
                acc[mf][nf] = __builtin_amdgcn_mfma_f32_16x16x32_bf16(ah[mf], bh[nf], acc[mf][nf], 0, 0, 0);
                acc[mf][nf] = __builtin_amdgcn_mfma_f32_16x16x32_bf16(ah[mf], bw[nf], acc[mf][nf], 0, 0, 0);
                acc[mf][nf] = __builtin_amdgcn_mfma_f32_16x16x32_bf16(al[mf], bh[nf], acc[mf][nf], 0, 0, 0);
            }
    }

    // epilogue: D col = lane&15, row = (lane>>4)*4 + reg
#pragma unroll
    for (int nf = 0; nf < 4; ++nf) {
        int col = wq * 64 + nf * 16 + lr;
        float bv = (col < 128) ? bl[col] : br[col - 128];
#pragma unroll
        for (int mf = 0; mf < 4; ++mf)
#pragma unroll
            for (int g = 0; g < 4; ++g) {
                int row = m0 + mf * 16 + lk * 4 + g;
                if (row > N_NODES - 1) row = N_NODES - 1;    // benign dup (same values)
                float v = acc[mf][nf][g] + bv;
                if (col < 128) xlb[(size_t)row * 128 + col] = f2h_(v);
                else           xr [(size_t)row * D1 + (col - 128)] = v;
            }
    }
}

// ---------- conv2 transform: 64 nodes/block, 8 nodes/thread, 2 cols/thread ----------
__global__ __launch_bounds__(256, 2) void k_transform2(
    const float* __restrict__ hin, const float* __restrict__ wtg,
    const float* __restrict__ bl, const float* __restrict__ br,
    unsigned short* __restrict__ xlb2, float* __restrict__ xr2)
{
    __shared__ float4 xs[64][32];   // 32 KB
    int node0 = blockIdx.x * 64;
    for (int i = threadIdx.x; i < 2048; i += 256) {
        int r = i >> 5, k4 = i & 31;
        int n = node0 + r; if (n > N_NODES - 1) n = N_NODES - 1;
        xs[r][k4] = *(const float4*)&hin[(size_t)n * D1 + k4 * 4];
    }
    __syncthreads();
    int j  = threadIdx.x & 31;
    int r0 = (threadIdx.x >> 5) * 8;
    const float4* __restrict__ wp = (const float4*)wtg;
    float accl[8], accr[8];
#pragma unroll
    for (int r = 0; r < 8; ++r) { accl[r] = 0.f; accr[r] = 0.f; }

    float4 wl_ = wp[j], wr_ = wp[j + 32];

#pragma unroll 2
    for (int k4 = 0; k4 < 32; ++k4) {
        int k4n = (k4 < 31) ? k4 + 1 : 31;
        float4 wln = wp[k4n * 64 + j];
        float4 wrn = wp[k4n * 64 + j + 32];
        float4 xv[8];
#pragma unroll
        for (int r = 0; r < 8; ++r) xv[r] = xs[r0 + r][k4];
#pragma unroll
        for (int r = 0; r < 8; ++r) {
            accl[r] = fmaf(wl_.x, xv[r].x, fmaf(wl_.y, xv[r].y,
                      fmaf(wl_.z, xv[r].z, fmaf(wl_.w, xv[r].w, accl[r]))));
            accr[r] = fmaf(wr_.x, xv[r].x, fmaf(wr_.y, xv[r].y,
                      fmaf(wr_.z, xv[r].z, fmaf(wr_.w, xv[r].w, accr[r]))));
        }
        wl_ = wln; wr_ = wrn;
    }
    float bls = bl[j], brs = br[j];
#pragma unroll
    for (int r = 0; r < 8; ++r) {
        int nn = node0 + r0 + r; if (nn > N_NODES - 1) nn = N_NODES - 1;
        size_t n = (size_t)nn;
        xlb2[n * HID + j] = f2h_(accl[r] + bls);
        xr2 [n * HID + j] = accr[r] + brs;
    }
}

// ---------- conv1 fused: wave per node, 2 edges/wave, fp16 ushort4 (8B) gathers,
// packed-f16 score path (v_pk_add/mul/max + v_dot2 f32 accumulate) ----------
__global__ __launch_bounds__(256) void k_gat1_fused(
    const int* __restrict__ rs, const int* __restrict__ csr_src,
    const unsigned short* __restrict__ xlb, const float* __restrict__ xr,
    const float* __restrict__ att, const float* __restrict__ bias,
    float* __restrict__ hout)
{
    int n = (blockIdx.x * 256 + threadIdx.x) >> 6;
    if (n >= N_NODES) return;
    int lane = threadIdx.x & 63;
    int d0   = lane & 31;
    int half = lane >> 5;
    const ushort4* xlp = (const ushort4*)xlb;
    float4 rf = ((const float4*)xr)[(size_t)n * 32 + d0];
    hv2 r01 = h2mk_(rf.x, rf.y), r23 = h2mk_(rf.z, rf.w);
    float4 af = ((const float4*)att)[d0];
    hv2 a01 = h2mk_(af.x, af.y), a23 = h2mk_(af.z, af.w);
    const hv2 c02 = h2mk_(0.2f, 0.2f);

    float den;
    float4 acc;
    {   // self edge (counted on half 0 only)
        ushort4 lu = xlp[(size_t)n * 32 + d0];
        hv2 l01 = *(hv2*)&lu.x, l23 = *(hv2*)&lu.z;
        float sc = dot2acc_(lrelu2_(l01 + r01, c02), a01,
                   dot2acc_(lrelu2_(l23 + r23, c02), a23, 0.f));
        sc += __shfl_xor(sc, 1);
        sc += __shfl_xor(sc, 2);
        sc += __shfl_xor(sc, 4);
        float ex = (half == 0) ? __expf(sc) : 0.f;
        den = ex;
        acc.x = ex * (float)l01.x;  acc.y = ex * (float)l01.y;
        acc.z = ex * (float)l23.x;  acc.w = ex * (float)l23.y;
    }
    int e0 = rs[n], e1 = rs[n + 1];
    int p = e0;
    for (; p + 8 <= e1; p += 8) {
        int     sA[4];
        ushort4 lu[4];
        float   sb[4];
#pragma unroll
        for (int i = 0; i < 4; ++i) sA[i] = csr_src[p + 2 * i + half];
#pragma unroll
        for (int i = 0; i < 4; ++i) lu[i] = xlp[(size_t)sA[i] * 32 + d0];
        hv2 l01[4], l23[4];
#pragma unroll
        for (int i = 0; i < 4; ++i) { l01[i] = *(hv2*)&lu[i].x; l23[i] = *(hv2*)&lu[i].z; }
#pragma unroll
        for (int i = 0; i < 4; ++i)
            sb[i] = dot2acc_(lrelu2_(l01[i] + r01, c02), a01,
                    dot2acc_(lrelu2_(l23[i] + r23, c02), a23, 0.f));
#pragma unroll
        for (int i = 0; i < 4; ++i) sb[i] += __shfl_xor(sb[i], 1);
#pragma unroll
        for (int i = 0; i < 4; ++i) sb[i] += __shfl_xor(sb[i], 2);
#pragma unroll
        for (int i = 0; i < 4; ++i) sb[i] += __shfl_xor(sb[i], 4);
#pragma unroll
        for (int i = 0; i < 4; ++i) {
            float exx = __expf(sb[i]);
            den   += exx;
            acc.x += exx * (float)l01[i].x;
            acc.y += exx * (float)l01[i].y;
            acc.z += exx * (float)l23[i].x;
            acc.w += exx * (float)l23[i].y;
        }
    }
    for (; p < e1; p += 2) {
        int  idx = p + half;
        bool v   = idx < e1;
        int  s   = csr_src[v ? idx : e1 - 1];
        ushort4 lu = xlp[(size_t)s * 32 + d0];
        hv2 l01 = *(hv2*)&lu.x, l23 = *(hv2*)&lu.z;
        float s1 = dot2acc_(lrelu2_(l01 + r01, c02), a01,
                   dot2acc_(lrelu2_(l23 + r23, c02), a23, 0.f));
        s1 += __shfl_xor(s1, 1);
        s1 += __shfl_xor(s1, 2);
        s1 += __shfl_xor(s1, 4);
        float exx = v ? __expf(s1) : 0.f;
        den   += exx;
        acc.x += exx * (float)l01.x;
        acc.y += exx * (float)l01.y;
        acc.z += exx * (float)l23.x;
        acc.w += exx * (float)l23.y;
    }
    den   += __shfl_xor(den, 32);
    acc.x += __shfl_xor(acc.x, 32);
    acc.y += __shfl_xor(acc.y, 32);
    acc.z += __shfl_xor(acc.z, 32);
    acc.w += __shfl_xor(acc.w, 32);
    if (half == 0) {
        float inv = 1.f / (den + 1e-16f);
        float4 b = ((const float4*)bias)[d0];
        float4 o;
        o.x = elu_(acc.x * inv + b.x);
        o.y = elu_(acc.y * inv + b.y);
        o.z = elu_(acc.z * inv + b.z);
        o.w = elu_(acc.w * inv + b.w);
        ((float4*)hout)[(size_t)n * 32 + d0] = o;   // hout aliases xr: own row only
    }
}

// ---------- conv2 fused: half-wave per node, 4 edges in flight, fp16 gathers, packed score ----------
__global__ __launch_bounds__(256) void k_gat2_fused(
    const int* __restrict__ rs, const int* __restrict__ csr_src,
    const unsigned short* __restrict__ xlb2, const float* __restrict__ xr2,
    const float* __restrict__ att, const float* __restrict__ bias,
    float* __restrict__ h2)
{
    int n = (blockIdx.x * 256 + threadIdx.x) >> 5;
    if (n >= N_NODES) return;
    int lane = threadIdx.x & 31;
    int d0   = lane & 7;
    int sub  = lane >> 3;
    const ushort4* xlp = (const ushort4*)xlb2;
    float4 rf = ((const float4*)xr2)[(size_t)n * 8 + d0];
    hv2 r01 = h2mk_(rf.x, rf.y), r23 = h2mk_(rf.z, rf.w);
    float4 af = ((const float4*)att)[d0];
    hv2 a01 = h2mk_(af.x, af.y), a23 = h2mk_(af.z, af.w);
    const hv2 c02 = h2mk_(0.2f, 0.2f);

    float den;
    float4 acc;
    {   // self edge (sub 0 only)
        ushort4 lu = xlp[(size_t)n * 8 + d0];
        hv2 l01 = *(hv2*)&lu.x, l23 = *(hv2*)&lu.z;
        float sc = dot2acc_(lrelu2_(l01 + r01, c02), a01,
                   dot2acc_(lrelu2_(l23 + r23, c02), a23, 0.f));
        sc += __shfl_xor(sc, 1);
        sc += __shfl_xor(sc, 2);
        sc += __shfl_xor(sc, 4);
        float ex = (sub == 0) ? __expf(sc) : 0.f;
        den = ex;
        acc.x = ex * (float)l01.x;  acc.y = ex * (float)l01.y;
        acc.z = ex * (float)l23.x;  acc.w = ex * (float)l23.y;
    }
    int e0 = rs[n], e1 = rs[n + 1];
    int p = e0;
    for (; p + 16 <= e1; p += 16) {
        int     sA[4];
        ushort4 lu[4];
        float   sb[4];
#pragma unroll
        for (int i = 0; i < 4; ++i) sA[i] = csr_src[p + 4 * i + sub];
#pragma unroll
        for (int i = 0; i < 4; ++i) lu[i] = xlp[(size_t)sA[i] * 8 + d0];
        hv2 l01[4], l23[4];
#pragma unroll
        for (int i = 0; i < 4; ++i) { l01[i] = *(hv2*)&lu[i].x; l23[i] = *(hv2*)&lu[i].z; }
#pragma unroll
        for (int i = 0; i < 4; ++i)
            sb[i] = dot2acc_(lrelu2_(l01[i] + r01, c02), a01,
                    dot2acc_(lrelu2_(l23[i] + r23, c02), a23, 0.f));
#pragma unroll
        for (int i = 0; i < 4; ++i) sb[i] += __shfl_xor(sb[i], 1);
#pragma unroll
        for (int i = 0; i < 4; ++i) sb[i] += __shfl_xor(sb[i], 2);
#pragma unroll
        for (int i = 0; i < 4; ++i) sb[i] += __shfl_xor(sb[i], 4);
#pragma unroll
        for (int i = 0; i < 4; ++i) {
            float exx = __expf(sb[i]);
            den   += exx;
            acc.x += exx * (float)l01[i].x;
            acc.y += exx * (float)l01[i].y;
            acc.z += exx * (float)l23[i].x;
            acc.w += exx * (float)l23[i].y;
        }
    }
    for (; p < e1; p += 4) {
        int  idx = p + sub;
        bool v   = idx < e1;
        int  s   = csr_src[v ? idx : e1 - 1];
        ushort4 lu = xlp[(size_t)s * 8 + d0];
        hv2 l01 = *(hv2*)&lu.x, l23 = *(hv2*)&lu.z;
        float s1 = dot2acc_(lrelu2_(l01 + r01, c02), a01,
                   dot2acc_(lrelu2_(l23 + r23, c02), a23, 0.f));
        s1 += __shfl_xor(s1, 1);
        s1 += __shfl_xor(s1, 2);
        s1 += __shfl_xor(s1, 4);
        float exx = v ? __expf(s1) : 0.f;
        den   += exx;
        acc.x += exx * (float)l01.x;
        acc.y += exx * (float)l01.y;
        acc.z += exx * (float)l23.x;
        acc.w += exx * (float)l23.y;
    }
    den   += __shfl_xor(den, 8);
    den   += __shfl_xor(den, 16);
    acc.x += __shfl_xor(acc.x, 8);  acc.x += __shfl_xor(acc.x, 16);
    acc.y += __shfl_xor(acc.y, 8);  acc.y += __shfl_xor(acc.y, 16);
    acc.z += __shfl_xor(acc.z, 8);  acc.z += __shfl_xor(acc.z, 16);
    acc.w += __shfl_xor(acc.w, 8);  acc.w += __shfl_xor(acc.w, 16);
    if (sub == 0) {
        float inv = 1.f / (den + 1e-16f);
        float4 b = ((const float4*)bias)[d0];
        float4 o;
        o.x = elu_(acc.x * inv + b.x);
        o.y = elu_(acc.y * inv + b.y);
        o.z = elu_(acc.z * inv + b.z);
        o.w = elu_(acc.w * inv + b.w);
        ((float4*)h2)[(size_t)n * 8 + d0] = o;
    }
}

// ---------- per-graph mean pool + both heads ----------
__global__ __launch_bounds__(256) void k_pool_heads(
    const float* __restrict__ h2, const int* __restrict__ gstart,
    const float* __restrict__ wc, const float* __restrict__ bc,
    const float* __restrict__ wp, const float* __restrict__ bp,
    float* __restrict__ out)
{
    int g  = blockIdx.x;
    int n0 = gstart[g], n1 = gstart[g + 1];
    int c    = threadIdx.x & 31;
    int slot = threadIdx.x >> 5;   // 0..7
    float s = 0.f;
    for (int n = n0 + slot; n < n1; n += 8)
        s += h2[n * HID + c];
    __shared__ float red[8][HID];
    red[slot][c] = s;
    __syncthreads();
    if (slot == 0) {
        float tot = 0.f;
#pragma unroll
        for (int i = 0; i < 8; ++i) tot += red[i][c];
        float cntf = fmaxf((float)(n1 - n0), 1.f);
        float p = tot / cntf;
        float sc = p * wc[c];
        float sp = p * wp[c];
        sc += __shfl_xor(sc, 1);  sp += __shfl_xor(sp, 1);
        sc += __shfl_xor(sc, 2);  sp += __shfl_xor(sp, 2);
        sc += __shfl_xor(sc, 4);  sp += __shfl_xor(sp, 4);
        sc += __shfl_xor(sc, 8);  sp += __shfl_xor(sp, 8);
        sc += __shfl_xor(sc, 16); sp += __shfl_xor(sp, 16);
        if (c == 0) {
            out[g]          = sc + bc[0];
            out[NGRAPH + g] = sp + bp[0];
        }
    }
}

extern "C" void kernel_launch(void* const* d_in, const int* in_sizes, int n_in,
                              void* d_out, int out_size, void* d_ws, size_t ws_size,
                              hipStream_t stream)
{
    const float* x     = (const float*)d_in[0];
    const int*   ei    = (const int*)d_in[1];
    const int*   batch = (const int*)d_in[2];
    const float* w1l   = (const float*)d_in[3];
    const float* b1l   = (const float*)d_in[4];
    const float* w1r   = (const float*)d_in[5];
    const float* b1r   = (const float*)d_in[6];
    const float* att1  = (const float*)d_in[7];
    const float* bias1 = (const float*)d_in[8];
    const float* w2l   = (const float*)d_in[9];
    const float* b2l   = (const float*)d_in[10];
    const float* w2r   = (const float*)d_in[11];
    const float* b2r   = (const float*)d_in[12];
    const float* att2  = (const float*)d_in[13];
    const float* bias2 = (const float*)d_in[14];
    const float* wc    = (const float*)d_in[15];
    const float* bc    = (const float*)d_in[16];
    const float* wp    = (const float*)d_in[17];
    const float* bp    = (const float*)d_in[18];
    float* out = (float*)d_out;

    float* ws   = (float*)d_ws;
    // conv1 phase: xlb (fp16 gathered table); xr1 at +6.4M
    unsigned short* xlb = (unsigned short*)ws;          // 6,400,000 ushorts = 12.8 MB
    float* xr1  = ws + 6400000;       // 6,400,000 floats
    float* hbuf = ws + 6400000;       // ALIASES xr1 (safe: per-wave read-own-row-then-write)
    // rank: 800,000 ints in ws floats [3.2M, 4M) — live only during CSR build,
    // later overwritten by h2 (conv2 phase). No temporal overlap.
    int* rank = (int*)(ws + 3200000);
    // conv2 phase (xlb region dead after k_gat1_fused)
    unsigned short* xlb2 = (unsigned short*)ws;         // 1,600,000 ushorts = 3.2 MB
    float* xr2  = ws + 1600000;       // 1,600,000 floats
    float* h2   = ws + 3200000;       // 1,600,000 floats
    // int region (after 12.8M floats)
    int* ibase   = (int*)(ws + 12800000);
    int* deg     = ibase;              //  50,000
    int* rs      = ibase + 50000;      //  50,001
    int* csr_src = ibase + 150001;     // 800,000
    int* gstart  = ibase + 950001;     //      65
    int* btot    = ibase + 950101;     //      49
    int* boff    = ibase + 950151;     //      49
    // re-laid-out weights: conv1 bf16 hi/lo frag-order, conv2 fp32
    unsigned short* bh1 = (unsigned short*)(ws + 13800000);   // 32768 ushort
    unsigned short* bl1_ = (unsigned short*)(ws + 13816384);  // 32768 ushort
    float* wtg2 = ws + 13840000;       //  8,192 floats

    // ---- fused prep, then CSR build (1 atomic pass; scatter is atomic-free) ----
    k_prep<<<552, 256, 0, stream>>>(w1l, w1r, bh1, bl1_, w2l, w2r, wtg2, deg, batch, gstart);
    k_hist<<<(N_EDGES + 255) / 256, 256, 0, stream>>>(ei, deg, rank);
    k_scan_local<<<SCAN_NB, 1024, 0, stream>>>(deg, rs, btot);
    k_scan_btot<<<1, 64, 0, stream>>>(btot, boff);
    k_scan_add<<<SCAN_NB, 1024, 0, stream>>>(rs, boff);
    k_scatter<<<(N_EDGES + 255) / 256, 256, 0, stream>>>(ei, rs, rank, csr_src);

    // ---- conv1 ----
    k_transform1<<<(N_NODES + 63) / 64, 256, 0, stream>>>(x, bh1, bl1_, b1l, b1r, xlb, xr1);
    k_gat1_fused<<<(N_NODES * 64 + 255) / 256, 256, 0, stream>>>(rs, csr_src, xlb, xr1, att1, bias1, hbuf);

    // ---- conv2 ----
    k_transform2<<<(N_NODES + 63) / 64, 256, 0, stream>>>(hbuf, wtg2, b2l, b2r, xlb2, xr2);
    k_gat2_fused<<<(N_NODES * 32 + 255) / 256, 256, 0, stream>>>(rs, csr_src, xlb2, xr2, att2, bias2, h2);

    // ---- pool + heads ----
    k_pool_heads<<<NGRAPH, 256, 0, stream>>>(h2, gstart, wc, bc, wp, bp, out);
}

// Round 14
// 201.452 us; speedup vs baseline: 1.3235x; 1.0053x over previous
//
#include <hip/hip_runtime.h>

#define N_NODES 50000
#define N_EDGES 800000
#define FEATS   128
#define HID     32
#define HEADS   4
#define D1      128      // HEADS*HID
#define NGRAPH  64
#define SCAN_NB ((N_NODES + 1023) / 1024)   // 49
#define T1_NB   ((N_NODES + 63) / 64)       // 782
#define HIST_NB ((N_EDGES + 255) / 256)     // 3125

__device__ __forceinline__ float lrelu_(float v) { return fmaxf(v, 0.2f * v); }
__device__ __forceinline__ float elu_(float v)   { return v > 0.f ? v : __expf(v) - 1.f; }

typedef __attribute__((ext_vector_type(8))) short short8v;
typedef __attribute__((ext_vector_type(4))) float f32x4;
typedef _Float16 hv2 __attribute__((ext_vector_type(2)));

// fp32 -> bf16 (RNE) high part (for MFMA input splitting)
__device__ __forceinline__ unsigned short bf16hi_(float x) {
    unsigned u = __float_as_uint(x);
    unsigned r = u + 0x7FFFu + ((u >> 16) & 1);
    return (unsigned short)(r >> 16);
}
__device__ __forceinline__ float bf16f_(unsigned short h) {
    return __uint_as_float(((unsigned)h) << 16);
}

// native packed-f16 helpers: +,* -> v_pk_add/mul_f16, max -> v_pk_max_f16, fdot2 -> v_dot2_f32_f16
__device__ __forceinline__ hv2 h2mk_(float x, float y) {
    hv2 r; r.x = (_Float16)x; r.y = (_Float16)y; return r;
}
__device__ __forceinline__ float dot2acc_(hv2 a, hv2 b, float c) {
#if __has_builtin(__builtin_amdgcn_fdot2)
    return __builtin_amdgcn_fdot2(a, b, c, false);
#else
    return fmaf((float)a.x, (float)b.x, fmaf((float)a.y, (float)b.y, c));
#endif
}
__device__ __forceinline__ hv2 lrelu2_(hv2 t, hv2 c02) {
    return __builtin_elementwise_max(t, t * c02);
}
__device__ __forceinline__ unsigned short f2h_(float v) {
    return __builtin_bit_cast(unsigned short, (_Float16)v);
}

// ---------- fused prep: wtrans1(bf16 hi/lo) | wtrans2 | zero(deg) | gbound ----------
__global__ __launch_bounds__(256) void k_prep(
    const float* __restrict__ w1l, const float* __restrict__ w1r,
    unsigned short* __restrict__ bh, unsigned short* __restrict__ blo,
    const float* __restrict__ w2l, const float* __restrict__ w2r, float* __restrict__ wtg2,
    int* __restrict__ deg,
    const int* __restrict__ batch, int* __restrict__ gstart)
{
    int b = blockIdx.x;
    if (b < 128) {
        int idx = b * 256 + threadIdx.x;            // 32768
        int j    = idx & 7;
        int lane = (idx >> 3) & 63;
        int ks   = (idx >> 9) & 3;
        int nfg  = idx >> 11;                       // 0..15
        int col  = nfg * 16 + (lane & 15);
        int k    = ks * 32 + ((lane >> 4) & 3) * 8 + j;
        float wv = (col < 128) ? w1l[col * FEATS + k] : w1r[(col - 128) * FEATS + k];
        unsigned short h = bf16hi_(wv);
        float lo = wv - bf16f_(h);
        bh[idx]  = h;
        blo[idx] = bf16hi_(lo);
    } else if (b < 160) {
        int idx = (b - 128) * 256 + threadIdx.x;    // 8192
        int kk = idx & 3, j = (idx >> 2) & 63, k4 = idx >> 8;
        int k = k4 * 4 + kk;
        wtg2[idx] = (j < 32) ? w2l[j * D1 + k] : w2r[(j - 32) * D1 + k];
    } else if (b < 356) {
        int i = (b - 160) * 256 + threadIdx.x;      // 50176 >= 50000
        if (i < N_NODES) deg[i] = 0;
    } else {
        int i = (b - 356) * 256 + threadIdx.x;      // 50001
        if (i > N_NODES) return;
        int bb   = (i < N_NODES) ? batch[i] : NGRAPH;
        int prev = (i == 0) ? -1 : batch[i - 1];
        for (int g = prev + 1; g <= bb; ++g) gstart[g] = i;
    }
}

// ---------- FUSED conv1-transform + histogram ----------
// blocks [0, T1_NB): MFMA bf16x3 transform (compute-bound);
// blocks [T1_NB, T1_NB+HIST_NB): rank-capturing atomic histogram (latency-bound).
// Independent work, complementary pipes -> co-scheduled, dur ~= max not sum.
__global__ __launch_bounds__(256) void k_t1_hist(
    const float* __restrict__ x,
    const unsigned short* __restrict__ bh1, const unsigned short* __restrict__ bl1,
    const float* __restrict__ bl, const float* __restrict__ br,
    unsigned short* __restrict__ xlb, float* __restrict__ xr,
    const int* __restrict__ ei, int* __restrict__ deg, int* __restrict__ rank)
{
    __shared__ unsigned short XH[64 * 136];   // 17.4 KB (reserved by all blocks; hist blocks idle it)
    __shared__ unsigned short XL[64 * 136];   // 17.4 KB

    if (blockIdx.x >= T1_NB) {
        int e = (blockIdx.x - T1_NB) * 256 + threadIdx.x;
        if (e < N_EDGES) rank[e] = atomicAdd(&deg[ei[N_EDGES + e]], 1);
        return;
    }

    int m0 = blockIdx.x * 64;
    for (int i = threadIdx.x; i < 2048; i += 256) {      // 64 rows x 32 float4
        int r = i >> 5, c4 = i & 31;
        int n = m0 + r; if (n > N_NODES - 1) n = N_NODES - 1;   // tail clamp (benign dup)
        float4 v = *(const float4*)&x[(size_t)n * FEATS + c4 * 4];
        ushort4 h, lo;
        h.x = bf16hi_(v.x); lo.x = bf16hi_(v.x - bf16f_(h.x));
        h.y = bf16hi_(v.y); lo.y = bf16hi_(v.y - bf16f_(h.y));
        h.z = bf16hi_(v.z); lo.z = bf16hi_(v.z - bf16f_(h.z));
        h.w = bf16hi_(v.w); lo.w = bf16hi_(v.w - bf16f_(h.w));
        *(ushort4*)&XH[r * 136 + c4 * 4] = h;
        *(ushort4*)&XL[r * 136 + c4 * 4] = lo;
    }
    __syncthreads();

    int l  = threadIdx.x & 63;
    int wq = threadIdx.x >> 6;          // wave id = col-quadrant (64 cols)
    int lr = l & 15;
    int lk = (l >> 4) & 3;

    f32x4 acc[4][4];
#pragma unroll
    for (int m = 0; m < 4; ++m)
#pragma unroll
        for (int n = 0; n < 4; ++n)
#pragma unroll
            for (int g = 0; g < 4; ++g) acc[m][n][g] = 0.f;

    const short8v* bhp = (const short8v*)bh1;
    const short8v* blp = (const short8v*)bl1;

#pragma unroll
    for (int ks = 0; ks < 4; ++ks) {
        short8v bh[4], bw[4], ah[4], al[4];
#pragma unroll
        for (int nf = 0; nf < 4; ++nf) {
            int fidx = (((wq * 4 + nf) * 4 + ks) * 64) + l;
            bh[nf] = bhp[fidx];
            bw[nf] = blp[fidx];
        }
#pragma unroll
        for (int mf = 0; mf < 4; ++mf) {
            int off = (mf * 16 + lr) * 136 + ks * 32 + lk * 8;
            ah[mf] = *(const short8v*)&XH[off];
            al[mf] = *(const short8v*)&XL[off];
        }
#pragma unroll
        for (int mf = 0; mf < 4; ++mf)
#pragma unroll
            for (int nf = 0; nf < 4; ++nf) {
                acc[mf][nf] = __builtin_amdgcn_mfma_f32_16x16x32_bf16(ah[mf], bh[nf], acc[mf][nf], 0, 0, 0);
                acc[mf][nf] = __builtin_amdgcn_mfma_f32_16x16x32_bf16(ah[mf], bw[nf], acc[mf][nf], 0, 0, 0);
                acc[mf][nf] = __builtin_amdgcn_mfma_f32_16x16x32_bf16(al[mf], bh[nf], acc[mf][nf], 0, 0, 0);
            }
    }

    // epilogue: D col = lane&15, row = (lane>>4)*4 + reg
#pragma unroll
    for (int nf = 0; nf < 4; ++nf) {
        int col = wq * 64 + nf * 16 + lr;
        float bv = (col < 128) ? bl[col] : br[col - 128];
#pragma unroll
        for (int mf = 0; mf < 4; ++mf)
#pragma unroll
            for (int g = 0; g < 4; ++g) {
                int row = m0 + mf * 16 + lk * 4 + g;
                if (row > N_NODES - 1) row = N_NODES - 1;    // benign dup (same values)
                float v = acc[mf][nf][g] + bv;
                if (col < 128) xlb[(size_t)row * 128 + col] = f2h_(v);
                else           xr [(size_t)row * D1 + (col - 128)] = v;
            }
    }
}

__global__ __launch_bounds__(1024) void k_scan_local(
    const int* __restrict__ deg, int* __restrict__ rs, int* __restrict__ btot)
{
    __shared__ int sm[1024];
    int idx = blockIdx.x * 1024 + threadIdx.x;
    int v = (idx < N_NODES) ? deg[idx] : 0;
    sm[threadIdx.x] = v;
    __syncthreads();
    for (int off = 1; off < 1024; off <<= 1) {
        int t = (threadIdx.x >= off) ? sm[threadIdx.x - off] : 0;
        __syncthreads();
        sm[threadIdx.x] += t;
        __syncthreads();
    }
    if (idx < N_NODES) rs[idx] = sm[threadIdx.x] - v;   // exclusive
    if (threadIdx.x == 1023) btot[blockIdx.x] = sm[1023];
}

__global__ __launch_bounds__(64) void k_scan_btot(
    const int* __restrict__ btot, int* __restrict__ boff)
{
    int t = threadIdx.x;
    int own = (t < SCAN_NB) ? btot[t] : 0;
    int v = own;
    for (int off = 1; off < 64; off <<= 1) {
        int u = __shfl_up(v, off);
        if (t >= off) v += u;
    }
    if (t < SCAN_NB) boff[t] = v - own;   // exclusive
}

__global__ __launch_bounds__(1024) void k_scan_add(
    int* __restrict__ rs, const int* __restrict__ boff)
{
    int idx = blockIdx.x * 1024 + threadIdx.x;
    if (idx < N_NODES) rs[idx] += boff[blockIdx.x];
    if (idx == N_NODES) rs[N_NODES] = N_EDGES;
}

// ---------- scatter: NO atomics — position = rs[dst] + rank[e] ----------
__global__ __launch_bounds__(256) void k_scatter(const int* __restrict__ ei,
                                                const int* __restrict__ rs,
                                                const int* __restrict__ rank,
                                                int* __restrict__ csr_src)
{
    int e = blockIdx.x * 256 + threadIdx.x;
    if (e >= N_EDGES) return;
    int d = ei[N_EDGES + e];
    csr_src[rs[d] + rank[e]] = ei[e];
}

// ---------- conv2 transform: 64 nodes/block, 8 nodes/thread, 2 cols/thread ----------
__global__ __launch_bounds__(256, 2) void k_transform2(
    const float* __restrict__ hin, const float* __restrict__ wtg,
    const float* __restrict__ bl, const float* __restrict__ br,
    unsigned short* __restrict__ xlb2, float* __restrict__ xr2)
{
    __shared__ float4 xs[64][32];   // 32 KB
    int node0 = blockIdx.x * 64;
    for (int i = threadIdx.x; i < 2048; i += 256) {
        int r = i >> 5, k4 = i & 31;
        int n = node0 + r; if (n > N_NODES - 1) n = N_NODES - 1;
        xs[r][k4] = *(const float4*)&hin[(size_t)n * D1 + k4 * 4];
    }
    __syncthreads();
    int j  = threadIdx.x & 31;
    int r0 = (threadIdx.x >> 5) * 8;
    const float4* __restrict__ wp = (const float4*)wtg;
    float accl[8], accr[8];
#pragma unroll
    for (int r = 0; r < 8; ++r) { accl[r] = 0.f; accr[r] = 0.f; }

    float4 wl_ = wp[j], wr_ = wp[j + 32];

#pragma unroll 2
    for (int k4 = 0; k4 < 32; ++k4) {
        int k4n = (k4 < 31) ? k4 + 1 : 31;
        float4 wln = wp[k4n * 64 + j];
        float4 wrn = wp[k4n * 64 + j + 32];
        float4 xv[8];
#pragma unroll
        for (int r = 0; r < 8; ++r) xv[r] = xs[r0 + r][k4];
#pragma unroll
        for (int r = 0; r < 8; ++r) {
            accl[r] = fmaf(wl_.x, xv[r].x, fmaf(wl_.y, xv[r].y,
                      fmaf(wl_.z, xv[r].z, fmaf(wl_.w, xv[r].w, accl[r]))));
            accr[r] = fmaf(wr_.x, xv[r].x, fmaf(wr_.y, xv[r].y,
                      fmaf(wr_.z, xv[r].z, fmaf(wr_.w, xv[r].w, accr[r]))));
        }
        wl_ = wln; wr_ = wrn;
    }
    float bls = bl[j], brs = br[j];
#pragma unroll
    for (int r = 0; r < 8; ++r) {
        int nn = node0 + r0 + r; if (nn > N_NODES - 1) nn = N_NODES - 1;
        size_t n = (size_t)nn;
        xlb2[n * HID + j] = f2h_(accl[r] + bls);
        xr2 [n * HID + j] = accr[r] + brs;
    }
}

// ---------- conv1 fused: wave per node, 2 edges/wave, fp16 gathers, 8 deep ----------
__global__ __launch_bounds__(256) void k_gat1_fused(
    const int* __restrict__ rs, const int* __restrict__ csr_src,
    const unsigned short* __restrict__ xlb, const float* __restrict__ xr,
    const float* __restrict__ att, const float* __restrict__ bias,
    float* __restrict__ hout)
{
    int n = (blockIdx.x * 256 + threadIdx.x) >> 6;
    if (n >= N_NODES) return;
    int lane = threadIdx.x & 63;
    int d0   = lane & 31;
    int half = lane >> 5;
    const ushort4* xlp = (const ushort4*)xlb;
    float4 rf = ((const float4*)xr)[(size_t)n * 32 + d0];
    hv2 r01 = h2mk_(rf.x, rf.y), r23 = h2mk_(rf.z, rf.w);
    float4 af = ((const float4*)att)[d0];
    hv2 a01 = h2mk_(af.x, af.y), a23 = h2mk_(af.z, af.w);
    const hv2 c02 = h2mk_(0.2f, 0.2f);

    float den;
    float4 acc;
    {   // self edge (counted on half 0 only)
        ushort4 lu = xlp[(size_t)n * 32 + d0];
        hv2 l01 = *(hv2*)&lu.x, l23 = *(hv2*)&lu.z;
        float sc = dot2acc_(lrelu2_(l01 + r01, c02), a01,
                   dot2acc_(lrelu2_(l23 + r23, c02), a23, 0.f));
        sc += __shfl_xor(sc, 1);
        sc += __shfl_xor(sc, 2);
        sc += __shfl_xor(sc, 4);
        float ex = (half == 0) ? __expf(sc) : 0.f;
        den = ex;
        acc.x = ex * (float)l01.x;  acc.y = ex * (float)l01.y;
        acc.z = ex * (float)l23.x;  acc.w = ex * (float)l23.y;
    }
    int e0 = rs[n], e1 = rs[n + 1];
    int p = e0;
    for (; p + 16 <= e1; p += 16) {      // 8 pairs = 16 edges, 8 gathers in flight
        int     sA[8];
        ushort4 lu[8];
        float   sb[8];
#pragma unroll
        for (int i = 0; i < 8; ++i) sA[i] = csr_src[p + 2 * i + half];
#pragma unroll
        for (int i = 0; i < 8; ++i) lu[i] = xlp[(size_t)sA[i] * 32 + d0];
        hv2 l01[8], l23[8];
#pragma unroll
        for (int i = 0; i < 8; ++i) { l01[i] = *(hv2*)&lu[i].x; l23[i] = *(hv2*)&lu[i].z; }
#pragma unroll
        for (int i = 0; i < 8; ++i)
            sb[i] = dot2acc_(lrelu2_(l01[i] + r01, c02), a01,
                    dot2acc_(lrelu2_(l23[i] + r23, c02), a23, 0.f));
#pragma unroll
        for (int i = 0; i < 8; ++i) sb[i] += __shfl_xor(sb[i], 1);
#pragma unroll
        for (int i = 0; i < 8; ++i) sb[i] += __shfl_xor(sb[i], 2);
#pragma unroll
        for (int i = 0; i < 8; ++i) sb[i] += __shfl_xor(sb[i], 4);
#pragma unroll
        for (int i = 0; i < 8; ++i) {
            float exx = __expf(sb[i]);
            den   += exx;
            acc.x += exx * (float)l01[i].x;
            acc.y += exx * (float)l01[i].y;
            acc.z += exx * (float)l23[i].x;
            acc.w += exx * (float)l23[i].y;
        }
    }
    for (; p + 8 <= e1; p += 8) {        // 4 pairs = 8 edges
        int     sA[4];
        ushort4 lu[4];
        float   sb[4];
#pragma unroll
        for (int i = 0; i < 4; ++i) sA[i] = csr_src[p + 2 * i + half];
#pragma unroll
        for (int i = 0; i < 4; ++i) lu[i] = xlp[(size_t)sA[i] * 32 + d0];
        hv2 l01[4], l23[4];
#pragma unroll
        for (int i = 0; i < 4; ++i) { l01[i] = *(hv2*)&lu[i].x; l23[i] = *(hv2*)&lu[i].z; }
#pragma unroll
        for (int i = 0; i < 4; ++i)
            sb[i] = dot2acc_(lrelu2_(l01[i] + r01, c02), a01,
                    dot2acc_(lrelu2_(l23[i] + r23, c02), a23, 0.f));
#pragma unroll
        for (int i = 0; i < 4; ++i) sb[i] += __shfl_xor(sb[i], 1);
#pragma unroll
        for (int i = 0; i < 4; ++i) sb[i] += __shfl_xor(sb[i], 2);
#pragma unroll
        for (int i = 0; i < 4; ++i) sb[i] += __shfl_xor(sb[i], 4);
#pragma unroll
        for (int i = 0; i < 4; ++i) {
            float exx = __expf(sb[i]);
            den   += exx;
            acc.x += exx * (float)l01[i].x;
            acc.y += exx * (float)l01[i].y;
            acc.z += exx * (float)l23[i].x;
            acc.w += exx * (float)l23[i].y;
        }
    }
    for (; p < e1; p += 2) {
        int  idx = p + half;
        bool v   = idx < e1;
        int  s   = csr_src[v ? idx : e1 - 1];
        ushort4 lu = xlp[(size_t)s * 32 + d0];
        hv2 l01 = *(hv2*)&lu.x, l23 = *(hv2*)&lu.z;
        float s1 = dot2acc_(lrelu2_(l01 + r01, c02), a01,
                   dot2acc_(lrelu2_(l23 + r23, c02), a23, 0.f));
        s1 += __shfl_xor(s1, 1);
        s1 += __shfl_xor(s1, 2);
        s1 += __shfl_xor(s1, 4);
        float exx = v ? __expf(s1) : 0.f;
        den   += exx;
        acc.x += exx * (float)l01.x;
        acc.y += exx * (float)l01.y;
        acc.z += exx * (float)l23.x;
        acc.w += exx * (float)l23.y;
    }
    den   += __shfl_xor(den, 32);
    acc.x += __shfl_xor(acc.x, 32);
    acc.y += __shfl_xor(acc.y, 32);
    acc.z += __shfl_xor(acc.z, 32);
    acc.w += __shfl_xor(acc.w, 32);
    if (half == 0) {
        float inv = 1.f / (den + 1e-16f);
        float4 b = ((const float4*)bias)[d0];
        float4 o;
        o.x = elu_(acc.x * inv + b.x);
        o.y = elu_(acc.y * inv + b.y);
        o.z = elu_(acc.z * inv + b.z);
        o.w = elu_(acc.w * inv + b.w);
        ((float4*)hout)[(size_t)n * 32 + d0] = o;   // hout aliases xr: own row only
    }
}

// ---------- conv2 fused: half-wave per node, 4 edges in flight, fp16 gathers, packed score ----------
__global__ __launch_bounds__(256) void k_gat2_fused(
    const int* __restrict__ rs, const int* __restrict__ csr_src,
    const unsigned short* __restrict__ xlb2, const float* __restrict__ xr2,
    const float* __restrict__ att, const float* __restrict__ bias,
    float* __restrict__ h2)
{
    int n = (blockIdx.x * 256 + threadIdx.x) >> 5;
    if (n >= N_NODES) return;
    int lane = threadIdx.x & 31;
    int d0   = lane & 7;
    int sub  = lane >> 3;
    const ushort4* xlp = (const ushort4*)xlb2;
    float4 rf = ((const float4*)xr2)[(size_t)n * 8 + d0];
    hv2 r01 = h2mk_(rf.x, rf.y), r23 = h2mk_(rf.z, rf.w);
    float4 af = ((const float4*)att)[d0];
    hv2 a01 = h2mk_(af.x, af.y), a23 = h2mk_(af.z, af.w);
    const hv2 c02 = h2mk_(0.2f, 0.2f);

    float den;
    float4 acc;
    {   // self edge (sub 0 only)
        ushort4 lu = xlp[(size_t)n * 8 + d0];
        hv2 l01 = *(hv2*)&lu.x, l23 = *(hv2*)&lu.z;
        float sc = dot2acc_(lrelu2_(l01 + r01, c02), a01,
                   dot2acc_(lrelu2_(l23 + r23, c02), a23, 0.f));
        sc += __shfl_xor(sc, 1);
        sc += __shfl_xor(sc, 2);
        sc += __shfl_xor(sc, 4);
        float ex = (sub == 0) ? __expf(sc) : 0.f;
        den = ex;
        acc.x = ex * (float)l01.x;  acc.y = ex * (float)l01.y;
        acc.z = ex * (float)l23.x;  acc.w = ex * (float)l23.y;
    }
    int e0 = rs[n], e1 = rs[n + 1];
    int p = e0;
    for (; p + 16 <= e1; p += 16) {
        int     sA[4];
        ushort4 lu[4];
        float   sb[4];
#pragma unroll
        for (int i = 0; i < 4; ++i) sA[i] = csr_src[p + 4 * i + sub];
#pragma unroll
        for (int i = 0; i < 4; ++i) lu[i] = xlp[(size_t)sA[i] * 8 + d0];
        hv2 l01[4], l23[4];
#pragma unroll
        for (int i = 0; i < 4; ++i) { l01[i] = *(hv2*)&lu[i].x; l23[i] = *(hv2*)&lu[i].z; }
#pragma unroll
        for (int i = 0; i < 4; ++i)
            sb[i] = dot2acc_(lrelu2_(l01[i] + r01, c02), a01,
                    dot2acc_(lrelu2_(l23[i] + r23, c02), a23, 0.f));
#pragma unroll
        for (int i = 0; i < 4; ++i) sb[i] += __shfl_xor(sb[i], 1);
#pragma unroll
        for (int i = 0; i < 4; ++i) sb[i] += __shfl_xor(sb[i], 2);
#pragma unroll
        for (int i = 0; i < 4; ++i) sb[i] += __shfl_xor(sb[i], 4);
#pragma unroll
        for (int i = 0; i < 4; ++i) {
            float exx = __expf(sb[i]);
            den   += exx;
            acc.x += exx * (float)l01[i].x;
            acc.y += exx * (float)l01[i].y;
            acc.z += exx * (float)l23[i].x;
            acc.w += exx * (float)l23[i].y;
        }
    }
    for (; p < e1; p += 4) {
        int  idx = p + sub;
        bool v   = idx < e1;
        int  s   = csr_src[v ? idx : e1 - 1];
        ushort4 lu = xlp[(size_t)s * 8 + d0];
        hv2 l01 = *(hv2*)&lu.x, l23 = *(hv2*)&lu.z;
        float s1 = dot2acc_(lrelu2_(l01 + r01, c02), a01,
                   dot2acc_(lrelu2_(l23 + r23, c02), a23, 0.f));
        s1 += __shfl_xor(s1, 1);
        s1 += __shfl_xor(s1, 2);
        s1 += __shfl_xor(s1, 4);
        float exx = v ? __expf(s1) : 0.f;
        den   += exx;
        acc.x += exx * (float)l01.x;
        acc.y += exx * (float)l01.y;
        acc.z += exx * (float)l23.x;
        acc.w += exx * (float)l23.y;
    }
    den   += __shfl_xor(den, 8);
    den   += __shfl_xor(den, 16);
    acc.x += __shfl_xor(acc.x, 8);  acc.x += __shfl_xor(acc.x, 16);
    acc.y += __shfl_xor(acc.y, 8);  acc.y += __shfl_xor(acc.y, 16);
    acc.z += __shfl_xor(acc.z, 8);  acc.z += __shfl_xor(acc.z, 16);
    acc.w += __shfl_xor(acc.w, 8);  acc.w += __shfl_xor(acc.w, 16);
    if (sub == 0) {
        float inv = 1.f / (den + 1e-16f);
        float4 b = ((const float4*)bias)[d0];
        float4 o;
        o.x = elu_(acc.x * inv + b.x);
        o.y = elu_(acc.y * inv + b.y);
        o.z = elu_(acc.z * inv + b.z);
        o.w = elu_(acc.w * inv + b.w);
        ((float4*)h2)[(size_t)n * 8 + d0] = o;
    }
}

// ---------- per-graph mean pool + both heads ----------
__global__ __launch_bounds__(256) void k_pool_heads(
    const float* __restrict__ h2, const int* __restrict__ gstart,
    const float* __restrict__ wc, const float* __restrict__ bc,
    const float* __restrict__ wp, const float* __restrict__ bp,
    float* __restrict__ out)
{
    int g  = blockIdx.x;
    int n0 = gstart[g], n1 = gstart[g + 1];
    int c    = threadIdx.x & 31;
    int slot = threadIdx.x >> 5;   // 0..7
    float s = 0.f;
    for (int n = n0 + slot; n < n1; n += 8)
        s += h2[n * HID + c];
    __shared__ float red[8][HID];
    red[slot][c] = s;
    __syncthreads();
    if (slot == 0) {
        float tot = 0.f;
#pragma unroll
        for (int i = 0; i < 8; ++i) tot += red[i][c];
        float cntf = fmaxf((float)(n1 - n0), 1.f);
        float p = tot / cntf;
        float sc = p * wc[c];
        float sp = p * wp[c];
        sc += __shfl_xor(sc, 1);  sp += __shfl_xor(sp, 1);
        sc += __shfl_xor(sc, 2);  sp += __shfl_xor(sp, 2);
        sc += __shfl_xor(sc, 4);  sp += __shfl_xor(sp, 4);
        sc += __shfl_xor(sc, 8);  sp += __shfl_xor(sp, 8);
        sc += __shfl_xor(sc, 16); sp += __shfl_xor(sp, 16);
        if (c == 0) {
            out[g]          = sc + bc[0];
            out[NGRAPH + g] = sp + bp[0];
        }
    }
}

extern "C" void kernel_launch(void* const* d_in, const int* in_sizes, int n_in,
                              void* d_out, int out_size, void* d_ws, size_t ws_size,
                              hipStream_t stream)
{
    const float* x     = (const float*)d_in[0];
    const int*   ei    = (const int*)d_in[1];
    const int*   batch = (const int*)d_in[2];
    const float* w1l   = (const float*)d_in[3];
    const float* b1l   = (const float*)d_in[4];
    const float* w1r   = (const float*)d_in[5];
    const float* b1r   = (const float*)d_in[6];
    const float* att1  = (const float*)d_in[7];
    const float* bias1 = (const float*)d_in[8];
    const float* w2l   = (const float*)d_in[9];
    const float* b2l   = (const float*)d_in[10];
    const float* w2r   = (const float*)d_in[11];
    const float* b2r   = (const float*)d_in[12];
    const float* att2  = (const float*)d_in[13];
    const float* bias2 = (const float*)d_in[14];
    const float* wc    = (const float*)d_in[15];
    const float* bc    = (const float*)d_in[16];
    const float* wp    = (const float*)d_in[17];
    const float* bp    = (const float*)d_in[18];
    float* out = (float*)d_out;

    float* ws   = (float*)d_ws;
    // conv1 phase: xlb (fp16 gathered table); xr1 at +6.4M
    unsigned short* xlb = (unsigned short*)ws;          // 6,400,000 ushorts = 12.8 MB
    float* xr1  = ws + 6400000;       // 6,400,000 floats
    float* hbuf = ws + 6400000;       // ALIASES xr1 (safe: per-wave read-own-row-then-write)
    // rank: 800,000 ints in ws floats [3.2M, 4M) — live only during CSR build,
    // later overwritten by h2 (conv2 phase). No temporal overlap.
    int* rank = (int*)(ws + 3200000);
    // conv2 phase (xlb region dead after k_gat1_fused)
    unsigned short* xlb2 = (unsigned short*)ws;         // 1,600,000 ushorts = 3.2 MB
    float* xr2  = ws + 1600000;       // 1,600,000 floats
    float* h2   = ws + 3200000;       // 1,600,000 floats
    // int region (after 12.8M floats)
    int* ibase   = (int*)(ws + 12800000);
    int* deg     = ibase;              //  50,000
    int* rs      = ibase + 50000;      //  50,001
    int* csr_src = ibase + 150001;     // 800,000
    int* gstart  = ibase + 950001;     //      65
    int* btot    = ibase + 950101;     //      49
    int* boff    = ibase + 950151;     //      49
    // re-laid-out weights: conv1 bf16 hi/lo frag-order, conv2 fp32
    unsigned short* bh1 = (unsigned short*)(ws + 13800000);   // 32768 ushort
    unsigned short* bl1_ = (unsigned short*)(ws + 13816384);  // 32768 ushort
    float* wtg2 = ws + 13840000;       //  8,192 floats

    // ---- fused prep, then FUSED transform1+hist (independent, complementary pipes) ----
    k_prep<<<552, 256, 0, stream>>>(w1l, w1r, bh1, bl1_, w2l, w2r, wtg2, deg, batch, gstart);
    k_t1_hist<<<T1_NB + HIST_NB, 256, 0, stream>>>(x, bh1, bl1_, b1l, b1r, xlb, xr1, ei, deg, rank);
    k_scan_local<<<SCAN_NB, 1024, 0, stream>>>(deg, rs, btot);
    k_scan_btot<<<1, 64, 0, stream>>>(btot, boff);
    k_scan_add<<<SCAN_NB, 1024, 0, stream>>>(rs, boff);
    k_scatter<<<(N_EDGES + 255) / 256, 256, 0, stream>>>(ei, rs, rank, csr_src);

    // ---- conv1 attention ----
    k_gat1_fused<<<(N_NODES * 64 + 255) / 256, 256, 0, stream>>>(rs, csr_src, xlb, xr1, att1, bias1, hbuf);

    // ---- conv2 ----
    k_transform2<<<(N_NODES + 63) / 64, 256, 0, stream>>>(hbuf, wtg2, b2l, b2r, xlb2, xr2);
    k_gat2_fused<<<(N_NODES * 32 + 255) / 256, 256, 0, stream>>>(rs, csr_src, xlb2, xr2, att2, bias2, h2);

    // ---- pool + heads ----
    k_pool_heads<<<NGRAPH, 256, 0, stream>>>(h2, gstart, wc, bc, wp, bp, out);
}

// Round 15
// 189.915 us; speedup vs baseline: 1.4039x; 1.0607x over previous
//
#include <hip/hip_runtime.h>

#define N_NODES 50000
#define N_EDGES 800000
#define FEATS   128
#define HID     32
#define HEADS   4
#define D1      128      // HEADS*HID
#define NGRAPH  64
#define SCAN_NB ((N_NODES + 1023) / 1024)   // 49
#define T1_NB   ((N_NODES + 63) / 64)       // 782
#define HIST_NB ((N_EDGES + 255) / 256)     // 3125

__device__ __forceinline__ float lrelu_(float v) { return fmaxf(v, 0.2f * v); }
__device__ __forceinline__ float elu_(float v)   { return v > 0.f ? v : __expf(v) - 1.f; }

typedef __attribute__((ext_vector_type(8))) short short8v;
typedef __attribute__((ext_vector_type(4))) float f32x4;
typedef _Float16 hv2 __attribute__((ext_vector_type(2)));

// fp32 -> bf16 (RNE) high part (for MFMA input splitting)
__device__ __forceinline__ unsigned short bf16hi_(float x) {
    unsigned u = __float_as_uint(x);
    unsigned r = u + 0x7FFFu + ((u >> 16) & 1);
    return (unsigned short)(r >> 16);
}
__device__ __forceinline__ float bf16f_(unsigned short h) {
    return __uint_as_float(((unsigned)h) << 16);
}

// native packed-f16 helpers: +,* -> v_pk_add/mul_f16, max -> v_pk_max_f16, fdot2 -> v_dot2_f32_f16
__device__ __forceinline__ hv2 h2mk_(float x, float y) {
    hv2 r; r.x = (_Float16)x; r.y = (_Float16)y; return r;
}
__device__ __forceinline__ float dot2acc_(hv2 a, hv2 b, float c) {
#if __has_builtin(__builtin_amdgcn_fdot2)
    return __builtin_amdgcn_fdot2(a, b, c, false);
#else
    return fmaf((float)a.x, (float)b.x, fmaf((float)a.y, (float)b.y, c));
#endif
}
__device__ __forceinline__ hv2 lrelu2_(hv2 t, hv2 c02) {
    return __builtin_elementwise_max(t, t * c02);
}
__device__ __forceinline__ unsigned short f2h_(float v) {
    return __builtin_bit_cast(unsigned short, (_Float16)v);
}

// ---------- fused prep: wtrans1(bf16 hi/lo) | wtrans2 | zero(deg) | gbound ----------
__global__ __launch_bounds__(256) void k_prep(
    const float* __restrict__ w1l, const float* __restrict__ w1r,
    unsigned short* __restrict__ bh, unsigned short* __restrict__ blo,
    const float* __restrict__ w2l, const float* __restrict__ w2r, float* __restrict__ wtg2,
    int* __restrict__ deg,
    const int* __restrict__ batch, int* __restrict__ gstart)
{
    int b = blockIdx.x;
    if (b < 128) {
        int idx = b * 256 + threadIdx.x;            // 32768
        int j    = idx & 7;
        int lane = (idx >> 3) & 63;
        int ks   = (idx >> 9) & 3;
        int nfg  = idx >> 11;                       // 0..15
        int col  = nfg * 16 + (lane & 15);
        int k    = ks * 32 + ((lane >> 4) & 3) * 8 + j;
        float wv = (col < 128) ? w1l[col * FEATS + k] : w1r[(col - 128) * FEATS + k];
        unsigned short h = bf16hi_(wv);
        float lo = wv - bf16f_(h);
        bh[idx]  = h;
        blo[idx] = bf16hi_(lo);
    } else if (b < 160) {
        int idx = (b - 128) * 256 + threadIdx.x;    // 8192
        int kk = idx & 3, j = (idx >> 2) & 63, k4 = idx >> 8;
        int k = k4 * 4 + kk;
        wtg2[idx] = (j < 32) ? w2l[j * D1 + k] : w2r[(j - 32) * D1 + k];
    } else if (b < 356) {
        int i = (b - 160) * 256 + threadIdx.x;      // 50176 >= 50000
        if (i < N_NODES) deg[i] = 0;
    } else {
        int i = (b - 356) * 256 + threadIdx.x;      // 50001
        if (i > N_NODES) return;
        int bb   = (i < N_NODES) ? batch[i] : NGRAPH;
        int prev = (i == 0) ? -1 : batch[i - 1];
        for (int g = prev + 1; g <= bb; ++g) gstart[g] = i;
    }
}

// ---------- FUSED conv1-transform + histogram ----------
// blocks [0, T1_NB): MFMA bf16x3 transform (compute-bound);
// blocks [T1_NB, T1_NB+HIST_NB): rank-capturing atomic histogram (latency-bound).
__global__ __launch_bounds__(256) void k_t1_hist(
    const float* __restrict__ x,
    const unsigned short* __restrict__ bh1, const unsigned short* __restrict__ bl1,
    const float* __restrict__ bl, const float* __restrict__ br,
    unsigned short* __restrict__ xlb, float* __restrict__ xr,
    const int* __restrict__ ei, int* __restrict__ deg, int* __restrict__ rank)
{
    __shared__ unsigned short XH[64 * 136];   // 17.4 KB (reserved by all blocks; hist blocks idle it)
    __shared__ unsigned short XL[64 * 136];   // 17.4 KB

    if (blockIdx.x >= T1_NB) {
        int e = (blockIdx.x - T1_NB) * 256 + threadIdx.x;
        if (e < N_EDGES) rank[e] = atomicAdd(&deg[ei[N_EDGES + e]], 1);
        return;
    }

    int m0 = blockIdx.x * 64;
    for (int i = threadIdx.x; i < 2048; i += 256) {      // 64 rows x 32 float4
        int r = i >> 5, c4 = i & 31;
        int n = m0 + r; if (n > N_NODES - 1) n = N_NODES - 1;   // tail clamp (benign dup)
        float4 v = *(const float4*)&x[(size_t)n * FEATS + c4 * 4];
        ushort4 h, lo;
        h.x = bf16hi_(v.x); lo.x = bf16hi_(v.x - bf16f_(h.x));
        h.y = bf16hi_(v.y); lo.y = bf16hi_(v.y - bf16f_(h.y));
        h.z = bf16hi_(v.z); lo.z = bf16hi_(v.z - bf16f_(h.z));
        h.w = bf16hi_(v.w); lo.w = bf16hi_(v.w - bf16f_(h.w));
        *(ushort4*)&XH[r * 136 + c4 * 4] = h;
        *(ushort4*)&XL[r * 136 + c4 * 4] = lo;
    }
    __syncthreads();

    int l  = threadIdx.x & 63;
    int wq = threadIdx.x >> 6;          // wave id = col-quadrant (64 cols)
    int lr = l & 15;
    int lk = (l >> 4) & 3;

    f32x4 acc[4][4];
#pragma unroll
    for (int m = 0; m < 4; ++m)
#pragma unroll
        for (int n = 0; n < 4; ++n)
#pragma unroll
            for (int g = 0; g < 4; ++g) acc[m][n][g] = 0.f;

    const short8v* bhp = (const short8v*)bh1;
    const short8v* blp = (const short8v*)bl1;

#pragma unroll
    for (int ks = 0; ks < 4; ++ks) {
        short8v bh[4], bw[4], ah[4], al[4];
#pragma unroll
        for (int nf = 0; nf < 4; ++nf) {
            int fidx = (((wq * 4 + nf) * 4 + ks) * 64) + l;
            bh[nf] = bhp[fidx];
            bw[nf] = blp[fidx];
        }
#pragma unroll
        for (int mf = 0; mf < 4; ++mf) {
            int off = (mf * 16 + lr) * 136 + ks * 32 + lk * 8;
            ah[mf] = *(const short8v*)&XH[off];
            al[mf] = *(const short8v*)&XL[off];
        }
#pragma unroll
        for (int mf = 0; mf < 4; ++mf)
#pragma unroll
            for (int nf = 0; nf < 4; ++nf) {
                acc[mf][nf] = __builtin_amdgcn_mfma_f32_16x16x32_bf16(ah[mf], bh[nf], acc[mf][nf], 0, 0, 0);
                acc[mf][nf] = __builtin_amdgcn_mfma_f32_16x16x32_bf16(ah[mf], bw[nf], acc[mf][nf], 0, 0, 0);
                acc[mf][nf] = __builtin_amdgcn_mfma_f32_16x16x32_bf16(al[mf], bh[nf], acc[mf][nf], 0, 0, 0);
            }
    }

    // epilogue: D col = lane&15, row = (lane>>4)*4 + reg
#pragma unroll
    for (int nf = 0; nf < 4; ++nf) {
        int col = wq * 64 + nf * 16 + lr;
        float bv = (col < 128) ? bl[col] : br[col - 128];
#pragma unroll
        for (int mf = 0; mf < 4; ++mf)
#pragma unroll
            for (int g = 0; g < 4; ++g) {
                int row = m0 + mf * 16 + lk * 4 + g;
                if (row > N_NODES - 1) row = N_NODES - 1;    // benign dup (same values)
                float v = acc[mf][nf][g] + bv;
                if (col < 128) xlb[(size_t)row * 128 + col] = f2h_(v);
                else           xr [(size_t)row * D1 + (col - 128)] = v;
            }
    }
}

__global__ __launch_bounds__(1024) void k_scan_local(
    const int* __restrict__ deg, int* __restrict__ rs, int* __restrict__ btot)
{
    __shared__ int sm[1024];
    int idx = blockIdx.x * 1024 + threadIdx.x;
    int v = (idx < N_NODES) ? deg[idx] : 0;
    sm[threadIdx.x] = v;
    __syncthreads();
    for (int off = 1; off < 1024; off <<= 1) {
        int t = (threadIdx.x >= off) ? sm[threadIdx.x - off] : 0;
        __syncthreads();
        sm[threadIdx.x] += t;
        __syncthreads();
    }
    if (idx < N_NODES) rs[idx] = sm[threadIdx.x] - v;   // exclusive
    if (threadIdx.x == 1023) btot[blockIdx.x] = sm[1023];
}

__global__ __launch_bounds__(64) void k_scan_btot(
    const int* __restrict__ btot, int* __restrict__ boff)
{
    int t = threadIdx.x;
    int own = (t < SCAN_NB) ? btot[t] : 0;
    int v = own;
    for (int off = 1; off < 64; off <<= 1) {
        int u = __shfl_up(v, off);
        if (t >= off) v += u;
    }
    if (t < SCAN_NB) boff[t] = v - own;   // exclusive
}

__global__ __launch_bounds__(1024) void k_scan_add(
    int* __restrict__ rs, const int* __restrict__ boff)
{
    int idx = blockIdx.x * 1024 + threadIdx.x;
    if (idx < N_NODES) rs[idx] += boff[blockIdx.x];
    if (idx == N_NODES) rs[N_NODES] = N_EDGES;
}

// ---------- scatter: NO atomics — position = rs[dst] + rank[e] ----------
__global__ __launch_bounds__(256) void k_scatter(const int* __restrict__ ei,
                                                const int* __restrict__ rs,
                                                const int* __restrict__ rank,
                                                int* __restrict__ csr_src)
{
    int e = blockIdx.x * 256 + threadIdx.x;
    if (e >= N_EDGES) return;
    int d = ei[N_EDGES + e];
    csr_src[rs[d] + rank[e]] = ei[e];
}

// ---------- conv2 transform: 64 nodes/block, 8 nodes/thread, 2 cols/thread ----------
__global__ __launch_bounds__(256, 2) void k_transform2(
    const float* __restrict__ hin, const float* __restrict__ wtg,
    const float* __restrict__ bl, const float* __restrict__ br,
    unsigned short* __restrict__ xlb2, float* __restrict__ xr2)
{
    __shared__ float4 xs[64][32];   // 32 KB
    int node0 = blockIdx.x * 64;
    for (int i = threadIdx.x; i < 2048; i += 256) {
        int r = i >> 5, k4 = i & 31;
        int n = node0 + r; if (n > N_NODES - 1) n = N_NODES - 1;
        xs[r][k4] = *(const float4*)&hin[(size_t)n * D1 + k4 * 4];
    }
    __syncthreads();
    int j  = threadIdx.x & 31;
    int r0 = (threadIdx.x >> 5) * 8;
    const float4* __restrict__ wp = (const float4*)wtg;
    float accl[8], accr[8];
#pragma unroll
    for (int r = 0; r < 8; ++r) { accl[r] = 0.f; accr[r] = 0.f; }

    float4 wl_ = wp[j], wr_ = wp[j + 32];

#pragma unroll 2
    for (int k4 = 0; k4 < 32; ++k4) {
        int k4n = (k4 < 31) ? k4 + 1 : 31;
        float4 wln = wp[k4n * 64 + j];
        float4 wrn = wp[k4n * 64 + j + 32];
        float4 xv[8];
#pragma unroll
        for (int r = 0; r < 8; ++r) xv[r] = xs[r0 + r][k4];
#pragma unroll
        for (int r = 0; r < 8; ++r) {
            accl[r] = fmaf(wl_.x, xv[r].x, fmaf(wl_.y, xv[r].y,
                      fmaf(wl_.z, xv[r].z, fmaf(wl_.w, xv[r].w, accl[r]))));
            accr[r] = fmaf(wr_.x, xv[r].x, fmaf(wr_.y, xv[r].y,
                      fmaf(wr_.z, xv[r].z, fmaf(wr_.w, xv[r].w, accr[r]))));
        }
        wl_ = wln; wr_ = wrn;
    }
    float bls = bl[j], brs = br[j];
#pragma unroll
    for (int r = 0; r < 8; ++r) {
        int nn = node0 + r0 + r; if (nn > N_NODES - 1) nn = N_NODES - 1;
        size_t n = (size_t)nn;
        xlb2[n * HID + j] = f2h_(accl[r] + bls);
        xr2 [n * HID + j] = accr[r] + brs;
    }
}

// ---------- conv1 fused: wave per node, 2 edges/wave, fp16 gathers, 4 deep (R13 form) ----------
__global__ __launch_bounds__(256) void k_gat1_fused(
    const int* __restrict__ rs, const int* __restrict__ csr_src,
    const unsigned short* __restrict__ xlb, const float* __restrict__ xr,
    const float* __restrict__ att, const float* __restrict__ bias,
    float* __restrict__ hout)
{
    int n = (blockIdx.x * 256 + threadIdx.x) >> 6;
    if (n >= N_NODES) return;
    int lane = threadIdx.x & 63;
    int d0   = lane & 31;
    int half = lane >> 5;
    const ushort4* xlp = (const ushort4*)xlb;
    float4 rf = ((const float4*)xr)[(size_t)n * 32 + d0];
    hv2 r01 = h2mk_(rf.x, rf.y), r23 = h2mk_(rf.z, rf.w);
    float4 af = ((const float4*)att)[d0];
    hv2 a01 = h2mk_(af.x, af.y), a23 = h2mk_(af.z, af.w);
    const hv2 c02 = h2mk_(0.2f, 0.2f);

    float den;
    float4 acc;
    {   // self edge (counted on half 0 only)
        ushort4 lu = xlp[(size_t)n * 32 + d0];
        hv2 l01 = *(hv2*)&lu.x, l23 = *(hv2*)&lu.z;
        float sc = dot2acc_(lrelu2_(l01 + r01, c02), a01,
                   dot2acc_(lrelu2_(l23 + r23, c02), a23, 0.f));
        sc += __shfl_xor(sc, 1);
        sc += __shfl_xor(sc, 2);
        sc += __shfl_xor(sc, 4);
        float ex = (half == 0) ? __expf(sc) : 0.f;
        den = ex;
        acc.x = ex * (float)l01.x;  acc.y = ex * (float)l01.y;
        acc.z = ex * (float)l23.x;  acc.w = ex * (float)l23.y;
    }
    int e0 = rs[n], e1 = rs[n + 1];
    int p = e0;
    for (; p + 8 <= e1; p += 8) {        // 4 pairs = 8 edges, 4 gathers in flight
        int     sA[4];
        ushort4 lu[4];
        float   sb[4];
#pragma unroll
        for (int i = 0; i < 4; ++i) sA[i] = csr_src[p + 2 * i + half];
#pragma unroll
        for (int i = 0; i < 4; ++i) lu[i] = xlp[(size_t)sA[i] * 32 + d0];
        hv2 l01[4], l23[4];
#pragma unroll
        for (int i = 0; i < 4; ++i) { l01[i] = *(hv2*)&lu[i].x; l23[i] = *(hv2*)&lu[i].z; }
#pragma unroll
        for (int i = 0; i < 4; ++i)
            sb[i] = dot2acc_(lrelu2_(l01[i] + r01, c02), a01,
                    dot2acc_(lrelu2_(l23[i] + r23, c02), a23, 0.f));
#pragma unroll
        for (int i = 0; i < 4; ++i) sb[i] += __shfl_xor(sb[i], 1);
#pragma unroll
        for (int i = 0; i < 4; ++i) sb[i] += __shfl_xor(sb[i], 2);
#pragma unroll
        for (int i = 0; i < 4; ++i) sb[i] += __shfl_xor(sb[i], 4);
#pragma unroll
        for (int i = 0; i < 4; ++i) {
            float exx = __expf(sb[i]);
            den   += exx;
            acc.x += exx * (float)l01[i].x;
            acc.y += exx * (float)l01[i].y;
            acc.z += exx * (float)l23[i].x;
            acc.w += exx * (float)l23[i].y;
        }
    }
    for (; p < e1; p += 2) {
        int  idx = p + half;
        bool v   = idx < e1;
        int  s   = csr_src[v ? idx : e1 - 1];
        ushort4 lu = xlp[(size_t)s * 32 + d0];
        hv2 l01 = *(hv2*)&lu.x, l23 = *(hv2*)&lu.z;
        float s1 = dot2acc_(lrelu2_(l01 + r01, c02), a01,
                   dot2acc_(lrelu2_(l23 + r23, c02), a23, 0.f));
        s1 += __shfl_xor(s1, 1);
        s1 += __shfl_xor(s1, 2);
        s1 += __shfl_xor(s1, 4);
        float exx = v ? __expf(s1) : 0.f;
        den   += exx;
        acc.x += exx * (float)l01.x;
        acc.y += exx * (float)l01.y;
        acc.z += exx * (float)l23.x;
        acc.w += exx * (float)l23.y;
    }
    den   += __shfl_xor(den, 32);
    acc.x += __shfl_xor(acc.x, 32);
    acc.y += __shfl_xor(acc.y, 32);
    acc.z += __shfl_xor(acc.z, 32);
    acc.w += __shfl_xor(acc.w, 32);
    if (half == 0) {
        float inv = 1.f / (den + 1e-16f);
        float4 b = ((const float4*)bias)[d0];
        float4 o;
        o.x = elu_(acc.x * inv + b.x);
        o.y = elu_(acc.y * inv + b.y);
        o.z = elu_(acc.z * inv + b.z);
        o.w = elu_(acc.w * inv + b.w);
        ((float4*)hout)[(size_t)n * 32 + d0] = o;   // hout aliases xr: own row only
    }
}

// ---------- conv2 fused: half-wave per node, 4 edges in flight, fp16 gathers, packed score ----------
__global__ __launch_bounds__(256) void k_gat2_fused(
    const int* __restrict__ rs, const int* __restrict__ csr_src,
    const unsigned short* __restrict__ xlb2, const float* __restrict__ xr2,
    const float* __restrict__ att, const float* __restrict__ bias,
    float* __restrict__ h2)
{
    int n = (blockIdx.x * 256 + threadIdx.x) >> 5;
    if (n >= N_NODES) return;
    int lane = threadIdx.x & 31;
    int d0   = lane & 7;
    int sub  = lane >> 3;
    const ushort4* xlp = (const ushort4*)xlb2;
    float4 rf = ((const float4*)xr2)[(size_t)n * 8 + d0];
    hv2 r01 = h2mk_(rf.x, rf.y), r23 = h2mk_(rf.z, rf.w);
    float4 af = ((const float4*)att)[d0];
    hv2 a01 = h2mk_(af.x, af.y), a23 = h2mk_(af.z, af.w);
    const hv2 c02 = h2mk_(0.2f, 0.2f);

    float den;
    float4 acc;
    {   // self edge (sub 0 only)
        ushort4 lu = xlp[(size_t)n * 8 + d0];
        hv2 l01 = *(hv2*)&lu.x, l23 = *(hv2*)&lu.z;
        float sc = dot2acc_(lrelu2_(l01 + r01, c02), a01,
                   dot2acc_(lrelu2_(l23 + r23, c02), a23, 0.f));
        sc += __shfl_xor(sc, 1);
        sc += __shfl_xor(sc, 2);
        sc += __shfl_xor(sc, 4);
        float ex = (sub == 0) ? __expf(sc) : 0.f;
        den = ex;
        acc.x = ex * (float)l01.x;  acc.y = ex * (float)l01.y;
        acc.z = ex * (float)l23.x;  acc.w = ex * (float)l23.y;
    }
    int e0 = rs[n], e1 = rs[n + 1];
    int p = e0;
    for (; p + 16 <= e1; p += 16) {
        int     sA[4];
        ushort4 lu[4];
        float   sb[4];
#pragma unroll
        for (int i = 0; i < 4; ++i) sA[i] = csr_src[p + 4 * i + sub];
#pragma unroll
        for (int i = 0; i < 4; ++i) lu[i] = xlp[(size_t)sA[i] * 8 + d0];
        hv2 l01[4], l23[4];
#pragma unroll
        for (int i = 0; i < 4; ++i) { l01[i] = *(hv2*)&lu[i].x; l23[i] = *(hv2*)&lu[i].z; }
#pragma unroll
        for (int i = 0; i < 4; ++i)
            sb[i] = dot2acc_(lrelu2_(l01[i] + r01, c02), a01,
                    dot2acc_(lrelu2_(l23[i] + r23, c02), a23, 0.f));
#pragma unroll
        for (int i = 0; i < 4; ++i) sb[i] += __shfl_xor(sb[i], 1);
#pragma unroll
        for (int i = 0; i < 4; ++i) sb[i] += __shfl_xor(sb[i], 2);
#pragma unroll
        for (int i = 0; i < 4; ++i) sb[i] += __shfl_xor(sb[i], 4);
#pragma unroll
        for (int i = 0; i < 4; ++i) {
            float exx = __expf(sb[i]);
            den   += exx;
            acc.x += exx * (float)l01[i].x;
            acc.y += exx * (float)l01[i].y;
            acc.z += exx * (float)l23[i].x;
            acc.w += exx * (float)l23[i].y;
        }
    }
    for (; p < e1; p += 4) {
        int  idx = p + sub;
        bool v   = idx < e1;
        int  s   = csr_src[v ? idx : e1 - 1];
        ushort4 lu = xlp[(size_t)s * 8 + d0];
        hv2 l01 = *(hv2*)&lu.x, l23 = *(hv2*)&lu.z;
        float s1 = dot2acc_(lrelu2_(l01 + r01, c02), a01,
                   dot2acc_(lrelu2_(l23 + r23, c02), a23, 0.f));
        s1 += __shfl_xor(s1, 1);
        s1 += __shfl_xor(s1, 2);
        s1 += __shfl_xor(s1, 4);
        float exx = v ? __expf(s1) : 0.f;
        den   += exx;
        acc.x += exx * (float)l01.x;
        acc.y += exx * (float)l01.y;
        acc.z += exx * (float)l23.x;
        acc.w += exx * (float)l23.y;
    }
    den   += __shfl_xor(den, 8);
    den   += __shfl_xor(den, 16);
    acc.x += __shfl_xor(acc.x, 8);  acc.x += __shfl_xor(acc.x, 16);
    acc.y += __shfl_xor(acc.y, 8);  acc.y += __shfl_xor(acc.y, 16);
    acc.z += __shfl_xor(acc.z, 8);  acc.z += __shfl_xor(acc.z, 16);
    acc.w += __shfl_xor(acc.w, 8);  acc.w += __shfl_xor(acc.w, 16);
    if (sub == 0) {
        float inv = 1.f / (den + 1e-16f);
        float4 b = ((const float4*)bias)[d0];
        float4 o;
        o.x = elu_(acc.x * inv + b.x);
        o.y = elu_(acc.y * inv + b.y);
        o.z = elu_(acc.z * inv + b.z);
        o.w = elu_(acc.w * inv + b.w);
        ((float4*)h2)[(size_t)n * 8 + d0] = o;
    }
}

// ---------- per-graph mean pool + both heads ----------
__global__ __launch_bounds__(256) void k_pool_heads(
    const float* __restrict__ h2, const int* __restrict__ gstart,
    const float* __restrict__ wc, const float* __restrict__ bc,
    const float* __restrict__ wp, const float* __restrict__ bp,
    float* __restrict__ out)
{
    int g  = blockIdx.x;
    int n0 = gstart[g], n1 = gstart[g + 1];
    int c    = threadIdx.x & 31;
    int slot = threadIdx.x >> 5;   // 0..7
    float s = 0.f;
    for (int n = n0 + slot; n < n1; n += 8)
        s += h2[n * HID + c];
    __shared__ float red[8][HID];
    red[slot][c] = s;
    __syncthreads();
    if (slot == 0) {
        float tot = 0.f;
#pragma unroll
        for (int i = 0; i < 8; ++i) tot += red[i][c];
        float cntf = fmaxf((float)(n1 - n0), 1.f);
        float p = tot / cntf;
        float sc = p * wc[c];
        float sp = p * wp[c];
        sc += __shfl_xor(sc, 1);  sp += __shfl_xor(sp, 1);
        sc += __shfl_xor(sc, 2);  sp += __shfl_xor(sp, 2);
        sc += __shfl_xor(sc, 4);  sp += __shfl_xor(sp, 4);
        sc += __shfl_xor(sc, 8);  sp += __shfl_xor(sp, 8);
        sc += __shfl_xor(sc, 16); sp += __shfl_xor(sp, 16);
        if (c == 0) {
            out[g]          = sc + bc[0];
            out[NGRAPH + g] = sp + bp[0];
        }
    }
}

extern "C" void kernel_launch(void* const* d_in, const int* in_sizes, int n_in,
                              void* d_out, int out_size, void* d_ws, size_t ws_size,
                              hipStream_t stream)
{
    const float* x     = (const float*)d_in[0];
    const int*   ei    = (const int*)d_in[1];
    const int*   batch = (const int*)d_in[2];
    const float* w1l   = (const float*)d_in[3];
    const float* b1l   = (const float*)d_in[4];
    const float* w1r   = (const float*)d_in[5];
    const float* b1r   = (const float*)d_in[6];
    const float* att1  = (const float*)d_in[7];
    const float* bias1 = (const float*)d_in[8];
    const float* w2l   = (const float*)d_in[9];
    const float* b2l   = (const float*)d_in[10];
    const float* w2r   = (const float*)d_in[11];
    const float* b2r   = (const float*)d_in[12];
    const float* att2  = (const float*)d_in[13];
    const float* bias2 = (const float*)d_in[14];
    const float* wc    = (const float*)d_in[15];
    const float* bc    = (const float*)d_in[16];
    const float* wp    = (const float*)d_in[17];
    const float* bp    = (const float*)d_in[18];
    float* out = (float*)d_out;

    float* ws   = (float*)d_ws;
    // conv1 phase: xlb (fp16 gathered table); xr1 at +6.4M
    unsigned short* xlb = (unsigned short*)ws;          // 6,400,000 ushorts = 12.8 MB
    float* xr1  = ws + 6400000;       // 6,400,000 floats
    float* hbuf = ws + 6400000;       // ALIASES xr1 (safe: per-wave read-own-row-then-write)
    // rank: 800,000 ints in ws floats [3.2M, 4M) — live only during CSR build,
    // later overwritten by h2 (conv2 phase). No temporal overlap.
    int* rank = (int*)(ws + 3200000);
    // conv2 phase (xlb region dead after k_gat1_fused)
    unsigned short* xlb2 = (unsigned short*)ws;         // 1,600,000 ushorts = 3.2 MB
    float* xr2  = ws + 1600000;       // 1,600,000 floats
    float* h2   = ws + 3200000;       // 1,600,000 floats
    // int region (after 12.8M floats)
    int* ibase   = (int*)(ws + 12800000);
    int* deg     = ibase;              //  50,000
    int* rs      = ibase + 50000;      //  50,001
    int* csr_src = ibase + 150001;     // 800,000
    int* gstart  = ibase + 950001;     //      65
    int* btot    = ibase + 950101;     //      49
    int* boff    = ibase + 950151;     //      49
    // re-laid-out weights: conv1 bf16 hi/lo frag-order, conv2 fp32
    unsigned short* bh1 = (unsigned short*)(ws + 13800000);   // 32768 ushort
    unsigned short* bl1_ = (unsigned short*)(ws + 13816384);  // 32768 ushort
    float* wtg2 = ws + 13840000;       //  8,192 floats

    // ---- fused prep, then FUSED transform1+hist (independent, complementary pipes) ----
    k_prep<<<552, 256, 0, stream>>>(w1l, w1r, bh1, bl1_, w2l, w2r, wtg2, deg, batch, gstart);
    k_t1_hist<<<T1_NB + HIST_NB, 256, 0, stream>>>(x, bh1, bl1_, b1l, b1r, xlb, xr1, ei, deg, rank);
    k_scan_local<<<SCAN_NB, 1024, 0, stream>>>(deg, rs, btot);
    k_scan_btot<<<1, 64, 0, stream>>>(btot, boff);
    k_scan_add<<<SCAN_NB, 1024, 0, stream>>>(rs, boff);
    k_scatter<<<(N_EDGES + 255) / 256, 256, 0, stream>>>(ei, rs, rank, csr_src);

    // ---- conv1 attention ----
    k_gat1_fused<<<(N_NODES * 64 + 255) / 256, 256, 0, stream>>>(rs, csr_src, xlb, xr1, att1, bias1, hbuf);

    // ---- conv2 ----
    k_transform2<<<(N_NODES + 63) / 64, 256, 0, stream>>>(hbuf, wtg2, b2l, b2r, xlb2, xr2);
    k_gat2_fused<<<(N_NODES * 32 + 255) / 256, 256, 0, stream>>>(rs, csr_src, xlb2, xr2, att2, bias2, h2);

    // ---- pool + heads ----
    k_pool_heads<<<NGRAPH, 256, 0, stream>>>(h2, gstart, wc, bc, wp, bp, out);
}